// Round 14
// baseline (564.686 us; speedup 1.0000x reference)
//
#include <hip/hip_runtime.h>
#include <math.h>

#define NPIX 131072   // 2*256*256

typedef __attribute__((ext_vector_type(8))) short bfrag;
typedef __attribute__((ext_vector_type(4))) float facc;
typedef __attribute__((ext_vector_type(4))) unsigned short us4;

__device__ __forceinline__ float lrelu_f(float x) { return x >= 0.f ? x : 0.2f * x; }

// window w (0..511): b=w>>8, wi=(w>>4)&15, wj=w&15 ; l (0..255): i=l>>4, j=l&15
__device__ __forceinline__ int pix_of(int w, int l) {
    int b = w >> 8, wi = (w >> 4) & 15, wj = w & 15;
    return ((((b << 4) + wi) * 16 + (l >> 4)) << 8) + (wj << 4) + (l & 15);
}

// ---- bf16 split helpers (round-to-nearest-even) ----
__device__ __forceinline__ unsigned short bf16rn(float f) {
    unsigned u = __builtin_bit_cast(unsigned, f);
    u += 0x7FFFu + ((u >> 16) & 1u);
    return (unsigned short)(u >> 16);
}
__device__ __forceinline__ float bf16tof(unsigned short h) {
    unsigned u = ((unsigned)h) << 16;
    return __builtin_bit_cast(float, u);
}

// ---------------- pre-pass: split fp32 -> packed [hi|lo] bf16 ----------------
// xs2 row: shorts [0,256) = hi(k), [256,512) = lo(k); k>=240 zero.
__global__ __launch_bounds__(256) void split_x_kernel(const float* __restrict__ x,
                                                      unsigned short* __restrict__ xs2)
{
    int idx = blockIdx.x * 256 + threadIdx.x;    // 131072*32
    int row = idx >> 5;
    int k = (idx & 31) * 8;
    float v[8];
    if (k < 240) {
        float4 a = *(const float4*)(x + (size_t)row * 240 + k);
        float4 b = *(const float4*)(x + (size_t)row * 240 + k + 4);
        v[0] = a.x; v[1] = a.y; v[2] = a.z; v[3] = a.w;
        v[4] = b.x; v[5] = b.y; v[6] = b.z; v[7] = b.w;
    } else {
#pragma unroll
        for (int e = 0; e < 8; ++e) v[e] = 0.f;
    }
    bfrag hi, lo;
#pragma unroll
    for (int e = 0; e < 8; ++e) {
        unsigned short h = bf16rn(v[e]);
        hi[e] = (short)h;
        lo[e] = (short)bf16rn(v[e] - bf16tof(h));
    }
    unsigned short* dst = xs2 + (size_t)row * 512 + k;
    *(bfrag*)(dst) = hi;
    *(bfrag*)(dst + 256) = lo;
}

// generic weight pack body: src [rows][K] fp32 -> dst [rows_pad][2*KPAD] shorts (zero padded)
__device__ __forceinline__ void pack_w_body(const float* __restrict__ src,
                                            int rows, int K,
                                            unsigned short* __restrict__ dst,
                                            int total8, int KPAD, int idx)
{
    if (idx >= total8) return;
    int kper = KPAD >> 3;
    int row = idx / kper;
    int k = (idx - row * kper) * 8;
    float v[8];
#pragma unroll
    for (int e = 0; e < 8; ++e) {
        int kk = k + e;
        v[e] = (row < rows && kk < K) ? src[(size_t)row * K + kk] : 0.f;
    }
    bfrag hi, lo;
#pragma unroll
    for (int e = 0; e < 8; ++e) {
        unsigned short h = bf16rn(v[e]);
        hi[e] = (short)h;
        lo[e] = (short)bf16rn(v[e] - bf16tof(h));
    }
    unsigned short* d = dst + (size_t)row * 2 * KPAD + k;
    *(bfrag*)(d) = hi;
    *(bfrag*)(d + KPAD) = lo;
}

// c2 weights body -> c2w2[tap][n][ hi64 | lo64 ]  (tap = ky*3+kx; ci pad 48..63 = 0)
__device__ __forceinline__ void pack_c2w_body(const float* __restrict__ c2_w,
                                              unsigned short* __restrict__ c2w2, int idx)
{
    if (idx >= 6912) return;
    int rowid = idx >> 4;          // tap*48 + n
    int c = idx & 15;
    int tap = rowid / 48, n = rowid - tap * 48;
    int ty = tap / 3, tx = tap - ty * 3;
    int lohalf = c >> 3;
    int cbase = (c & 7) * 8;
    bfrag outv;
#pragma unroll
    for (int e = 0; e < 8; ++e) {
        int ci = cbase + e;
        float v = (ci < 48) ? c2_w[(((size_t)n * 48 + ci) * 3 + ty) * 3 + tx] : 0.f;
        unsigned short h = bf16rn(v);
        outv[e] = (short)(lohalf ? bf16rn(v - bf16tof(h)) : h);
    }
    *(bfrag*)(c2w2 + (size_t)rowid * 128 + c * 8) = outv;
}

// merged weight-pack kernel: block-range dispatch over the 5 pack jobs
__global__ __launch_bounds__(256) void pack_all_kernel(
    const float* __restrict__ lin_w, const float* __restrict__ proj_w,
    const float* __restrict__ c3_w, const float* __restrict__ c1_w,
    const float* __restrict__ c2_w,
    unsigned short* __restrict__ lin_w2, unsigned short* __restrict__ proj_w2,
    unsigned short* __restrict__ c3_w2, unsigned short* __restrict__ c1_w2,
    unsigned short* __restrict__ c2w2)
{
    int blk = blockIdx.x, tid = threadIdx.x;
    if (blk < 32)       pack_w_body(lin_w, 240, 240, lin_w2, 8192, 256, blk * 256 + tid);
    else if (blk < 64)  pack_w_body(proj_w, 240, 240, proj_w2, 8192, 256, (blk - 32) * 256 + tid);
    else if (blk < 72)  pack_w_body(c3_w, 240, 48, c3_w2, 2048, 64, (blk - 64) * 256 + tid);
    else if (blk < 88)  pack_w_body(c1_w, 48, 240, c1_w2, 4096, 256, (blk - 72) * 256 + tid);
    else                pack_c2w_body(c2_w, c2w2, (blk - 88) * 256 + tid);
}

// ---------------- prep: DynamicPosBias MLP ----------------
__device__ __forceinline__ void ln_relu15(const float* h, float* r,
                                          const float* __restrict__ g,
                                          const float* __restrict__ b) {
    float m = 0.f;
#pragma unroll
    for (int f = 0; f < 15; ++f) m += h[f];
    m *= (1.f / 15.f);
    float v = 0.f;
#pragma unroll
    for (int f = 0; f < 15; ++f) { float d = h[f] - m; v += d * d; }
    float rs = rsqrtf(v * (1.f / 15.f) + 1e-5f);
#pragma unroll
    for (int f = 0; f < 15; ++f) {
        float xx = (h[f] - m) * rs * g[f] + b[f];
        r[f] = xx > 0.f ? xx : 0.f;
    }
}

__device__ __forceinline__ void lin15(const float* r, float* h,
                                      const float* __restrict__ w,
                                      const float* __restrict__ b) {
#pragma unroll
    for (int o = 0; o < 15; ++o) {
        float s = b[o];
#pragma unroll
        for (int g = 0; g < 15; ++g) s += r[g] * w[o * 15 + g];
        h[o] = s;
    }
}

__global__ __launch_bounds__(256) void prep_pos_kernel(
    const float* __restrict__ pp_w, const float* __restrict__ pp_b,
    const float* __restrict__ ln1_g, const float* __restrict__ ln1_b,
    const float* __restrict__ p1_w, const float* __restrict__ p1_b,
    const float* __restrict__ ln2_g, const float* __restrict__ ln2_b,
    const float* __restrict__ p2_w, const float* __restrict__ p2_b,
    const float* __restrict__ ln3_g, const float* __restrict__ ln3_b,
    const float* __restrict__ p3_w, const float* __restrict__ p3_b,
    float* __restrict__ pos3)
{
    int idx = blockIdx.x * 256 + threadIdx.x;
    if (idx >= 961) return;
    float h[15], r[15];
    float in0 = (float)(idx / 31) - 15.f;
    float in1 = (float)(idx % 31) - 15.f;
#pragma unroll
    for (int f = 0; f < 15; ++f) h[f] = in0 * pp_w[2 * f] + in1 * pp_w[2 * f + 1] + pp_b[f];
    ln_relu15(h, r, ln1_g, ln1_b);
    lin15(r, h, p1_w, p1_b);
    ln_relu15(h, r, ln2_g, ln2_b);
    lin15(r, h, p2_w, p2_b);
    ln_relu15(h, r, ln3_g, ln3_b);
#pragma unroll
    for (int o = 0; o < 6; ++o) {
        float s = p3_b[o];
#pragma unroll
        for (int g = 0; g < 15; ++g) s += r[g] * p3_w[o * 15 + g];
        pos3[idx * 6 + o] = s;
    }
}

// rpb_t[n][k][l]  (n<6, k<64 base-window key, l<256 query pos)
__global__ __launch_bounds__(256) void rpb_kernel(const float* __restrict__ pos3,
                                                  float* __restrict__ rpb_t)
{
    int out = blockIdx.x * 256 + threadIdx.x;   // < 98304
    int n = out >> 14;
    int k = (out >> 8) & 63;
    int l = out & 255;
    int a = k >> 3, c = k & 7;
    int i1 = l >> 4, j1 = l & 15;
    float s = 0.f;
#pragma unroll
    for (int bb = 0; bb < 2; ++bb)
#pragma unroll
        for (int d = 0; d < 2; ++d) {
            int i2 = a * 2 + bb, j2 = c * 2 + d;
            int rpi = (i1 - i2 + 15) * 31 + (j1 - j2 + 15);
            s += pos3[rpi * 6 + n];
        }
    rpb_t[out] = s * 0.25f;
}

// ---------------- MFMA split-bf16 NT GEMM core, BM=128 BN=128 (R11 known-good) ----------------
// LDS row: [32 hi][32 lo] shorts, stride 72. Frag: lane l -> row (l&15), chunk (l>>4)*8.
__device__ __forceinline__ void mfma_kpass3(const unsigned short* __restrict__ A2, int lda2,
                                            const unsigned short* __restrict__ W2, int ldw2,
                                            int ksteps, int mbase, int nbase,
                                            short* lds_a, short* lds_w,
                                            int tid, int wm, int wn,
                                            facc acc[4][4])
{
    int lane = tid & 63;
    int i = lane & 15, g = lane >> 4;
    int kpa = lda2 >> 1, kpw = ldw2 >> 1;
    for (int s = 0; s < ksteps; ++s) {
        int k0 = s * 32;
        {   // stage A: 128 rows x (32 hi + 32 lo) shorts
            int r = tid >> 1, h16 = (tid & 1) * 16;
            const unsigned short* src = A2 + (size_t)(mbase + r) * lda2 + k0 + h16;
            bfrag h0 = *(const bfrag*)(src);
            bfrag h1 = *(const bfrag*)(src + 8);
            bfrag l0 = *(const bfrag*)(src + kpa);
            bfrag l1 = *(const bfrag*)(src + kpa + 8);
            short* dst = lds_a + r * 72 + h16;
            *(bfrag*)(dst)      = h0;  *(bfrag*)(dst + 8)  = h1;
            *(bfrag*)(dst + 32) = l0;  *(bfrag*)(dst + 40) = l1;
        }
        {   // stage W: 128 rows x (32 hi + 32 lo) shorts; thread: row + half
            int r = tid >> 1, half = tid & 1;
            const unsigned short* src = W2 + (size_t)(nbase + r) * ldw2 + half * kpw + k0;
            bfrag v0 = *(const bfrag*)(src);
            bfrag v1 = *(const bfrag*)(src + 8);
            bfrag v2 = *(const bfrag*)(src + 16);
            bfrag v3 = *(const bfrag*)(src + 24);
            short* dst = lds_w + r * 72 + half * 32;
            *(bfrag*)(dst)      = v0;  *(bfrag*)(dst + 8)  = v1;
            *(bfrag*)(dst + 16) = v2;  *(bfrag*)(dst + 24) = v3;
        }
        __syncthreads();
        bfrag ah[4], al[4], bh[4], bl[4];
#pragma unroll
        for (int mu = 0; mu < 4; ++mu) {
            const short* p = lds_a + (wm * 64 + mu * 16 + i) * 72 + g * 8;
            ah[mu] = *(const bfrag*)(p);
            al[mu] = *(const bfrag*)(p + 32);
        }
#pragma unroll
        for (int nu = 0; nu < 4; ++nu) {
            const short* p = lds_w + (wn * 64 + nu * 16 + i) * 72 + g * 8;
            bh[nu] = *(const bfrag*)(p);
            bl[nu] = *(const bfrag*)(p + 32);
        }
#pragma unroll
        for (int mu = 0; mu < 4; ++mu)
#pragma unroll
            for (int nu = 0; nu < 4; ++nu) {
                acc[mu][nu] = __builtin_amdgcn_mfma_f32_16x16x32_bf16(ah[mu], bh[nu], acc[mu][nu], 0, 0, 0);
                acc[mu][nu] = __builtin_amdgcn_mfma_f32_16x16x32_bf16(ah[mu], bl[nu], acc[mu][nu], 0, 0, 0);
                acc[mu][nu] = __builtin_amdgcn_mfma_f32_16x16x32_bf16(al[mu], bh[nu], acc[mu][nu], 0, 0, 0);
            }
        __syncthreads();
    }
}

// ---------------- BN=64 variant (conv1): simple 2-barrier loop, 4 waves = 2x2 ----------------
__device__ __forceinline__ void mfma_kpass_n64(const unsigned short* __restrict__ A2, int lda2,
                                               const unsigned short* __restrict__ W2, int ldw2,
                                               int ksteps, int mbase,
                                               short* lds_a, short* lds_w,
                                               int tid, int wm, int wn,
                                               facc acc[4][2])
{
    int lane = tid & 63;
    int i = lane & 15, g = lane >> 4;
    int kpa = lda2 >> 1, kpw = ldw2 >> 1;
    for (int s = 0; s < ksteps; ++s) {
        int k0 = s * 32;
        {   // stage A: 128 rows x (32 hi + 32 lo) shorts
            int r = tid >> 1, h16 = (tid & 1) * 16;
            const unsigned short* src = A2 + (size_t)(mbase + r) * lda2 + k0 + h16;
            bfrag h0 = *(const bfrag*)(src);
            bfrag h1 = *(const bfrag*)(src + 8);
            bfrag l0 = *(const bfrag*)(src + kpa);
            bfrag l1 = *(const bfrag*)(src + kpa + 8);
            short* dst = lds_a + r * 72 + h16;
            *(bfrag*)(dst)      = h0;  *(bfrag*)(dst + 8)  = h1;
            *(bfrag*)(dst + 32) = l0;  *(bfrag*)(dst + 40) = l1;
        }
        if (tid < 128) {   // stage W: 64 rows
            int r = tid >> 1, half = tid & 1;
            const unsigned short* src = W2 + (size_t)r * ldw2 + half * kpw + k0;
            bfrag v0 = *(const bfrag*)(src);
            bfrag v1 = *(const bfrag*)(src + 8);
            bfrag v2 = *(const bfrag*)(src + 16);
            bfrag v3 = *(const bfrag*)(src + 24);
            short* dst = lds_w + r * 72 + half * 32;
            *(bfrag*)(dst)      = v0;  *(bfrag*)(dst + 8)  = v1;
            *(bfrag*)(dst + 16) = v2;  *(bfrag*)(dst + 24) = v3;
        }
        __syncthreads();
        bfrag ah[4], al[4], bh[2], bl[2];
#pragma unroll
        for (int mu = 0; mu < 4; ++mu) {
            const short* p = lds_a + (wm * 64 + mu * 16 + i) * 72 + g * 8;
            ah[mu] = *(const bfrag*)(p);
            al[mu] = *(const bfrag*)(p + 32);
        }
#pragma unroll
        for (int nu = 0; nu < 2; ++nu) {
            const short* p = lds_w + (wn * 32 + nu * 16 + i) * 72 + g * 8;
            bh[nu] = *(const bfrag*)(p);
            bl[nu] = *(const bfrag*)(p + 32);
        }
#pragma unroll
        for (int mu = 0; mu < 4; ++mu)
#pragma unroll
            for (int nu = 0; nu < 2; ++nu) {
                acc[mu][nu] = __builtin_amdgcn_mfma_f32_16x16x32_bf16(ah[mu], bh[nu], acc[mu][nu], 0, 0, 0);
                acc[mu][nu] = __builtin_amdgcn_mfma_f32_16x16x32_bf16(ah[mu], bl[nu], acc[mu][nu], 0, 0, 0);
                acc[mu][nu] = __builtin_amdgcn_mfma_f32_16x16x32_bf16(al[mu], bh[nu], acc[mu][nu], 0, 0, 0);
            }
        __syncthreads();
    }
}

// conv1: t1s = split(lrelu(x @ c1_w^T + c1_b)) packed [hi64|lo64], N=48 (BN=64)
// launch_bounds(256,3): single 32-AGPR acc -> cap regs for 3 waves/SIMD
__global__ __launch_bounds__(256, 3) void conv1_mfma_kernel(const unsigned short* __restrict__ xs2,
    const unsigned short* __restrict__ c1_w2, const float* __restrict__ bias,
    unsigned short* __restrict__ t1s)
{
    __shared__ __align__(16) short lds_a[128 * 72];
    __shared__ __align__(16) short lds_w[64 * 72];
    int tid = threadIdx.x;
    int lane = tid & 63, wid = tid >> 6;
    int wm = wid >> 1, wn = wid & 1;
    int mbase = blockIdx.x * 128;
    facc zero = {0.f, 0.f, 0.f, 0.f};
    facc acc[4][2];
#pragma unroll
    for (int mu = 0; mu < 4; ++mu)
#pragma unroll
        for (int nu = 0; nu < 2; ++nu) acc[mu][nu] = zero;

    mfma_kpass_n64(xs2, 512, c1_w2, 512, 8, mbase, lds_a, lds_w, tid, wm, wn, acc);

    int i = lane & 15, g = lane >> 4;
#pragma unroll
    for (int nu = 0; nu < 2; ++nu) {
        int n = wn * 32 + nu * 16 + i;
        if (n < 48) {
            float bv = bias[n];
#pragma unroll
            for (int mu = 0; mu < 4; ++mu)
#pragma unroll
                for (int rr = 0; rr < 4; ++rr) {
                    size_t m = (size_t)mbase + wm * 64 + mu * 16 + g * 4 + rr;
                    float v = lrelu_f(acc[mu][nu][rr] + bv);
                    unsigned short h = bf16rn(v);
                    t1s[m * 128 + n] = h;
                    t1s[m * 128 + 64 + n] = bf16rn(v - bf16tof(h));
                }
        }
    }
    if (tid < 128) {   // zero ci pads 48..63 (hi & lo)
        size_t m = (size_t)mbase + tid;
        bfrag z = {0, 0, 0, 0, 0, 0, 0, 0};
        *(bfrag*)(t1s + m * 128 + 48)  = z;
        *(bfrag*)(t1s + m * 128 + 56)  = z;
        *(bfrag*)(t1s + m * 128 + 112) = z;
        *(bfrag*)(t1s + m * 128 + 120) = z;
    }
}

// conv2: 3x3 48->48 as MFMA shifted-GEMM.  block = 128 pixels (half image row).
// XCD row-banding: each XCD owns a contiguous 32-row band per image -> halo re-reads are L2 hits.
__global__ __launch_bounds__(256) void conv2_mfma_kernel(const unsigned short* __restrict__ t1s,
    const unsigned short* __restrict__ c2w2, const float* __restrict__ bias,
    unsigned short* __restrict__ t2s)
{
    __shared__ __align__(16) short a_s[130 * 128];   // 33,280 B
    int bid = blockIdx.x;                 // 1024 = 8 xcd * 128
    int xcd = bid & 7;
    int j = bid >> 3;                     // [0,128)
    int half = j & 1;
    int rl = (j >> 1) & 31;
    int b = j >> 6;
    int r = xcd * 32 + rl;
    int c0 = half * 128;
    int tid = threadIdx.x;
    int lane = tid & 63, wid = tid >> 6;  // 4 waves, wave = 32 pixels
    int i = lane & 15, g = lane >> 4;
    facc zero = {0.f, 0.f, 0.f, 0.f};
    facc acc[2][3];
#pragma unroll
    for (int mu = 0; mu < 2; ++mu)
#pragma unroll
        for (int nu = 0; nu < 3; ++nu) acc[mu][nu] = zero;

    for (int dy = 0; dy < 3; ++dy) {
        int grow = r + dy - 1;
        bool rowok = (grow >= 0 && grow < 256);
        for (int idx = tid; idx < 130 * 16; idx += 256) {
            int j2 = idx >> 4, ch = idx & 15;
            int gc = c0 - 1 + j2;
            bfrag v = {0, 0, 0, 0, 0, 0, 0, 0};
            if (rowok && gc >= 0 && gc < 256) {
                size_t gpix = ((size_t)b * 256 + grow) * 256 + gc;
                v = *(const bfrag*)(t1s + gpix * 128 + ch * 8);
            }
            *(bfrag*)&a_s[j2 * 128 + ((ch ^ (j2 & 7)) * 8)] = v;
        }
        __syncthreads();
#pragma unroll
        for (int dx = 0; dx < 3; ++dx) {
            const unsigned short* wb = c2w2 + (size_t)(dy * 3 + dx) * 48 * 128;
#pragma unroll
            for (int h = 0; h < 2; ++h) {
                bfrag ah[2], al[2], bh[3], bl[3];
#pragma unroll
                for (int mu = 0; mu < 2; ++mu) {
                    int j2 = wid * 32 + mu * 16 + i + dx;   // halo pixel index
                    int chi = (h * 4 + g) ^ (j2 & 7);
                    int clo = (8 + h * 4 + g) ^ (j2 & 7);
                    ah[mu] = *(const bfrag*)&a_s[j2 * 128 + chi * 8];
                    al[mu] = *(const bfrag*)&a_s[j2 * 128 + clo * 8];
                }
#pragma unroll
                for (int nu = 0; nu < 3; ++nu) {
                    const unsigned short* wp = wb + (size_t)(nu * 16 + i) * 128 + h * 32 + g * 8;
                    bh[nu] = *(const bfrag*)(wp);
                    bl[nu] = *(const bfrag*)(wp + 64);
                }
#pragma unroll
                for (int mu = 0; mu < 2; ++mu)
#pragma unroll
                    for (int nu = 0; nu < 3; ++nu) {
                        acc[mu][nu] = __builtin_amdgcn_mfma_f32_16x16x32_bf16(ah[mu], bh[nu], acc[mu][nu], 0, 0, 0);
                        acc[mu][nu] = __builtin_amdgcn_mfma_f32_16x16x32_bf16(ah[mu], bl[nu], acc[mu][nu], 0, 0, 0);
                        acc[mu][nu] = __builtin_amdgcn_mfma_f32_16x16x32_bf16(al[mu], bh[nu], acc[mu][nu], 0, 0, 0);
                    }
            }
        }
        __syncthreads();
    }
    // epilogue: bias + lrelu + split-pack -> t2s
#pragma unroll
    for (int nu = 0; nu < 3; ++nu) {
        int n = nu * 16 + i;
        float bv = bias[n];
#pragma unroll
        for (int mu = 0; mu < 2; ++mu)
#pragma unroll
            for (int rr = 0; rr < 4; ++rr) {
                int lp = wid * 32 + mu * 16 + g * 4 + rr;
                size_t gpix = ((size_t)b * 256 + r) * 256 + (c0 + lp);
                float v = lrelu_f(acc[mu][nu][rr] + bv);
                unsigned short h = bf16rn(v);
                t2s[gpix * 128 + n] = h;
                t2s[gpix * 128 + 64 + n] = bf16rn(v - bf16tof(h));
            }
    }
    if (tid < 128) {   // zero ci pads 48..63
        size_t gpix = ((size_t)b * 256 + r) * 256 + (c0 + tid);
        bfrag z = {0, 0, 0, 0, 0, 0, 0, 0};
        *(bfrag*)(t2s + gpix * 128 + 48)  = z;
        *(bfrag*)(t2s + gpix * 128 + 56)  = z;
        *(bfrag*)(t2s + gpix * 128 + 112) = z;
        *(bfrag*)(t2s + gpix * 128 + 120) = z;
    }
}

// qv = (t2 @ c3_w^T + c3_b) * (x @ lin_w^T + lin_b)   [MFMA, BN=128, XCD-swizzled]
// dual accumulator (252 regs) -> 2 waves/SIMD is the hard cap.
__global__ __launch_bounds__(256) void qv_mfma_kernel(const unsigned short* __restrict__ xs2,
    const unsigned short* __restrict__ lin_w2, const float* __restrict__ lin_b,
    const unsigned short* __restrict__ t2s, const unsigned short* __restrict__ c3_w2,
    const float* __restrict__ c3_b, float* __restrict__ qv)
{
    __shared__ __align__(16) short lds_a[128 * 72];
    __shared__ __align__(16) short lds_w[128 * 72];
    int tid = threadIdx.x;
    int lane = tid & 63, wid = tid >> 6;
    int wm = wid >> 1, wn = wid & 1;
    // XCD swizzle: co-locate both N-halves of an M-block on one XCD (A fetched once per XCD)
    int bid = blockIdx.y * 2 + blockIdx.x;        // 0..2047, x fastest
    int xcd = bid & 7, j = bid >> 3;              // j 0..255
    int mbase = (xcd * 128 + (j >> 1)) * 128;
    int nbase = (j & 1) * 128;
    facc zero = {0.f, 0.f, 0.f, 0.f};
    facc acc1[4][4], acc2[4][4];
#pragma unroll
    for (int mu = 0; mu < 4; ++mu)
#pragma unroll
        for (int nu = 0; nu < 4; ++nu) { acc1[mu][nu] = zero; acc2[mu][nu] = zero; }

    mfma_kpass3(xs2, 512, lin_w2, 512, 8, mbase, nbase, lds_a, lds_w, tid, wm, wn, acc1);
    mfma_kpass3(t2s, 128, c3_w2, 128, 2, mbase, nbase, lds_a, lds_w, tid, wm, wn, acc2);

    int i = lane & 15, g = lane >> 4;
#pragma unroll
    for (int nu = 0; nu < 4; ++nu) {
        int n = nbase + wn * 64 + nu * 16 + i;
        if (n < 240) {
            float lb = lin_b[n], cb = c3_b[n];
#pragma unroll
            for (int mu = 0; mu < 4; ++mu)
#pragma unroll
                for (int rr = 0; rr < 4; ++rr) {
                    size_t m = (size_t)mbase + wm * 64 + mu * 16 + g * 4 + rr;
                    qv[m * 240 + n] = (acc2[mu][nu][rr] + cb) * (acc1[mu][nu][rr] + lb);
                }
        }
    }
}

// proj: out = cat2 @ proj_w^T + proj_b   [MFMA, BN=128, XCD-swizzled]
// launch_bounds(256,3): single 64-AGPR acc -> cap regs for 3 waves/SIMD
__global__ __launch_bounds__(256, 3) void proj_mfma_kernel(const unsigned short* __restrict__ cat2,
    const unsigned short* __restrict__ proj_w2, const float* __restrict__ bias,
    float* __restrict__ out)
{
    __shared__ __align__(16) short lds_a[128 * 72];
    __shared__ __align__(16) short lds_w[128 * 72];
    int tid = threadIdx.x;
    int lane = tid & 63, wid = tid >> 6;
    int wm = wid >> 1, wn = wid & 1;
    int bid = blockIdx.y * 2 + blockIdx.x;
    int xcd = bid & 7, j = bid >> 3;
    int mbase = (xcd * 128 + (j >> 1)) * 128;
    int nbase = (j & 1) * 128;
    facc zero = {0.f, 0.f, 0.f, 0.f};
    facc acc[4][4];
#pragma unroll
    for (int mu = 0; mu < 4; ++mu)
#pragma unroll
        for (int nu = 0; nu < 4; ++nu) acc[mu][nu] = zero;

    mfma_kpass3(cat2, 512, proj_w2, 512, 8, mbase, nbase, lds_a, lds_w, tid, wm, wn, acc);

    int i = lane & 15, g = lane >> 4;
#pragma unroll
    for (int nu = 0; nu < 4; ++nu) {
        int n = nbase + wn * 64 + nu * 16 + i;
        if (n < 240) {
            float bv = bias[n];
#pragma unroll
            for (int mu = 0; mu < 4; ++mu)
#pragma unroll
                for (int rr = 0; rr < 4; ++rr) {
                    size_t m = (size_t)mbase + wm * 64 + mu * 16 + g * 4 + rr;
                    out[m * 240 + n] = acc[mu][nu][rr] + bv;
                }
        }
    }
}

// spatial correlation: per (window, head) -> cat2 channels [n*20, n*20+20) split-bf16
// XCD swizzle: all 6 heads of a window on one XCD.
// v_s staging ELIMINATED: vs_s built directly from qv global reads (L2-resident window
// slice via XCD affinity).  LDS 25.6 KB -> 5.1 KB => occupancy cap moves to VGPR.
__global__ __launch_bounds__(256) void xs_kernel(const float* __restrict__ qv,
    const float* __restrict__ rpb_t, const float* __restrict__ sl_w,
    const float* __restrict__ sl_b, unsigned short* __restrict__ cat2)
{
    __shared__ __align__(16) float vs_s[64 * 20];
    int bid = blockIdx.x;                 // 3072 = 8 xcd * 64 windows * 6 heads
    int xcd = bid & 7;
    int j = bid >> 3;                     // 0..383
    int wl = j / 6;
    int n = j - wl * 6;
    int w = xcd * 64 + wl;
    int tid = threadIdx.x;
    int l = tid;
    size_t pix = (size_t)pix_of(w, l);
    const float* qp = qv + pix * 240 + n * 20;
    float qr[20];
#pragma unroll
    for (int h4 = 0; h4 < 5; ++h4)
        *(float4*)&qr[h4 * 4] = *(const float4*)(qp + h4 * 4);          // q -> regs
    float slw0 = sl_w[0], slw1 = sl_w[1], slw2 = sl_w[2], slw3 = sl_w[3];
    float slb = sl_b[0];
    // build vs_s[k*20+hd] straight from qv (v channels 120 + n*20 + hd)
    for (int idx = tid; idx < 1280; idx += 256) {
        int k = idx / 20, hd = idx % 20;
        int a = k >> 3, c = k & 7;
        int l00 = a * 32 + c * 2;     // (a*2)*16 + c*2
        int off = 120 + n * 20 + hd;
        float vsum = slb
                   + slw0 * qv[(size_t)pix_of(w, l00 + 0)  * 240 + off]
                   + slw1 * qv[(size_t)pix_of(w, l00 + 1)  * 240 + off]
                   + slw2 * qv[(size_t)pix_of(w, l00 + 16) * 240 + off]
                   + slw3 * qv[(size_t)pix_of(w, l00 + 17) * 240 + off];
        vs_s[idx] = vsum;
    }
    __syncthreads();
    const float* rp = rpb_t + (size_t)n * 16384 + l;
    float acc[20];
#pragma unroll
    for (int hd = 0; hd < 20; ++hd) acc[hd] = 0.f;
    // fused: one pass over k; vr loaded once, used for dot AND PV update
#pragma unroll
    for (int k = 0; k < 64; ++k) {
        float vr[20];
#pragma unroll
        for (int h4 = 0; h4 < 5; ++h4)
            *(float4*)&vr[h4 * 4] = *(const float4*)&vs_s[k * 20 + h4 * 4];
        float s0 = 0.f, s1 = 0.f, s2 = 0.f, s3 = 0.f;
#pragma unroll
        for (int hd = 0; hd < 20; hd += 4) {
            s0 += qr[hd + 0] * vr[hd + 0];
            s1 += qr[hd + 1] * vr[hd + 1];
            s2 += qr[hd + 2] * vr[hd + 2];
            s3 += qr[hd + 3] * vr[hd + 3];
        }
        float cc = (s0 + s1 + s2 + s3) * (1.f / 20.f) + rp[(size_t)k * 256];
#pragma unroll
        for (int hd = 0; hd < 20; ++hd) acc[hd] += cc * vr[hd];
    }
    unsigned short* op = cat2 + pix * 512 + n * 20;
#pragma unroll
    for (int h4 = 0; h4 < 5; ++h4) {
        us4 h, lo;
#pragma unroll
        for (int e = 0; e < 4; ++e) {
            float v = acc[h4 * 4 + e];
            unsigned short hh = bf16rn(v);
            h[e] = hh;
            lo[e] = bf16rn(v - bf16tof(hh));
        }
        *(us4*)(op + h4 * 4) = h;
        *(us4*)(op + 256 + h4 * 4) = lo;
    }
    if (n == 0) {   // zero K-pad channels 240..255 (hi and lo)
        bfrag z = {0, 0, 0, 0, 0, 0, 0, 0};
        unsigned short* zp = cat2 + pix * 512;
        *(bfrag*)(zp + 240) = z;  *(bfrag*)(zp + 248) = z;
        *(bfrag*)(zp + 496) = z;  *(bfrag*)(zp + 504) = z;
    }
}

// channel correlation phase 1: G[w][d][c] = sum_l vc[l,d]*qc[l,c]   (K=256)
// XCD swizzle: window w -> XCD w/64 (consistent with xs/xc)
__global__ __launch_bounds__(256) void corrc_kernel(const float* __restrict__ qv,
                                                    float* __restrict__ G)
{
    __shared__ __align__(16) float vc_s[16 * 124];
    __shared__ __align__(16) float qc_s[16 * 124];
    int bid = blockIdx.x;                 // 512 = 8 * 64
    int w = (bid & 7) * 64 + (bid >> 3);
    int tid = threadIdx.x, ty = tid >> 4, tx = tid & 15;
    float acc[8][8] = {};
    for (int l0 = 0; l0 < 256; l0 += 16) {
        for (int idx = tid; idx < 480; idx += 256) {
            int k = idx / 30, c4 = idx % 30;
            size_t pix = (size_t)pix_of(w, l0 + k);
            const float* qp = qv + pix * 240;
            *(float4*)&qc_s[k * 124 + c4 * 4] = *(const float4*)(qp + c4 * 4);
            *(float4*)&vc_s[k * 124 + c4 * 4] = *(const float4*)(qp + 120 + c4 * 4);
        }
        __syncthreads();
#pragma unroll
        for (int k = 0; k < 16; ++k) {
            float4 a0 = *(const float4*)&vc_s[k * 124 + ty * 8];
            float4 a1 = *(const float4*)&vc_s[k * 124 + ty * 8 + 4];
            float4 b0 = *(const float4*)&qc_s[k * 124 + tx * 8];
            float4 b1 = *(const float4*)&qc_s[k * 124 + tx * 8 + 4];
            float av[8] = {a0.x, a0.y, a0.z, a0.w, a1.x, a1.y, a1.z, a1.w};
            float bv[8] = {b0.x, b0.y, b0.z, b0.w, b1.x, b1.y, b1.z, b1.w};
#pragma unroll
            for (int i = 0; i < 8; ++i)
#pragma unroll
                for (int j = 0; j < 8; ++j) acc[i][j] += av[i] * bv[j];
        }
        __syncthreads();
    }
    float* gp = G + (size_t)w * 14400;
#pragma unroll
    for (int i = 0; i < 8; ++i) {
        int d = ty * 8 + i;
        if (d < 120) {
#pragma unroll
            for (int j4 = 0; j4 < 2; ++j4) {
                int c = tx * 8 + j4 * 4;
                if (c < 120) {
                    float4 o;
                    o.x = acc[i][j4 * 4 + 0]; o.y = acc[i][j4 * 4 + 1];
                    o.z = acc[i][j4 * 4 + 2]; o.w = acc[i][j4 * 4 + 3];
                    *(float4*)(gp + (size_t)d * 120 + c) = o;
                }
            }
        }
    }
}

// channel correlation phase 2: x_c[l,c] = (1/256) sum_d vc[l,d]*G[d,c]  -> cat2 ch 120..239
// XCD swizzle: window w -> XCD w/64; both mh halves co-located & adjacent.
__global__ __launch_bounds__(256) void xc_kernel(const float* __restrict__ qv,
    const float* __restrict__ G, unsigned short* __restrict__ cat2)
{
    __shared__ __align__(16) float a_s[8 * 132];
    __shared__ __align__(16) float b_s[8 * 124];
    int bid = blockIdx.x;                 // 1024 = 8 * 64 * 2
    int xcd = bid & 7, j = bid >> 3;      // j 0..127
    int w = xcd * 64 + (j >> 1);
    int mh = j & 1;
    int tid = threadIdx.x, ty = tid >> 4, tx = tid & 15;
    const float* gp = G + (size_t)w * 14400;
    float acc[8][8] = {};
    for (int k0 = 0; k0 < 120; k0 += 8) {
        {
            int lloc = tid >> 1;
            int kk = (tid & 1) * 4;
            int l = mh * 128 + lloc;
            size_t pix = (size_t)pix_of(w, l);
            float4 v = *(const float4*)(qv + pix * 240 + 120 + k0 + kk);
            a_s[(kk + 0) * 132 + lloc] = v.x;
            a_s[(kk + 1) * 132 + lloc] = v.y;
            a_s[(kk + 2) * 132 + lloc] = v.z;
            a_s[(kk + 3) * 132 + lloc] = v.w;
        }
        if (tid < 240) {
            int k = tid / 30, c4 = tid % 30;
            *(float4*)&b_s[k * 124 + c4 * 4] =
                *(const float4*)(gp + (size_t)(k0 + k) * 120 + c4 * 4);
        }
        __syncthreads();
#pragma unroll
        for (int k = 0; k < 8; ++k) {
            float4 a0 = *(const float4*)&a_s[k * 132 + ty * 8];
            float4 a1 = *(const float4*)&a_s[k * 132 + ty * 8 + 4];
            float4 b0 = *(const float4*)&b_s[k * 124 + tx * 8];
            float4 b1 = *(const float4*)&b_s[k * 124 + tx * 8 + 4];
            float av[8] = {a0.x, a0.y, a0.z, a0.w, a1.x, a1.y, a1.z, a1.w};
            float bv[8] = {b0.x, b0.y, b0.z, b0.w, b1.x, b1.y, b1.z, b1.w};
#pragma unroll
            for (int i = 0; i < 8; ++i)
#pragma unroll
                for (int j2 = 0; j2 < 8; ++j2) acc[i][j2] += av[i] * bv[j2];
        }
        __syncthreads();
    }
#pragma unroll
    for (int i = 0; i < 8; ++i) {
        int l = mh * 128 + ty * 8 + i;
        size_t pix = (size_t)pix_of(w, l);
        unsigned short* op = cat2 + pix * 512;
#pragma unroll
        for (int j4 = 0; j4 < 2; ++j4) {
            int c = tx * 8 + j4 * 4;
            if (c < 120) {
                us4 h, lo;
#pragma unroll
                for (int e = 0; e < 4; ++e) {
                    float v = acc[i][j4 * 4 + e] * (1.f / 256.f);
                    unsigned short hh = bf16rn(v);
                    h[e] = hh;
                    lo[e] = bf16rn(v - bf16tof(hh));
                }
                *(us4*)(op + 120 + c) = h;
                *(us4*)(op + 256 + 120 + c) = lo;
            }
        }
    }
}

extern "C" void kernel_launch(void* const* d_in, const int* in_sizes, int n_in,
                              void* d_out, int out_size, void* d_ws, size_t ws_size,
                              hipStream_t stream)
{
    (void)in_sizes; (void)n_in; (void)out_size;
    const float* x     = (const float*)d_in[0];
    const float* c1_w  = (const float*)d_in[1];
    const float* c1_b  = (const float*)d_in[2];
    const float* c2_w  = (const float*)d_in[3];
    const float* c2_b  = (const float*)d_in[4];
    const float* c3_w  = (const float*)d_in[5];
    const float* c3_b  = (const float*)d_in[6];
    const float* lin_w = (const float*)d_in[7];
    const float* lin_b = (const float*)d_in[8];
    const float* sl_w  = (const float*)d_in[9];
    const float* sl_b  = (const float*)d_in[10];
    const float* pp_w  = (const float*)d_in[11];
    const float* pp_b  = (const float*)d_in[12];
    const float* ln1_g = (const float*)d_in[13];
    const float* ln1_b = (const float*)d_in[14];
    const float* p1_w  = (const float*)d_in[15];
    const float* p1_b  = (const float*)d_in[16];
    const float* ln2_g = (const float*)d_in[17];
    const float* ln2_b = (const float*)d_in[18];
    const float* p2_w  = (const float*)d_in[19];
    const float* p2_b  = (const float*)d_in[20];
    const float* ln3_g = (const float*)d_in[21];
    const float* ln3_b = (const float*)d_in[22];
    const float* p3_w  = (const float*)d_in[23];
    const float* p3_b  = (const float*)d_in[24];
    const float* proj_w = (const float*)d_in[25];
    const float* proj_b = (const float*)d_in[26];

    float* ws = (float*)d_ws;
    // ---------------- workspace layout (float units) ----------------
    // overlays (timeline-checked):
    //   t1s (8,388,608 fl) = head of qvb  [t1s dead after conv2; qvb written by qv]
    //   G   (7,372,800 fl) = head of t2s  [t2s dead after qv; G written by corrc after qv]
    //   cat2 = xs2                         [xs2 dead after qv]
    float* pos3   = ws;                                           // -> 8192
    float* rpb_t  = ws + 8192;                                    // -> 106496
    unsigned short* lin_w2  = (unsigned short*)(ws + 106496);     // 256x512 sh -> 172032
    unsigned short* c3_w2   = (unsigned short*)(ws + 172032);     // 256x128 sh -> 188416
    unsigned short* proj_w2 = (unsigned short*)(ws + 188416);     // 256x512 sh -> 253952
    unsigned short* c1_w2   = (unsigned short*)(ws + 253952);     // 128x512 sh -> 286720
    unsigned short* c2w2    = (unsigned short*)(ws + 286720);     // 432x128 sh -> 314368
    unsigned short* t2s = (unsigned short*)(ws + 314368);         // 8388608 fl -> 8702976
    float* G      = ws + 314368;                                  // overlays t2s
    unsigned short* xs2 = (unsigned short*)(ws + 8702976);        // 33554432 fl -> 42257408
    unsigned short* cat2 = xs2;                                   // overlays xs2
    float* qvb    = ws + 42257408;                                // 31457280 fl -> 73714688
    unsigned short* t1s = (unsigned short*)qvb;                   // overlays qvb head
    const size_t required = (size_t)73714688 * 4;                 // 294.9 MB
    if (ws_size < required) return;

    pack_all_kernel<<<115, 256, 0, stream>>>(lin_w, proj_w, c3_w, c1_w, c2_w,
                                             lin_w2, proj_w2, c3_w2, c1_w2, c2w2);
    split_x_kernel<<<16384, 256, 0, stream>>>(x, xs2);
    prep_pos_kernel<<<4, 256, 0, stream>>>(pp_w, pp_b, ln1_g, ln1_b, p1_w, p1_b,
                                           ln2_g, ln2_b, p2_w, p2_b, ln3_g, ln3_b,
                                           p3_w, p3_b, pos3);
    rpb_kernel<<<384, 256, 0, stream>>>(pos3, rpb_t);
    conv1_mfma_kernel<<<1024, 256, 0, stream>>>(xs2, c1_w2, c1_b, t1s);
    conv2_mfma_kernel<<<1024, 256, 0, stream>>>(t1s, c2w2, c2_b, t2s);
    qv_mfma_kernel<<<dim3(2, 1024), 256, 0, stream>>>(xs2, lin_w2, lin_b, t2s, c3_w2, c3_b, qvb);
    xs_kernel<<<3072, 256, 0, stream>>>(qvb, rpb_t, sl_w, sl_b, cat2);
    corrc_kernel<<<512, 256, 0, stream>>>(qvb, G);
    xc_kernel<<<1024, 256, 0, stream>>>(qvb, G, cat2);
    proj_mfma_kernel<<<dim3(2, 1024), 256, 0, stream>>>(cat2, proj_w2, proj_b, (float*)d_out);
}

// Round 15
// 553.321 us; speedup vs baseline: 1.0205x; 1.0205x over previous
//
#include <hip/hip_runtime.h>
#include <math.h>

#define NPIX 131072   // 2*256*256

typedef __attribute__((ext_vector_type(8))) short bfrag;
typedef __attribute__((ext_vector_type(4))) float facc;
typedef __attribute__((ext_vector_type(4))) unsigned short us4;

__device__ __forceinline__ float lrelu_f(float x) { return x >= 0.f ? x : 0.2f * x; }

// window w (0..511): b=w>>8, wi=(w>>4)&15, wj=w&15 ; l (0..255): i=l>>4, j=l&15
__device__ __forceinline__ int pix_of(int w, int l) {
    int b = w >> 8, wi = (w >> 4) & 15, wj = w & 15;
    return ((((b << 4) + wi) * 16 + (l >> 4)) << 8) + (wj << 4) + (l & 15);
}

// ---- bf16 split helpers (round-to-nearest-even) ----
__device__ __forceinline__ unsigned short bf16rn(float f) {
    unsigned u = __builtin_bit_cast(unsigned, f);
    u += 0x7FFFu + ((u >> 16) & 1u);
    return (unsigned short)(u >> 16);
}
__device__ __forceinline__ float bf16tof(unsigned short h) {
    unsigned u = ((unsigned)h) << 16;
    return __builtin_bit_cast(float, u);
}

// ---------------- split_x body: fp32 -> packed [hi|lo] bf16 ----------------
// xs2 row: shorts [0,256) = hi(k), [256,512) = lo(k); k>=240 zero.
__device__ __forceinline__ void split_x_body(const float* __restrict__ x,
                                             unsigned short* __restrict__ xs2, int idx)
{
    int row = idx >> 5;
    int k = (idx & 31) * 8;
    float v[8];
    if (k < 240) {
        float4 a = *(const float4*)(x + (size_t)row * 240 + k);
        float4 b = *(const float4*)(x + (size_t)row * 240 + k + 4);
        v[0] = a.x; v[1] = a.y; v[2] = a.z; v[3] = a.w;
        v[4] = b.x; v[5] = b.y; v[6] = b.z; v[7] = b.w;
    } else {
#pragma unroll
        for (int e = 0; e < 8; ++e) v[e] = 0.f;
    }
    bfrag hi, lo;
#pragma unroll
    for (int e = 0; e < 8; ++e) {
        unsigned short h = bf16rn(v[e]);
        hi[e] = (short)h;
        lo[e] = (short)bf16rn(v[e] - bf16tof(h));
    }
    unsigned short* dst = xs2 + (size_t)row * 512 + k;
    *(bfrag*)(dst) = hi;
    *(bfrag*)(dst + 256) = lo;
}

// generic weight pack body: src [rows][K] fp32 -> dst [rows_pad][2*KPAD] shorts (zero padded)
__device__ __forceinline__ void pack_w_body(const float* __restrict__ src,
                                            int rows, int K,
                                            unsigned short* __restrict__ dst,
                                            int total8, int KPAD, int idx)
{
    if (idx >= total8) return;
    int kper = KPAD >> 3;
    int row = idx / kper;
    int k = (idx - row * kper) * 8;
    float v[8];
#pragma unroll
    for (int e = 0; e < 8; ++e) {
        int kk = k + e;
        v[e] = (row < rows && kk < K) ? src[(size_t)row * K + kk] : 0.f;
    }
    bfrag hi, lo;
#pragma unroll
    for (int e = 0; e < 8; ++e) {
        unsigned short h = bf16rn(v[e]);
        hi[e] = (short)h;
        lo[e] = (short)bf16rn(v[e] - bf16tof(h));
    }
    unsigned short* d = dst + (size_t)row * 2 * KPAD + k;
    *(bfrag*)(d) = hi;
    *(bfrag*)(d + KPAD) = lo;
}

// c2 weights body -> c2w2[tap][n][ hi64 | lo64 ]  (tap = ky*3+kx; ci pad 48..63 = 0)
__device__ __forceinline__ void pack_c2w_body(const float* __restrict__ c2_w,
                                              unsigned short* __restrict__ c2w2, int idx)
{
    if (idx >= 6912) return;
    int rowid = idx >> 4;          // tap*48 + n
    int c = idx & 15;
    int tap = rowid / 48, n = rowid - tap * 48;
    int ty = tap / 3, tx = tap - ty * 3;
    int lohalf = c >> 3;
    int cbase = (c & 7) * 8;
    bfrag outv;
#pragma unroll
    for (int e = 0; e < 8; ++e) {
        int ci = cbase + e;
        float v = (ci < 48) ? c2_w[(((size_t)n * 48 + ci) * 3 + ty) * 3 + tx] : 0.f;
        unsigned short h = bf16rn(v);
        outv[e] = (short)(lohalf ? bf16rn(v - bf16tof(h)) : h);
    }
    *(bfrag*)(c2w2 + (size_t)rowid * 128 + c * 8) = outv;
}

// merged pre-pass kernel: weight packs (blocks 0..114) + split_x (blocks 115..16498)
__global__ __launch_bounds__(256) void pack_all_kernel(
    const float* __restrict__ lin_w, const float* __restrict__ proj_w,
    const float* __restrict__ c3_w, const float* __restrict__ c1_w,
    const float* __restrict__ c2_w, const float* __restrict__ x,
    unsigned short* __restrict__ lin_w2, unsigned short* __restrict__ proj_w2,
    unsigned short* __restrict__ c3_w2, unsigned short* __restrict__ c1_w2,
    unsigned short* __restrict__ c2w2, unsigned short* __restrict__ xs2)
{
    int blk = blockIdx.x, tid = threadIdx.x;
    if (blk < 32)       pack_w_body(lin_w, 240, 240, lin_w2, 8192, 256, blk * 256 + tid);
    else if (blk < 64)  pack_w_body(proj_w, 240, 240, proj_w2, 8192, 256, (blk - 32) * 256 + tid);
    else if (blk < 72)  pack_w_body(c3_w, 240, 48, c3_w2, 2048, 64, (blk - 64) * 256 + tid);
    else if (blk < 88)  pack_w_body(c1_w, 48, 240, c1_w2, 4096, 256, (blk - 72) * 256 + tid);
    else if (blk < 115) pack_c2w_body(c2_w, c2w2, (blk - 88) * 256 + tid);
    else                split_x_body(x, xs2, (blk - 115) * 256 + tid);
}

// ---------------- prep: DynamicPosBias MLP ----------------
__device__ __forceinline__ void ln_relu15(const float* h, float* r,
                                          const float* __restrict__ g,
                                          const float* __restrict__ b) {
    float m = 0.f;
#pragma unroll
    for (int f = 0; f < 15; ++f) m += h[f];
    m *= (1.f / 15.f);
    float v = 0.f;
#pragma unroll
    for (int f = 0; f < 15; ++f) { float d = h[f] - m; v += d * d; }
    float rs = rsqrtf(v * (1.f / 15.f) + 1e-5f);
#pragma unroll
    for (int f = 0; f < 15; ++f) {
        float xx = (h[f] - m) * rs * g[f] + b[f];
        r[f] = xx > 0.f ? xx : 0.f;
    }
}

__device__ __forceinline__ void lin15(const float* r, float* h,
                                      const float* __restrict__ w,
                                      const float* __restrict__ b) {
#pragma unroll
    for (int o = 0; o < 15; ++o) {
        float s = b[o];
#pragma unroll
        for (int g = 0; g < 15; ++g) s += r[g] * w[o * 15 + g];
        h[o] = s;
    }
}

__global__ __launch_bounds__(256) void prep_pos_kernel(
    const float* __restrict__ pp_w, const float* __restrict__ pp_b,
    const float* __restrict__ ln1_g, const float* __restrict__ ln1_b,
    const float* __restrict__ p1_w, const float* __restrict__ p1_b,
    const float* __restrict__ ln2_g, const float* __restrict__ ln2_b,
    const float* __restrict__ p2_w, const float* __restrict__ p2_b,
    const float* __restrict__ ln3_g, const float* __restrict__ ln3_b,
    const float* __restrict__ p3_w, const float* __restrict__ p3_b,
    float* __restrict__ pos3)
{
    int idx = blockIdx.x * 256 + threadIdx.x;
    if (idx >= 961) return;
    float h[15], r[15];
    float in0 = (float)(idx / 31) - 15.f;
    float in1 = (float)(idx % 31) - 15.f;
#pragma unroll
    for (int f = 0; f < 15; ++f) h[f] = in0 * pp_w[2 * f] + in1 * pp_w[2 * f + 1] + pp_b[f];
    ln_relu15(h, r, ln1_g, ln1_b);
    lin15(r, h, p1_w, p1_b);
    ln_relu15(h, r, ln2_g, ln2_b);
    lin15(r, h, p2_w, p2_b);
    ln_relu15(h, r, ln3_g, ln3_b);
#pragma unroll
    for (int o = 0; o < 6; ++o) {
        float s = p3_b[o];
#pragma unroll
        for (int g = 0; g < 15; ++g) s += r[g] * p3_w[o * 15 + g];
        pos3[idx * 6 + o] = s;
    }
}

// rpb_t[n][k][l]  (n<6, k<64 base-window key, l<256 query pos)
__global__ __launch_bounds__(256) void rpb_kernel(const float* __restrict__ pos3,
                                                  float* __restrict__ rpb_t)
{
    int out = blockIdx.x * 256 + threadIdx.x;   // < 98304
    int n = out >> 14;
    int k = (out >> 8) & 63;
    int l = out & 255;
    int a = k >> 3, c = k & 7;
    int i1 = l >> 4, j1 = l & 15;
    float s = 0.f;
#pragma unroll
    for (int bb = 0; bb < 2; ++bb)
#pragma unroll
        for (int d = 0; d < 2; ++d) {
            int i2 = a * 2 + bb, j2 = c * 2 + d;
            int rpi = (i1 - i2 + 15) * 31 + (j1 - j2 + 15);
            s += pos3[rpi * 6 + n];
        }
    rpb_t[out] = s * 0.25f;
}

// ---------------- MFMA split-bf16 NT GEMM core, BM=128 BN=128 (R11 known-good) ----------------
// LDS row: [32 hi][32 lo] shorts, stride 72. Frag: lane l -> row (l&15), chunk (l>>4)*8.
__device__ __forceinline__ void mfma_kpass3(const unsigned short* __restrict__ A2, int lda2,
                                            const unsigned short* __restrict__ W2, int ldw2,
                                            int ksteps, int mbase, int nbase,
                                            short* lds_a, short* lds_w,
                                            int tid, int wm, int wn,
                                            facc acc[4][4])
{
    int lane = tid & 63;
    int i = lane & 15, g = lane >> 4;
    int kpa = lda2 >> 1, kpw = ldw2 >> 1;
    for (int s = 0; s < ksteps; ++s) {
        int k0 = s * 32;
        {   // stage A: 128 rows x (32 hi + 32 lo) shorts
            int r = tid >> 1, h16 = (tid & 1) * 16;
            const unsigned short* src = A2 + (size_t)(mbase + r) * lda2 + k0 + h16;
            bfrag h0 = *(const bfrag*)(src);
            bfrag h1 = *(const bfrag*)(src + 8);
            bfrag l0 = *(const bfrag*)(src + kpa);
            bfrag l1 = *(const bfrag*)(src + kpa + 8);
            short* dst = lds_a + r * 72 + h16;
            *(bfrag*)(dst)      = h0;  *(bfrag*)(dst + 8)  = h1;
            *(bfrag*)(dst + 32) = l0;  *(bfrag*)(dst + 40) = l1;
        }
        {   // stage W: 128 rows x (32 hi + 32 lo) shorts; thread: row + half
            int r = tid >> 1, half = tid & 1;
            const unsigned short* src = W2 + (size_t)(nbase + r) * ldw2 + half * kpw + k0;
            bfrag v0 = *(const bfrag*)(src);
            bfrag v1 = *(const bfrag*)(src + 8);
            bfrag v2 = *(const bfrag*)(src + 16);
            bfrag v3 = *(const bfrag*)(src + 24);
            short* dst = lds_w + r * 72 + half * 32;
            *(bfrag*)(dst)      = v0;  *(bfrag*)(dst + 8)  = v1;
            *(bfrag*)(dst + 16) = v2;  *(bfrag*)(dst + 24) = v3;
        }
        __syncthreads();
        bfrag ah[4], al[4], bh[4], bl[4];
#pragma unroll
        for (int mu = 0; mu < 4; ++mu) {
            const short* p = lds_a + (wm * 64 + mu * 16 + i) * 72 + g * 8;
            ah[mu] = *(const bfrag*)(p);
            al[mu] = *(const bfrag*)(p + 32);
        }
#pragma unroll
        for (int nu = 0; nu < 4; ++nu) {
            const short* p = lds_w + (wn * 64 + nu * 16 + i) * 72 + g * 8;
            bh[nu] = *(const bfrag*)(p);
            bl[nu] = *(const bfrag*)(p + 32);
        }
#pragma unroll
        for (int mu = 0; mu < 4; ++mu)
#pragma unroll
            for (int nu = 0; nu < 4; ++nu) {
                acc[mu][nu] = __builtin_amdgcn_mfma_f32_16x16x32_bf16(ah[mu], bh[nu], acc[mu][nu], 0, 0, 0);
                acc[mu][nu] = __builtin_amdgcn_mfma_f32_16x16x32_bf16(ah[mu], bl[nu], acc[mu][nu], 0, 0, 0);
                acc[mu][nu] = __builtin_amdgcn_mfma_f32_16x16x32_bf16(al[mu], bh[nu], acc[mu][nu], 0, 0, 0);
            }
        __syncthreads();
    }
}

// ---------------- BN=64 variant (conv1): simple 2-barrier loop, 4 waves = 2x2 ----------------
__device__ __forceinline__ void mfma_kpass_n64(const unsigned short* __restrict__ A2, int lda2,
                                               const unsigned short* __restrict__ W2, int ldw2,
                                               int ksteps, int mbase,
                                               short* lds_a, short* lds_w,
                                               int tid, int wm, int wn,
                                               facc acc[4][2])
{
    int lane = tid & 63;
    int i = lane & 15, g = lane >> 4;
    int kpa = lda2 >> 1, kpw = ldw2 >> 1;
    for (int s = 0; s < ksteps; ++s) {
        int k0 = s * 32;
        {   // stage A: 128 rows x (32 hi + 32 lo) shorts
            int r = tid >> 1, h16 = (tid & 1) * 16;
            const unsigned short* src = A2 + (size_t)(mbase + r) * lda2 + k0 + h16;
            bfrag h0 = *(const bfrag*)(src);
            bfrag h1 = *(const bfrag*)(src + 8);
            bfrag l0 = *(const bfrag*)(src + kpa);
            bfrag l1 = *(const bfrag*)(src + kpa + 8);
            short* dst = lds_a + r * 72 + h16;
            *(bfrag*)(dst)      = h0;  *(bfrag*)(dst + 8)  = h1;
            *(bfrag*)(dst + 32) = l0;  *(bfrag*)(dst + 40) = l1;
        }
        if (tid < 128) {   // stage W: 64 rows
            int r = tid >> 1, half = tid & 1;
            const unsigned short* src = W2 + (size_t)r * ldw2 + half * kpw + k0;
            bfrag v0 = *(const bfrag*)(src);
            bfrag v1 = *(const bfrag*)(src + 8);
            bfrag v2 = *(const bfrag*)(src + 16);
            bfrag v3 = *(const bfrag*)(src + 24);
            short* dst = lds_w + r * 72 + half * 32;
            *(bfrag*)(dst)      = v0;  *(bfrag*)(dst + 8)  = v1;
            *(bfrag*)(dst + 16) = v2;  *(bfrag*)(dst + 24) = v3;
        }
        __syncthreads();
        bfrag ah[4], al[4], bh[2], bl[2];
#pragma unroll
        for (int mu = 0; mu < 4; ++mu) {
            const short* p = lds_a + (wm * 64 + mu * 16 + i) * 72 + g * 8;
            ah[mu] = *(const bfrag*)(p);
            al[mu] = *(const bfrag*)(p + 32);
        }
#pragma unroll
        for (int nu = 0; nu < 2; ++nu) {
            const short* p = lds_w + (wn * 32 + nu * 16 + i) * 72 + g * 8;
            bh[nu] = *(const bfrag*)(p);
            bl[nu] = *(const bfrag*)(p + 32);
        }
#pragma unroll
        for (int mu = 0; mu < 4; ++mu)
#pragma unroll
            for (int nu = 0; nu < 2; ++nu) {
                acc[mu][nu] = __builtin_amdgcn_mfma_f32_16x16x32_bf16(ah[mu], bh[nu], acc[mu][nu], 0, 0, 0);
                acc[mu][nu] = __builtin_amdgcn_mfma_f32_16x16x32_bf16(ah[mu], bl[nu], acc[mu][nu], 0, 0, 0);
                acc[mu][nu] = __builtin_amdgcn_mfma_f32_16x16x32_bf16(al[mu], bh[nu], acc[mu][nu], 0, 0, 0);
            }
        __syncthreads();
    }
}

// conv1: t1s = split(lrelu(x @ c1_w^T + c1_b)) packed [hi64|lo64], N=48 (BN=64)
__global__ __launch_bounds__(256, 3) void conv1_mfma_kernel(const unsigned short* __restrict__ xs2,
    const unsigned short* __restrict__ c1_w2, const float* __restrict__ bias,
    unsigned short* __restrict__ t1s)
{
    __shared__ __align__(16) short lds_a[128 * 72];
    __shared__ __align__(16) short lds_w[64 * 72];
    int tid = threadIdx.x;
    int lane = tid & 63, wid = tid >> 6;
    int wm = wid >> 1, wn = wid & 1;
    int mbase = blockIdx.x * 128;
    facc zero = {0.f, 0.f, 0.f, 0.f};
    facc acc[4][2];
#pragma unroll
    for (int mu = 0; mu < 4; ++mu)
#pragma unroll
        for (int nu = 0; nu < 2; ++nu) acc[mu][nu] = zero;

    mfma_kpass_n64(xs2, 512, c1_w2, 512, 8, mbase, lds_a, lds_w, tid, wm, wn, acc);

    int i = lane & 15, g = lane >> 4;
#pragma unroll
    for (int nu = 0; nu < 2; ++nu) {
        int n = wn * 32 + nu * 16 + i;
        if (n < 48) {
            float bv = bias[n];
#pragma unroll
            for (int mu = 0; mu < 4; ++mu)
#pragma unroll
                for (int rr = 0; rr < 4; ++rr) {
                    size_t m = (size_t)mbase + wm * 64 + mu * 16 + g * 4 + rr;
                    float v = lrelu_f(acc[mu][nu][rr] + bv);
                    unsigned short h = bf16rn(v);
                    t1s[m * 128 + n] = h;
                    t1s[m * 128 + 64 + n] = bf16rn(v - bf16tof(h));
                }
        }
    }
    if (tid < 128) {   // zero ci pads 48..63 (hi & lo)
        size_t m = (size_t)mbase + tid;
        bfrag z = {0, 0, 0, 0, 0, 0, 0, 0};
        *(bfrag*)(t1s + m * 128 + 48)  = z;
        *(bfrag*)(t1s + m * 128 + 56)  = z;
        *(bfrag*)(t1s + m * 128 + 112) = z;
        *(bfrag*)(t1s + m * 128 + 120) = z;
    }
}

// conv2: 3x3 48->48 as MFMA shifted-GEMM.  block = 128 pixels (half image row).
// XCD row-banding: each XCD owns a contiguous 32-row band per image -> halo re-reads are L2 hits.
__global__ __launch_bounds__(256) void conv2_mfma_kernel(const unsigned short* __restrict__ t1s,
    const unsigned short* __restrict__ c2w2, const float* __restrict__ bias,
    unsigned short* __restrict__ t2s)
{
    __shared__ __align__(16) short a_s[130 * 128];   // 33,280 B
    int bid = blockIdx.x;                 // 1024 = 8 xcd * 128
    int xcd = bid & 7;
    int j = bid >> 3;                     // [0,128)
    int half = j & 1;
    int rl = (j >> 1) & 31;
    int b = j >> 6;
    int r = xcd * 32 + rl;
    int c0 = half * 128;
    int tid = threadIdx.x;
    int lane = tid & 63, wid = tid >> 6;  // 4 waves, wave = 32 pixels
    int i = lane & 15, g = lane >> 4;
    facc zero = {0.f, 0.f, 0.f, 0.f};
    facc acc[2][3];
#pragma unroll
    for (int mu = 0; mu < 2; ++mu)
#pragma unroll
        for (int nu = 0; nu < 3; ++nu) acc[mu][nu] = zero;

    for (int dy = 0; dy < 3; ++dy) {
        int grow = r + dy - 1;
        bool rowok = (grow >= 0 && grow < 256);
        for (int idx = tid; idx < 130 * 16; idx += 256) {
            int j2 = idx >> 4, ch = idx & 15;
            int gc = c0 - 1 + j2;
            bfrag v = {0, 0, 0, 0, 0, 0, 0, 0};
            if (rowok && gc >= 0 && gc < 256) {
                size_t gpix = ((size_t)b * 256 + grow) * 256 + gc;
                v = *(const bfrag*)(t1s + gpix * 128 + ch * 8);
            }
            *(bfrag*)&a_s[j2 * 128 + ((ch ^ (j2 & 7)) * 8)] = v;
        }
        __syncthreads();
#pragma unroll
        for (int dx = 0; dx < 3; ++dx) {
            const unsigned short* wb = c2w2 + (size_t)(dy * 3 + dx) * 48 * 128;
#pragma unroll
            for (int h = 0; h < 2; ++h) {
                bfrag ah[2], al[2], bh[3], bl[3];
#pragma unroll
                for (int mu = 0; mu < 2; ++mu) {
                    int j2 = wid * 32 + mu * 16 + i + dx;   // halo pixel index
                    int chi = (h * 4 + g) ^ (j2 & 7);
                    int clo = (8 + h * 4 + g) ^ (j2 & 7);
                    ah[mu] = *(const bfrag*)&a_s[j2 * 128 + chi * 8];
                    al[mu] = *(const bfrag*)&a_s[j2 * 128 + clo * 8];
                }
#pragma unroll
                for (int nu = 0; nu < 3; ++nu) {
                    const unsigned short* wp = wb + (size_t)(nu * 16 + i) * 128 + h * 32 + g * 8;
                    bh[nu] = *(const bfrag*)(wp);
                    bl[nu] = *(const bfrag*)(wp + 64);
                }
#pragma unroll
                for (int mu = 0; mu < 2; ++mu)
#pragma unroll
                    for (int nu = 0; nu < 3; ++nu) {
                        acc[mu][nu] = __builtin_amdgcn_mfma_f32_16x16x32_bf16(ah[mu], bh[nu], acc[mu][nu], 0, 0, 0);
                        acc[mu][nu] = __builtin_amdgcn_mfma_f32_16x16x32_bf16(ah[mu], bl[nu], acc[mu][nu], 0, 0, 0);
                        acc[mu][nu] = __builtin_amdgcn_mfma_f32_16x16x32_bf16(al[mu], bh[nu], acc[mu][nu], 0, 0, 0);
                    }
            }
        }
        __syncthreads();
    }
    // epilogue: bias + lrelu + split-pack -> t2s
#pragma unroll
    for (int nu = 0; nu < 3; ++nu) {
        int n = nu * 16 + i;
        float bv = bias[n];
#pragma unroll
        for (int mu = 0; mu < 2; ++mu)
#pragma unroll
            for (int rr = 0; rr < 4; ++rr) {
                int lp = wid * 32 + mu * 16 + g * 4 + rr;
                size_t gpix = ((size_t)b * 256 + r) * 256 + (c0 + lp);
                float v = lrelu_f(acc[mu][nu][rr] + bv);
                unsigned short h = bf16rn(v);
                t2s[gpix * 128 + n] = h;
                t2s[gpix * 128 + 64 + n] = bf16rn(v - bf16tof(h));
            }
    }
    if (tid < 128) {   // zero ci pads 48..63
        size_t gpix = ((size_t)b * 256 + r) * 256 + (c0 + tid);
        bfrag z = {0, 0, 0, 0, 0, 0, 0, 0};
        *(bfrag*)(t2s + gpix * 128 + 48)  = z;
        *(bfrag*)(t2s + gpix * 128 + 56)  = z;
        *(bfrag*)(t2s + gpix * 128 + 112) = z;
        *(bfrag*)(t2s + gpix * 128 + 120) = z;
    }
}

// qv = (t2 @ c3_w^T + c3_b) * (x @ lin_w^T + lin_b)   [MFMA, BN=128, XCD-swizzled]
__global__ __launch_bounds__(256) void qv_mfma_kernel(const unsigned short* __restrict__ xs2,
    const unsigned short* __restrict__ lin_w2, const float* __restrict__ lin_b,
    const unsigned short* __restrict__ t2s, const unsigned short* __restrict__ c3_w2,
    const float* __restrict__ c3_b, float* __restrict__ qv)
{
    __shared__ __align__(16) short lds_a[128 * 72];
    __shared__ __align__(16) short lds_w[128 * 72];
    int tid = threadIdx.x;
    int lane = tid & 63, wid = tid >> 6;
    int wm = wid >> 1, wn = wid & 1;
    int bid = blockIdx.y * 2 + blockIdx.x;        // 0..2047, x fastest
    int xcd = bid & 7, j = bid >> 3;              // j 0..255
    int mbase = (xcd * 128 + (j >> 1)) * 128;
    int nbase = (j & 1) * 128;
    facc zero = {0.f, 0.f, 0.f, 0.f};
    facc acc1[4][4], acc2[4][4];
#pragma unroll
    for (int mu = 0; mu < 4; ++mu)
#pragma unroll
        for (int nu = 0; nu < 4; ++nu) { acc1[mu][nu] = zero; acc2[mu][nu] = zero; }

    mfma_kpass3(xs2, 512, lin_w2, 512, 8, mbase, nbase, lds_a, lds_w, tid, wm, wn, acc1);
    mfma_kpass3(t2s, 128, c3_w2, 128, 2, mbase, nbase, lds_a, lds_w, tid, wm, wn, acc2);

    int i = lane & 15, g = lane >> 4;
#pragma unroll
    for (int nu = 0; nu < 4; ++nu) {
        int n = nbase + wn * 64 + nu * 16 + i;
        if (n < 240) {
            float lb = lin_b[n], cb = c3_b[n];
#pragma unroll
            for (int mu = 0; mu < 4; ++mu)
#pragma unroll
                for (int rr = 0; rr < 4; ++rr) {
                    size_t m = (size_t)mbase + wm * 64 + mu * 16 + g * 4 + rr;
                    qv[m * 240 + n] = (acc2[mu][nu][rr] + cb) * (acc1[mu][nu][rr] + lb);
                }
        }
    }
}

// proj: out = cat2 @ proj_w^T + proj_b   [MFMA, BN=128, XCD-swizzled]
__global__ __launch_bounds__(256, 3) void proj_mfma_kernel(const unsigned short* __restrict__ cat2,
    const unsigned short* __restrict__ proj_w2, const float* __restrict__ bias,
    float* __restrict__ out)
{
    __shared__ __align__(16) short lds_a[128 * 72];
    __shared__ __align__(16) short lds_w[128 * 72];
    int tid = threadIdx.x;
    int lane = tid & 63, wid = tid >> 6;
    int wm = wid >> 1, wn = wid & 1;
    int bid = blockIdx.y * 2 + blockIdx.x;
    int xcd = bid & 7, j = bid >> 3;
    int mbase = (xcd * 128 + (j >> 1)) * 128;
    int nbase = (j & 1) * 128;
    facc zero = {0.f, 0.f, 0.f, 0.f};
    facc acc[4][4];
#pragma unroll
    for (int mu = 0; mu < 4; ++mu)
#pragma unroll
        for (int nu = 0; nu < 4; ++nu) acc[mu][nu] = zero;

    mfma_kpass3(cat2, 512, proj_w2, 512, 8, mbase, nbase, lds_a, lds_w, tid, wm, wn, acc);

    int i = lane & 15, g = lane >> 4;
#pragma unroll
    for (int nu = 0; nu < 4; ++nu) {
        int n = nbase + wn * 64 + nu * 16 + i;
        if (n < 240) {
            float bv = bias[n];
#pragma unroll
            for (int mu = 0; mu < 4; ++mu)
#pragma unroll
                for (int rr = 0; rr < 4; ++rr) {
                    size_t m = (size_t)mbase + wm * 64 + mu * 16 + g * 4 + rr;
                    out[m * 240 + n] = acc[mu][nu][rr] + bv;
                }
        }
    }
}

// spatial correlation: per (window, head) -> cat2 channels [n*20, n*20+20) split-bf16
// R13 known-good form: v_s LDS staging + fused k-loop.
__global__ __launch_bounds__(256) void xs_kernel(const float* __restrict__ qv,
    const float* __restrict__ rpb_t, const float* __restrict__ sl_w,
    const float* __restrict__ sl_b, unsigned short* __restrict__ cat2)
{
    __shared__ __align__(16) float v_s[256 * 20];
    __shared__ __align__(16) float vs_s[64 * 20];
    int bid = blockIdx.x;                 // 3072 = 8 xcd * 64 windows * 6 heads
    int xcd = bid & 7;
    int j = bid >> 3;                     // 0..383
    int wl = j / 6;
    int n = j - wl * 6;
    int w = xcd * 64 + wl;
    int tid = threadIdx.x;
    int l = tid;
    size_t pix = (size_t)pix_of(w, l);
    const float* qp = qv + pix * 240 + n * 20;
    float qr[20];
#pragma unroll
    for (int h4 = 0; h4 < 5; ++h4) {
        *(float4*)&qr[h4 * 4] = *(const float4*)(qp + h4 * 4);          // q -> regs
        *(float4*)&v_s[l * 20 + h4 * 4] = *(const float4*)(qp + 120 + h4 * 4);
    }
    __syncthreads();
    float slw0 = sl_w[0], slw1 = sl_w[1], slw2 = sl_w[2], slw3 = sl_w[3];
    float slb = sl_b[0];
    for (int idx = tid; idx < 1280; idx += 256) {
        int k = idx / 20, hd = idx % 20;
        int a = k >> 3, c = k & 7;
        int l00 = a * 32 + c * 2;     // (a*2)*16 + c*2
        float vsum = slb
                   + slw0 * v_s[(l00 + 0) * 20 + hd]
                   + slw1 * v_s[(l00 + 1) * 20 + hd]
                   + slw2 * v_s[(l00 + 16) * 20 + hd]
                   + slw3 * v_s[(l00 + 17) * 20 + hd];
        vs_s[idx] = vsum;             // idx == k*20+hd
    }
    __syncthreads();
    const float* rp = rpb_t + (size_t)n * 16384 + l;
    float acc[20];
#pragma unroll
    for (int hd = 0; hd < 20; ++hd) acc[hd] = 0.f;
    // fused: one pass over k; vr loaded once, used for dot AND PV update
#pragma unroll
    for (int k = 0; k < 64; ++k) {
        float vr[20];
#pragma unroll
        for (int h4 = 0; h4 < 5; ++h4)
            *(float4*)&vr[h4 * 4] = *(const float4*)&vs_s[k * 20 + h4 * 4];
        float s0 = 0.f, s1 = 0.f, s2 = 0.f, s3 = 0.f;
#pragma unroll
        for (int hd = 0; hd < 20; hd += 4) {
            s0 += qr[hd + 0] * vr[hd + 0];
            s1 += qr[hd + 1] * vr[hd + 1];
            s2 += qr[hd + 2] * vr[hd + 2];
            s3 += qr[hd + 3] * vr[hd + 3];
        }
        float cc = (s0 + s1 + s2 + s3) * (1.f / 20.f) + rp[(size_t)k * 256];
#pragma unroll
        for (int hd = 0; hd < 20; ++hd) acc[hd] += cc * vr[hd];
    }
    unsigned short* op = cat2 + pix * 512 + n * 20;
#pragma unroll
    for (int h4 = 0; h4 < 5; ++h4) {
        us4 h, lo;
#pragma unroll
        for (int e = 0; e < 4; ++e) {
            float v = acc[h4 * 4 + e];
            unsigned short hh = bf16rn(v);
            h[e] = hh;
            lo[e] = bf16rn(v - bf16tof(hh));
        }
        *(us4*)(op + h4 * 4) = h;
        *(us4*)(op + 256 + h4 * 4) = lo;
    }
    if (n == 0) {   // zero K-pad channels 240..255 (hi and lo)
        bfrag z = {0, 0, 0, 0, 0, 0, 0, 0};
        unsigned short* zp = cat2 + pix * 512;
        *(bfrag*)(zp + 240) = z;  *(bfrag*)(zp + 248) = z;
        *(bfrag*)(zp + 496) = z;  *(bfrag*)(zp + 504) = z;
    }
}

// channel correlation phase 1: G[w][d][c] = sum_l vc[l,d]*qc[l,c]   (K=256)
__global__ __launch_bounds__(256) void corrc_kernel(const float* __restrict__ qv,
                                                    float* __restrict__ G)
{
    __shared__ __align__(16) float vc_s[16 * 124];
    __shared__ __align__(16) float qc_s[16 * 124];
    int bid = blockIdx.x;                 // 512 = 8 * 64
    int w = (bid & 7) * 64 + (bid >> 3);
    int tid = threadIdx.x, ty = tid >> 4, tx = tid & 15;
    float acc[8][8] = {};
    for (int l0 = 0; l0 < 256; l0 += 16) {
        for (int idx = tid; idx < 480; idx += 256) {
            int k = idx / 30, c4 = idx % 30;
            size_t pix = (size_t)pix_of(w, l0 + k);
            const float* qp = qv + pix * 240;
            *(float4*)&qc_s[k * 124 + c4 * 4] = *(const float4*)(qp + c4 * 4);
            *(float4*)&vc_s[k * 124 + c4 * 4] = *(const float4*)(qp + 120 + c4 * 4);
        }
        __syncthreads();
#pragma unroll
        for (int k = 0; k < 16; ++k) {
            float4 a0 = *(const float4*)&vc_s[k * 124 + ty * 8];
            float4 a1 = *(const float4*)&vc_s[k * 124 + ty * 8 + 4];
            float4 b0 = *(const float4*)&qc_s[k * 124 + tx * 8];
            float4 b1 = *(const float4*)&qc_s[k * 124 + tx * 8 + 4];
            float av[8] = {a0.x, a0.y, a0.z, a0.w, a1.x, a1.y, a1.z, a1.w};
            float bv[8] = {b0.x, b0.y, b0.z, b0.w, b1.x, b1.y, b1.z, b1.w};
#pragma unroll
            for (int i = 0; i < 8; ++i)
#pragma unroll
                for (int j = 0; j < 8; ++j) acc[i][j] += av[i] * bv[j];
        }
        __syncthreads();
    }
    float* gp = G + (size_t)w * 14400;
#pragma unroll
    for (int i = 0; i < 8; ++i) {
        int d = ty * 8 + i;
        if (d < 120) {
#pragma unroll
            for (int j4 = 0; j4 < 2; ++j4) {
                int c = tx * 8 + j4 * 4;
                if (c < 120) {
                    float4 o;
                    o.x = acc[i][j4 * 4 + 0]; o.y = acc[i][j4 * 4 + 1];
                    o.z = acc[i][j4 * 4 + 2]; o.w = acc[i][j4 * 4 + 3];
                    *(float4*)(gp + (size_t)d * 120 + c) = o;
                }
            }
        }
    }
}

// channel correlation phase 2: x_c[l,c] = (1/256) sum_d vc[l,d]*G[d,c]  -> cat2 ch 120..239
__global__ __launch_bounds__(256) void xc_kernel(const float* __restrict__ qv,
    const float* __restrict__ G, unsigned short* __restrict__ cat2)
{
    __shared__ __align__(16) float a_s[8 * 132];
    __shared__ __align__(16) float b_s[8 * 124];
    int bid = blockIdx.x;                 // 1024 = 8 * 64 * 2
    int xcd = bid & 7, j = bid >> 3;      // j 0..127
    int w = xcd * 64 + (j >> 1);
    int mh = j & 1;
    int tid = threadIdx.x, ty = tid >> 4, tx = tid & 15;
    const float* gp = G + (size_t)w * 14400;
    float acc[8][8] = {};
    for (int k0 = 0; k0 < 120; k0 += 8) {
        {
            int lloc = tid >> 1;
            int kk = (tid & 1) * 4;
            int l = mh * 128 + lloc;
            size_t pix = (size_t)pix_of(w, l);
            float4 v = *(const float4*)(qv + pix * 240 + 120 + k0 + kk);
            a_s[(kk + 0) * 132 + lloc] = v.x;
            a_s[(kk + 1) * 132 + lloc] = v.y;
            a_s[(kk + 2) * 132 + lloc] = v.z;
            a_s[(kk + 3) * 132 + lloc] = v.w;
        }
        if (tid < 240) {
            int k = tid / 30, c4 = tid % 30;
            *(float4*)&b_s[k * 124 + c4 * 4] =
                *(const float4*)(gp + (size_t)(k0 + k) * 120 + c4 * 4);
        }
        __syncthreads();
#pragma unroll
        for (int k = 0; k < 8; ++k) {
            float4 a0 = *(const float4*)&a_s[k * 132 + ty * 8];
            float4 a1 = *(const float4*)&a_s[k * 132 + ty * 8 + 4];
            float4 b0 = *(const float4*)&b_s[k * 124 + tx * 8];
            float4 b1 = *(const float4*)&b_s[k * 124 + tx * 8 + 4];
            float av[8] = {a0.x, a0.y, a0.z, a0.w, a1.x, a1.y, a1.z, a1.w};
            float bv[8] = {b0.x, b0.y, b0.z, b0.w, b1.x, b1.y, b1.z, b1.w};
#pragma unroll
            for (int i = 0; i < 8; ++i)
#pragma unroll
                for (int j2 = 0; j2 < 8; ++j2) acc[i][j2] += av[i] * bv[j2];
        }
        __syncthreads();
    }
#pragma unroll
    for (int i = 0; i < 8; ++i) {
        int l = mh * 128 + ty * 8 + i;
        size_t pix = (size_t)pix_of(w, l);
        unsigned short* op = cat2 + pix * 512;
#pragma unroll
        for (int j4 = 0; j4 < 2; ++j4) {
            int c = tx * 8 + j4 * 4;
            if (c < 120) {
                us4 h, lo;
#pragma unroll
                for (int e = 0; e < 4; ++e) {
                    float v = acc[i][j4 * 4 + e] * (1.f / 256.f);
                    unsigned short hh = bf16rn(v);
                    h[e] = hh;
                    lo[e] = bf16rn(v - bf16tof(hh));
                }
                *(us4*)(op + 120 + c) = h;
                *(us4*)(op + 256 + 120 + c) = lo;
            }
        }
    }
}

extern "C" void kernel_launch(void* const* d_in, const int* in_sizes, int n_in,
                              void* d_out, int out_size, void* d_ws, size_t ws_size,
                              hipStream_t stream)
{
    (void)in_sizes; (void)n_in; (void)out_size;
    const float* x     = (const float*)d_in[0];
    const float* c1_w  = (const float*)d_in[1];
    const float* c1_b  = (const float*)d_in[2];
    const float* c2_w  = (const float*)d_in[3];
    const float* c2_b  = (const float*)d_in[4];
    const float* c3_w  = (const float*)d_in[5];
    const float* c3_b  = (const float*)d_in[6];
    const float* lin_w = (const float*)d_in[7];
    const float* lin_b = (const float*)d_in[8];
    const float* sl_w  = (const float*)d_in[9];
    const float* sl_b  = (const float*)d_in[10];
    const float* pp_w  = (const float*)d_in[11];
    const float* pp_b  = (const float*)d_in[12];
    const float* ln1_g = (const float*)d_in[13];
    const float* ln1_b = (const float*)d_in[14];
    const float* p1_w  = (const float*)d_in[15];
    const float* p1_b  = (const float*)d_in[16];
    const float* ln2_g = (const float*)d_in[17];
    const float* ln2_b = (const float*)d_in[18];
    const float* p2_w  = (const float*)d_in[19];
    const float* p2_b  = (const float*)d_in[20];
    const float* ln3_g = (const float*)d_in[21];
    const float* ln3_b = (const float*)d_in[22];
    const float* p3_w  = (const float*)d_in[23];
    const float* p3_b  = (const float*)d_in[24];
    const float* proj_w = (const float*)d_in[25];
    const float* proj_b = (const float*)d_in[26];

    float* ws = (float*)d_ws;
    // ---------------- workspace layout (float units) ----------------
    // overlays (timeline-checked):
    //   t1s (8,388,608 fl) = head of qvb  [t1s dead after conv2; qvb written by qv]
    //   G   (7,372,800 fl) = head of t2s  [t2s dead after qv; G written by corrc after qv]
    //   cat2 = xs2                         [xs2 dead after qv]
    float* pos3   = ws;                                           // -> 8192
    float* rpb_t  = ws + 8192;                                    // -> 106496
    unsigned short* lin_w2  = (unsigned short*)(ws + 106496);     // 256x512 sh -> 172032
    unsigned short* c3_w2   = (unsigned short*)(ws + 172032);     // 256x128 sh -> 188416
    unsigned short* proj_w2 = (unsigned short*)(ws + 188416);     // 256x512 sh -> 253952
    unsigned short* c1_w2   = (unsigned short*)(ws + 253952);     // 128x512 sh -> 286720
    unsigned short* c2w2    = (unsigned short*)(ws + 286720);     // 432x128 sh -> 314368
    unsigned short* t2s = (unsigned short*)(ws + 314368);         // 8388608 fl -> 8702976
    float* G      = ws + 314368;                                  // overlays t2s
    unsigned short* xs2 = (unsigned short*)(ws + 8702976);        // 33554432 fl -> 42257408
    unsigned short* cat2 = xs2;                                   // overlays xs2
    float* qvb    = ws + 42257408;                                // 31457280 fl -> 73714688
    unsigned short* t1s = (unsigned short*)qvb;                   // overlays qvb head
    const size_t required = (size_t)73714688 * 4;                 // 294.9 MB
    if (ws_size < required) return;

    pack_all_kernel<<<16499, 256, 0, stream>>>(lin_w, proj_w, c3_w, c1_w, c2_w, x,
                                               lin_w2, proj_w2, c3_w2, c1_w2, c2w2, xs2);
    prep_pos_kernel<<<4, 256, 0, stream>>>(pp_w, pp_b, ln1_g, ln1_b, p1_w, p1_b,
                                           ln2_g, ln2_b, p2_w, p2_b, ln3_g, ln3_b,
                                           p3_w, p3_b, pos3);
    rpb_kernel<<<384, 256, 0, stream>>>(pos3, rpb_t);
    conv1_mfma_kernel<<<1024, 256, 0, stream>>>(xs2, c1_w2, c1_b, t1s);
    conv2_mfma_kernel<<<1024, 256, 0, stream>>>(t1s, c2w2, c2_b, t2s);
    qv_mfma_kernel<<<dim3(2, 1024), 256, 0, stream>>>(xs2, lin_w2, lin_b, t2s, c3_w2, c3_b, qvb);
    xs_kernel<<<3072, 256, 0, stream>>>(qvb, rpb_t, sl_w, sl_b, cat2);
    corrc_kernel<<<512, 256, 0, stream>>>(qvb, G);
    xc_kernel<<<1024, 256, 0, stream>>>(qvb, G, cat2);
    proj_mfma_kernel<<<dim3(2, 1024), 256, 0, stream>>>(cat2, proj_w2, proj_b, (float*)d_out);
}

// Round 16
// 541.964 us; speedup vs baseline: 1.0419x; 1.0210x over previous
//
#include <hip/hip_runtime.h>
#include <math.h>

#define NPIX 131072   // 2*256*256

typedef __attribute__((ext_vector_type(8))) short bfrag;
typedef __attribute__((ext_vector_type(4))) float facc;
typedef __attribute__((ext_vector_type(4))) unsigned short us4;

__device__ __forceinline__ float lrelu_f(float x) { return x >= 0.f ? x : 0.2f * x; }

// window w (0..511): b=w>>8, wi=(w>>4)&15, wj=w&15 ; l (0..255): i=l>>4, j=l&15
__device__ __forceinline__ int pix_of(int w, int l) {
    int b = w >> 8, wi = (w >> 4) & 15, wj = w & 15;
    return ((((b << 4) + wi) * 16 + (l >> 4)) << 8) + (wj << 4) + (l & 15);
}

// ---- bf16 split helpers (round-to-nearest-even) ----
__device__ __forceinline__ unsigned short bf16rn(float f) {
    unsigned u = __builtin_bit_cast(unsigned, f);
    u += 0x7FFFu + ((u >> 16) & 1u);
    return (unsigned short)(u >> 16);
}
__device__ __forceinline__ float bf16tof(unsigned short h) {
    unsigned u = ((unsigned)h) << 16;
    return __builtin_bit_cast(float, u);
}

// ---------------- split_x body: fp32 -> packed [hi|lo] bf16 ----------------
// xs2 row: shorts [0,256) = hi(k), [256,512) = lo(k); k>=240 zero.
__device__ __forceinline__ void split_x_body(const float* __restrict__ x,
                                             unsigned short* __restrict__ xs2, int idx)
{
    int row = idx >> 5;
    int k = (idx & 31) * 8;
    float v[8];
    if (k < 240) {
        float4 a = *(const float4*)(x + (size_t)row * 240 + k);
        float4 b = *(const float4*)(x + (size_t)row * 240 + k + 4);
        v[0] = a.x; v[1] = a.y; v[2] = a.z; v[3] = a.w;
        v[4] = b.x; v[5] = b.y; v[6] = b.z; v[7] = b.w;
    } else {
#pragma unroll
        for (int e = 0; e < 8; ++e) v[e] = 0.f;
    }
    bfrag hi, lo;
#pragma unroll
    for (int e = 0; e < 8; ++e) {
        unsigned short h = bf16rn(v[e]);
        hi[e] = (short)h;
        lo[e] = (short)bf16rn(v[e] - bf16tof(h));
    }
    unsigned short* dst = xs2 + (size_t)row * 512 + k;
    *(bfrag*)(dst) = hi;
    *(bfrag*)(dst + 256) = lo;
}

// generic weight pack body: src [rows][K] fp32 -> dst [rows_pad][2*KPAD] shorts (zero padded)
__device__ __forceinline__ void pack_w_body(const float* __restrict__ src,
                                            int rows, int K,
                                            unsigned short* __restrict__ dst,
                                            int total8, int KPAD, int idx)
{
    if (idx >= total8) return;
    int kper = KPAD >> 3;
    int row = idx / kper;
    int k = (idx - row * kper) * 8;
    float v[8];
#pragma unroll
    for (int e = 0; e < 8; ++e) {
        int kk = k + e;
        v[e] = (row < rows && kk < K) ? src[(size_t)row * K + kk] : 0.f;
    }
    bfrag hi, lo;
#pragma unroll
    for (int e = 0; e < 8; ++e) {
        unsigned short h = bf16rn(v[e]);
        hi[e] = (short)h;
        lo[e] = (short)bf16rn(v[e] - bf16tof(h));
    }
    unsigned short* d = dst + (size_t)row * 2 * KPAD + k;
    *(bfrag*)(d) = hi;
    *(bfrag*)(d + KPAD) = lo;
}

// c2 weights body -> c2w2[tap][n][ hi64 | lo64 ]  (tap = ky*3+kx; ci pad 48..63 = 0)
__device__ __forceinline__ void pack_c2w_body(const float* __restrict__ c2_w,
                                              unsigned short* __restrict__ c2w2, int idx)
{
    if (idx >= 6912) return;
    int rowid = idx >> 4;          // tap*48 + n
    int c = idx & 15;
    int tap = rowid / 48, n = rowid - tap * 48;
    int ty = tap / 3, tx = tap - ty * 3;
    int lohalf = c >> 3;
    int cbase = (c & 7) * 8;
    bfrag outv;
#pragma unroll
    for (int e = 0; e < 8; ++e) {
        int ci = cbase + e;
        float v = (ci < 48) ? c2_w[(((size_t)n * 48 + ci) * 3 + ty) * 3 + tx] : 0.f;
        unsigned short h = bf16rn(v);
        outv[e] = (short)(lohalf ? bf16rn(v - bf16tof(h)) : h);
    }
    *(bfrag*)(c2w2 + (size_t)rowid * 128 + c * 8) = outv;
}

// merged pre-pass kernel: weight packs (blocks 0..114) + split_x (blocks 115..16498)
__global__ __launch_bounds__(256) void pack_all_kernel(
    const float* __restrict__ lin_w, const float* __restrict__ proj_w,
    const float* __restrict__ c3_w, const float* __restrict__ c1_w,
    const float* __restrict__ c2_w, const float* __restrict__ x,
    unsigned short* __restrict__ lin_w2, unsigned short* __restrict__ proj_w2,
    unsigned short* __restrict__ c3_w2, unsigned short* __restrict__ c1_w2,
    unsigned short* __restrict__ c2w2, unsigned short* __restrict__ xs2)
{
    int blk = blockIdx.x, tid = threadIdx.x;
    if (blk < 32)       pack_w_body(lin_w, 240, 240, lin_w2, 8192, 256, blk * 256 + tid);
    else if (blk < 64)  pack_w_body(proj_w, 240, 240, proj_w2, 8192, 256, (blk - 32) * 256 + tid);
    else if (blk < 72)  pack_w_body(c3_w, 240, 48, c3_w2, 2048, 64, (blk - 64) * 256 + tid);
    else if (blk < 88)  pack_w_body(c1_w, 48, 240, c1_w2, 4096, 256, (blk - 72) * 256 + tid);
    else if (blk < 115) pack_c2w_body(c2_w, c2w2, (blk - 88) * 256 + tid);
    else                split_x_body(x, xs2, (blk - 115) * 256 + tid);
}

// ---------------- prep: DynamicPosBias MLP ----------------
__device__ __forceinline__ void ln_relu15(const float* h, float* r,
                                          const float* __restrict__ g,
                                          const float* __restrict__ b) {
    float m = 0.f;
#pragma unroll
    for (int f = 0; f < 15; ++f) m += h[f];
    m *= (1.f / 15.f);
    float v = 0.f;
#pragma unroll
    for (int f = 0; f < 15; ++f) { float d = h[f] - m; v += d * d; }
    float rs = rsqrtf(v * (1.f / 15.f) + 1e-5f);
#pragma unroll
    for (int f = 0; f < 15; ++f) {
        float xx = (h[f] - m) * rs * g[f] + b[f];
        r[f] = xx > 0.f ? xx : 0.f;
    }
}

__device__ __forceinline__ void lin15(const float* r, float* h,
                                      const float* __restrict__ w,
                                      const float* __restrict__ b) {
#pragma unroll
    for (int o = 0; o < 15; ++o) {
        float s = b[o];
#pragma unroll
        for (int g = 0; g < 15; ++g) s += r[g] * w[o * 15 + g];
        h[o] = s;
    }
}

__global__ __launch_bounds__(256) void prep_pos_kernel(
    const float* __restrict__ pp_w, const float* __restrict__ pp_b,
    const float* __restrict__ ln1_g, const float* __restrict__ ln1_b,
    const float* __restrict__ p1_w, const float* __restrict__ p1_b,
    const float* __restrict__ ln2_g, const float* __restrict__ ln2_b,
    const float* __restrict__ p2_w, const float* __restrict__ p2_b,
    const float* __restrict__ ln3_g, const float* __restrict__ ln3_b,
    const float* __restrict__ p3_w, const float* __restrict__ p3_b,
    float* __restrict__ pos3)
{
    int idx = blockIdx.x * 256 + threadIdx.x;
    if (idx >= 961) return;
    float h[15], r[15];
    float in0 = (float)(idx / 31) - 15.f;
    float in1 = (float)(idx % 31) - 15.f;
#pragma unroll
    for (int f = 0; f < 15; ++f) h[f] = in0 * pp_w[2 * f] + in1 * pp_w[2 * f + 1] + pp_b[f];
    ln_relu15(h, r, ln1_g, ln1_b);
    lin15(r, h, p1_w, p1_b);
    ln_relu15(h, r, ln2_g, ln2_b);
    lin15(r, h, p2_w, p2_b);
    ln_relu15(h, r, ln3_g, ln3_b);
#pragma unroll
    for (int o = 0; o < 6; ++o) {
        float s = p3_b[o];
#pragma unroll
        for (int g = 0; g < 15; ++g) s += r[g] * p3_w[o * 15 + g];
        pos3[idx * 6 + o] = s;
    }
}

// rpb_t[n][k][l]  (n<6, k<64 base-window key, l<256 query pos)
__global__ __launch_bounds__(256) void rpb_kernel(const float* __restrict__ pos3,
                                                  float* __restrict__ rpb_t)
{
    int out = blockIdx.x * 256 + threadIdx.x;   // < 98304
    int n = out >> 14;
    int k = (out >> 8) & 63;
    int l = out & 255;
    int a = k >> 3, c = k & 7;
    int i1 = l >> 4, j1 = l & 15;
    float s = 0.f;
#pragma unroll
    for (int bb = 0; bb < 2; ++bb)
#pragma unroll
        for (int d = 0; d < 2; ++d) {
            int i2 = a * 2 + bb, j2 = c * 2 + d;
            int rpi = (i1 - i2 + 15) * 31 + (j1 - j2 + 15);
            s += pos3[rpi * 6 + n];
        }
    rpb_t[out] = s * 0.25f;
}

// ---------------- MFMA split-bf16 NT GEMM core, BM=128 BN=128 (R11 known-good) ----------------
// LDS row: [32 hi][32 lo] shorts, stride 72. Frag: lane l -> row (l&15), chunk (l>>4)*8.
__device__ __forceinline__ void mfma_kpass3(const unsigned short* __restrict__ A2, int lda2,
                                            const unsigned short* __restrict__ W2, int ldw2,
                                            int ksteps, int mbase, int nbase,
                                            short* lds_a, short* lds_w,
                                            int tid, int wm, int wn,
                                            facc acc[4][4])
{
    int lane = tid & 63;
    int i = lane & 15, g = lane >> 4;
    int kpa = lda2 >> 1, kpw = ldw2 >> 1;
    for (int s = 0; s < ksteps; ++s) {
        int k0 = s * 32;
        {   // stage A: 128 rows x (32 hi + 32 lo) shorts
            int r = tid >> 1, h16 = (tid & 1) * 16;
            const unsigned short* src = A2 + (size_t)(mbase + r) * lda2 + k0 + h16;
            bfrag h0 = *(const bfrag*)(src);
            bfrag h1 = *(const bfrag*)(src + 8);
            bfrag l0 = *(const bfrag*)(src + kpa);
            bfrag l1 = *(const bfrag*)(src + kpa + 8);
            short* dst = lds_a + r * 72 + h16;
            *(bfrag*)(dst)      = h0;  *(bfrag*)(dst + 8)  = h1;
            *(bfrag*)(dst + 32) = l0;  *(bfrag*)(dst + 40) = l1;
        }
        {   // stage W: 128 rows x (32 hi + 32 lo) shorts; thread: row + half
            int r = tid >> 1, half = tid & 1;
            const unsigned short* src = W2 + (size_t)(nbase + r) * ldw2 + half * kpw + k0;
            bfrag v0 = *(const bfrag*)(src);
            bfrag v1 = *(const bfrag*)(src + 8);
            bfrag v2 = *(const bfrag*)(src + 16);
            bfrag v3 = *(const bfrag*)(src + 24);
            short* dst = lds_w + r * 72 + half * 32;
            *(bfrag*)(dst)      = v0;  *(bfrag*)(dst + 8)  = v1;
            *(bfrag*)(dst + 16) = v2;  *(bfrag*)(dst + 24) = v3;
        }
        __syncthreads();
        bfrag ah[4], al[4], bh[4], bl[4];
#pragma unroll
        for (int mu = 0; mu < 4; ++mu) {
            const short* p = lds_a + (wm * 64 + mu * 16 + i) * 72 + g * 8;
            ah[mu] = *(const bfrag*)(p);
            al[mu] = *(const bfrag*)(p + 32);
        }
#pragma unroll
        for (int nu = 0; nu < 4; ++nu) {
            const short* p = lds_w + (wn * 64 + nu * 16 + i) * 72 + g * 8;
            bh[nu] = *(const bfrag*)(p);
            bl[nu] = *(const bfrag*)(p + 32);
        }
#pragma unroll
        for (int mu = 0; mu < 4; ++mu)
#pragma unroll
            for (int nu = 0; nu < 4; ++nu) {
                acc[mu][nu] = __builtin_amdgcn_mfma_f32_16x16x32_bf16(ah[mu], bh[nu], acc[mu][nu], 0, 0, 0);
                acc[mu][nu] = __builtin_amdgcn_mfma_f32_16x16x32_bf16(ah[mu], bl[nu], acc[mu][nu], 0, 0, 0);
                acc[mu][nu] = __builtin_amdgcn_mfma_f32_16x16x32_bf16(al[mu], bh[nu], acc[mu][nu], 0, 0, 0);
            }
        __syncthreads();
    }
}

// ---------------- BN=64 variant (conv1): simple 2-barrier loop, 4 waves = 2x2 ----------------
__device__ __forceinline__ void mfma_kpass_n64(const unsigned short* __restrict__ A2, int lda2,
                                               const unsigned short* __restrict__ W2, int ldw2,
                                               int ksteps, int mbase,
                                               short* lds_a, short* lds_w,
                                               int tid, int wm, int wn,
                                               facc acc[4][2])
{
    int lane = tid & 63;
    int i = lane & 15, g = lane >> 4;
    int kpa = lda2 >> 1, kpw = ldw2 >> 1;
    for (int s = 0; s < ksteps; ++s) {
        int k0 = s * 32;
        {   // stage A: 128 rows x (32 hi + 32 lo) shorts
            int r = tid >> 1, h16 = (tid & 1) * 16;
            const unsigned short* src = A2 + (size_t)(mbase + r) * lda2 + k0 + h16;
            bfrag h0 = *(const bfrag*)(src);
            bfrag h1 = *(const bfrag*)(src + 8);
            bfrag l0 = *(const bfrag*)(src + kpa);
            bfrag l1 = *(const bfrag*)(src + kpa + 8);
            short* dst = lds_a + r * 72 + h16;
            *(bfrag*)(dst)      = h0;  *(bfrag*)(dst + 8)  = h1;
            *(bfrag*)(dst + 32) = l0;  *(bfrag*)(dst + 40) = l1;
        }
        if (tid < 128) {   // stage W: 64 rows
            int r = tid >> 1, half = tid & 1;
            const unsigned short* src = W2 + (size_t)r * ldw2 + half * kpw + k0;
            bfrag v0 = *(const bfrag*)(src);
            bfrag v1 = *(const bfrag*)(src + 8);
            bfrag v2 = *(const bfrag*)(src + 16);
            bfrag v3 = *(const bfrag*)(src + 24);
            short* dst = lds_w + r * 72 + half * 32;
            *(bfrag*)(dst)      = v0;  *(bfrag*)(dst + 8)  = v1;
            *(bfrag*)(dst + 16) = v2;  *(bfrag*)(dst + 24) = v3;
        }
        __syncthreads();
        bfrag ah[4], al[4], bh[2], bl[2];
#pragma unroll
        for (int mu = 0; mu < 4; ++mu) {
            const short* p = lds_a + (wm * 64 + mu * 16 + i) * 72 + g * 8;
            ah[mu] = *(const bfrag*)(p);
            al[mu] = *(const bfrag*)(p + 32);
        }
#pragma unroll
        for (int nu = 0; nu < 2; ++nu) {
            const short* p = lds_w + (wn * 32 + nu * 16 + i) * 72 + g * 8;
            bh[nu] = *(const bfrag*)(p);
            bl[nu] = *(const bfrag*)(p + 32);
        }
#pragma unroll
        for (int mu = 0; mu < 4; ++mu)
#pragma unroll
            for (int nu = 0; nu < 2; ++nu) {
                acc[mu][nu] = __builtin_amdgcn_mfma_f32_16x16x32_bf16(ah[mu], bh[nu], acc[mu][nu], 0, 0, 0);
                acc[mu][nu] = __builtin_amdgcn_mfma_f32_16x16x32_bf16(ah[mu], bl[nu], acc[mu][nu], 0, 0, 0);
                acc[mu][nu] = __builtin_amdgcn_mfma_f32_16x16x32_bf16(al[mu], bh[nu], acc[mu][nu], 0, 0, 0);
            }
        __syncthreads();
    }
}

// conv1: t1s = split(lrelu(x @ c1_w^T + c1_b)) packed [hi64|lo64], N=48 (BN=64)
__global__ __launch_bounds__(256, 3) void conv1_mfma_kernel(const unsigned short* __restrict__ xs2,
    const unsigned short* __restrict__ c1_w2, const float* __restrict__ bias,
    unsigned short* __restrict__ t1s)
{
    __shared__ __align__(16) short lds_a[128 * 72];
    __shared__ __align__(16) short lds_w[64 * 72];
    int tid = threadIdx.x;
    int lane = tid & 63, wid = tid >> 6;
    int wm = wid >> 1, wn = wid & 1;
    int mbase = blockIdx.x * 128;
    facc zero = {0.f, 0.f, 0.f, 0.f};
    facc acc[4][2];
#pragma unroll
    for (int mu = 0; mu < 4; ++mu)
#pragma unroll
        for (int nu = 0; nu < 2; ++nu) acc[mu][nu] = zero;

    mfma_kpass_n64(xs2, 512, c1_w2, 512, 8, mbase, lds_a, lds_w, tid, wm, wn, acc);

    int i = lane & 15, g = lane >> 4;
#pragma unroll
    for (int nu = 0; nu < 2; ++nu) {
        int n = wn * 32 + nu * 16 + i;
        if (n < 48) {
            float bv = bias[n];
#pragma unroll
            for (int mu = 0; mu < 4; ++mu)
#pragma unroll
                for (int rr = 0; rr < 4; ++rr) {
                    size_t m = (size_t)mbase + wm * 64 + mu * 16 + g * 4 + rr;
                    float v = lrelu_f(acc[mu][nu][rr] + bv);
                    unsigned short h = bf16rn(v);
                    t1s[m * 128 + n] = h;
                    t1s[m * 128 + 64 + n] = bf16rn(v - bf16tof(h));
                }
        }
    }
    if (tid < 128) {   // zero ci pads 48..63 (hi & lo)
        size_t m = (size_t)mbase + tid;
        bfrag z = {0, 0, 0, 0, 0, 0, 0, 0};
        *(bfrag*)(t1s + m * 128 + 48)  = z;
        *(bfrag*)(t1s + m * 128 + 56)  = z;
        *(bfrag*)(t1s + m * 128 + 112) = z;
        *(bfrag*)(t1s + m * 128 + 120) = z;
    }
}

// conv2: 3x3 48->48 as MFMA shifted-GEMM.  block = 128 pixels (half image row).
// XCD row-banding: each XCD owns a contiguous 32-row band per image -> halo re-reads are L2 hits.
__global__ __launch_bounds__(256) void conv2_mfma_kernel(const unsigned short* __restrict__ t1s,
    const unsigned short* __restrict__ c2w2, const float* __restrict__ bias,
    unsigned short* __restrict__ t2s)
{
    __shared__ __align__(16) short a_s[130 * 128];   // 33,280 B
    int bid = blockIdx.x;                 // 1024 = 8 xcd * 128
    int xcd = bid & 7;
    int j = bid >> 3;                     // [0,128)
    int half = j & 1;
    int rl = (j >> 1) & 31;
    int b = j >> 6;
    int r = xcd * 32 + rl;
    int c0 = half * 128;
    int tid = threadIdx.x;
    int lane = tid & 63, wid = tid >> 6;  // 4 waves, wave = 32 pixels
    int i = lane & 15, g = lane >> 4;
    facc zero = {0.f, 0.f, 0.f, 0.f};
    facc acc[2][3];
#pragma unroll
    for (int mu = 0; mu < 2; ++mu)
#pragma unroll
        for (int nu = 0; nu < 3; ++nu) acc[mu][nu] = zero;

    for (int dy = 0; dy < 3; ++dy) {
        int grow = r + dy - 1;
        bool rowok = (grow >= 0 && grow < 256);
        for (int idx = tid; idx < 130 * 16; idx += 256) {
            int j2 = idx >> 4, ch = idx & 15;
            int gc = c0 - 1 + j2;
            bfrag v = {0, 0, 0, 0, 0, 0, 0, 0};
            if (rowok && gc >= 0 && gc < 256) {
                size_t gpix = ((size_t)b * 256 + grow) * 256 + gc;
                v = *(const bfrag*)(t1s + gpix * 128 + ch * 8);
            }
            *(bfrag*)&a_s[j2 * 128 + ((ch ^ (j2 & 7)) * 8)] = v;
        }
        __syncthreads();
#pragma unroll
        for (int dx = 0; dx < 3; ++dx) {
            const unsigned short* wb = c2w2 + (size_t)(dy * 3 + dx) * 48 * 128;
#pragma unroll
            for (int h = 0; h < 2; ++h) {
                bfrag ah[2], al[2], bh[3], bl[3];
#pragma unroll
                for (int mu = 0; mu < 2; ++mu) {
                    int j2 = wid * 32 + mu * 16 + i + dx;   // halo pixel index
                    int chi = (h * 4 + g) ^ (j2 & 7);
                    int clo = (8 + h * 4 + g) ^ (j2 & 7);
                    ah[mu] = *(const bfrag*)&a_s[j2 * 128 + chi * 8];
                    al[mu] = *(const bfrag*)&a_s[j2 * 128 + clo * 8];
                }
#pragma unroll
                for (int nu = 0; nu < 3; ++nu) {
                    const unsigned short* wp = wb + (size_t)(nu * 16 + i) * 128 + h * 32 + g * 8;
                    bh[nu] = *(const bfrag*)(wp);
                    bl[nu] = *(const bfrag*)(wp + 64);
                }
#pragma unroll
                for (int mu = 0; mu < 2; ++mu)
#pragma unroll
                    for (int nu = 0; nu < 3; ++nu) {
                        acc[mu][nu] = __builtin_amdgcn_mfma_f32_16x16x32_bf16(ah[mu], bh[nu], acc[mu][nu], 0, 0, 0);
                        acc[mu][nu] = __builtin_amdgcn_mfma_f32_16x16x32_bf16(ah[mu], bl[nu], acc[mu][nu], 0, 0, 0);
                        acc[mu][nu] = __builtin_amdgcn_mfma_f32_16x16x32_bf16(al[mu], bh[nu], acc[mu][nu], 0, 0, 0);
                    }
            }
        }
        __syncthreads();
    }
    // epilogue: bias + lrelu + split-pack -> t2s
#pragma unroll
    for (int nu = 0; nu < 3; ++nu) {
        int n = nu * 16 + i;
        float bv = bias[n];
#pragma unroll
        for (int mu = 0; mu < 2; ++mu)
#pragma unroll
            for (int rr = 0; rr < 4; ++rr) {
                int lp = wid * 32 + mu * 16 + g * 4 + rr;
                size_t gpix = ((size_t)b * 256 + r) * 256 + (c0 + lp);
                float v = lrelu_f(acc[mu][nu][rr] + bv);
                unsigned short h = bf16rn(v);
                t2s[gpix * 128 + n] = h;
                t2s[gpix * 128 + 64 + n] = bf16rn(v - bf16tof(h));
            }
    }
    if (tid < 128) {   // zero ci pads 48..63
        size_t gpix = ((size_t)b * 256 + r) * 256 + (c0 + tid);
        bfrag z = {0, 0, 0, 0, 0, 0, 0, 0};
        *(bfrag*)(t2s + gpix * 128 + 48)  = z;
        *(bfrag*)(t2s + gpix * 128 + 56)  = z;
        *(bfrag*)(t2s + gpix * 128 + 112) = z;
        *(bfrag*)(t2s + gpix * 128 + 120) = z;
    }
}

// qv = (t2 @ c3_w^T + c3_b) * (x @ lin_w^T + lin_b)   [MFMA, BN=128, XCD-swizzled]
__global__ __launch_bounds__(256) void qv_mfma_kernel(const unsigned short* __restrict__ xs2,
    const unsigned short* __restrict__ lin_w2, const float* __restrict__ lin_b,
    const unsigned short* __restrict__ t2s, const unsigned short* __restrict__ c3_w2,
    const float* __restrict__ c3_b, float* __restrict__ qv)
{
    __shared__ __align__(16) short lds_a[128 * 72];
    __shared__ __align__(16) short lds_w[128 * 72];
    int tid = threadIdx.x;
    int lane = tid & 63, wid = tid >> 6;
    int wm = wid >> 1, wn = wid & 1;
    int bid = blockIdx.y * 2 + blockIdx.x;        // 0..2047, x fastest
    int xcd = bid & 7, j = bid >> 3;              // j 0..255
    int mbase = (xcd * 128 + (j >> 1)) * 128;
    int nbase = (j & 1) * 128;
    facc zero = {0.f, 0.f, 0.f, 0.f};
    facc acc1[4][4], acc2[4][4];
#pragma unroll
    for (int mu = 0; mu < 4; ++mu)
#pragma unroll
        for (int nu = 0; nu < 4; ++nu) { acc1[mu][nu] = zero; acc2[mu][nu] = zero; }

    mfma_kpass3(xs2, 512, lin_w2, 512, 8, mbase, nbase, lds_a, lds_w, tid, wm, wn, acc1);
    mfma_kpass3(t2s, 128, c3_w2, 128, 2, mbase, nbase, lds_a, lds_w, tid, wm, wn, acc2);

    int i = lane & 15, g = lane >> 4;
#pragma unroll
    for (int nu = 0; nu < 4; ++nu) {
        int n = nbase + wn * 64 + nu * 16 + i;
        if (n < 240) {
            float lb = lin_b[n], cb = c3_b[n];
#pragma unroll
            for (int mu = 0; mu < 4; ++mu)
#pragma unroll
                for (int rr = 0; rr < 4; ++rr) {
                    size_t m = (size_t)mbase + wm * 64 + mu * 16 + g * 4 + rr;
                    qv[m * 240 + n] = (acc2[mu][nu][rr] + cb) * (acc1[mu][nu][rr] + lb);
                }
        }
    }
}

// proj: out = cat2 @ proj_w^T + proj_b   [MFMA, BN=128, XCD-swizzled]
__global__ __launch_bounds__(256, 3) void proj_mfma_kernel(const unsigned short* __restrict__ cat2,
    const unsigned short* __restrict__ proj_w2, const float* __restrict__ bias,
    float* __restrict__ out)
{
    __shared__ __align__(16) short lds_a[128 * 72];
    __shared__ __align__(16) short lds_w[128 * 72];
    int tid = threadIdx.x;
    int lane = tid & 63, wid = tid >> 6;
    int wm = wid >> 1, wn = wid & 1;
    int bid = blockIdx.y * 2 + blockIdx.x;
    int xcd = bid & 7, j = bid >> 3;
    int mbase = (xcd * 128 + (j >> 1)) * 128;
    int nbase = (j & 1) * 128;
    facc zero = {0.f, 0.f, 0.f, 0.f};
    facc acc[4][4];
#pragma unroll
    for (int mu = 0; mu < 4; ++mu)
#pragma unroll
        for (int nu = 0; nu < 4; ++nu) acc[mu][nu] = zero;

    mfma_kpass3(cat2, 512, proj_w2, 512, 8, mbase, nbase, lds_a, lds_w, tid, wm, wn, acc);

    int i = lane & 15, g = lane >> 4;
#pragma unroll
    for (int nu = 0; nu < 4; ++nu) {
        int n = nbase + wn * 64 + nu * 16 + i;
        if (n < 240) {
            float bv = bias[n];
#pragma unroll
            for (int mu = 0; mu < 4; ++mu)
#pragma unroll
                for (int rr = 0; rr < 4; ++rr) {
                    size_t m = (size_t)mbase + wm * 64 + mu * 16 + g * 4 + rr;
                    out[m * 240 + n] = acc[mu][nu][rr] + bv;
                }
        }
    }
}

// spatial correlation: per (window, head) -> cat2 channels [n*20, n*20+20) split-bf16
// R13 known-good form: v_s LDS staging + fused k-loop.
__global__ __launch_bounds__(256) void xs_kernel(const float* __restrict__ qv,
    const float* __restrict__ rpb_t, const float* __restrict__ sl_w,
    const float* __restrict__ sl_b, unsigned short* __restrict__ cat2)
{
    __shared__ __align__(16) float v_s[256 * 20];
    __shared__ __align__(16) float vs_s[64 * 20];
    int bid = blockIdx.x;                 // 3072 = 8 xcd * 64 windows * 6 heads
    int xcd = bid & 7;
    int j = bid >> 3;                     // 0..383
    int wl = j / 6;
    int n = j - wl * 6;
    int w = xcd * 64 + wl;
    int tid = threadIdx.x;
    int l = tid;
    size_t pix = (size_t)pix_of(w, l);
    const float* qp = qv + pix * 240 + n * 20;
    float qr[20];
#pragma unroll
    for (int h4 = 0; h4 < 5; ++h4) {
        *(float4*)&qr[h4 * 4] = *(const float4*)(qp + h4 * 4);          // q -> regs
        *(float4*)&v_s[l * 20 + h4 * 4] = *(const float4*)(qp + 120 + h4 * 4);
    }
    __syncthreads();
    float slw0 = sl_w[0], slw1 = sl_w[1], slw2 = sl_w[2], slw3 = sl_w[3];
    float slb = sl_b[0];
    for (int idx = tid; idx < 1280; idx += 256) {
        int k = idx / 20, hd = idx % 20;
        int a = k >> 3, c = k & 7;
        int l00 = a * 32 + c * 2;     // (a*2)*16 + c*2
        float vsum = slb
                   + slw0 * v_s[(l00 + 0) * 20 + hd]
                   + slw1 * v_s[(l00 + 1) * 20 + hd]
                   + slw2 * v_s[(l00 + 16) * 20 + hd]
                   + slw3 * v_s[(l00 + 17) * 20 + hd];
        vs_s[idx] = vsum;             // idx == k*20+hd
    }
    __syncthreads();
    const float* rp = rpb_t + (size_t)n * 16384 + l;
    float acc[20];
#pragma unroll
    for (int hd = 0; hd < 20; ++hd) acc[hd] = 0.f;
#pragma unroll
    for (int k = 0; k < 64; ++k) {
        float vr[20];
#pragma unroll
        for (int h4 = 0; h4 < 5; ++h4)
            *(float4*)&vr[h4 * 4] = *(const float4*)&vs_s[k * 20 + h4 * 4];
        float s0 = 0.f, s1 = 0.f, s2 = 0.f, s3 = 0.f;
#pragma unroll
        for (int hd = 0; hd < 20; hd += 4) {
            s0 += qr[hd + 0] * vr[hd + 0];
            s1 += qr[hd + 1] * vr[hd + 1];
            s2 += qr[hd + 2] * vr[hd + 2];
            s3 += qr[hd + 3] * vr[hd + 3];
        }
        float cc = (s0 + s1 + s2 + s3) * (1.f / 20.f) + rp[(size_t)k * 256];
#pragma unroll
        for (int hd = 0; hd < 20; ++hd) acc[hd] += cc * vr[hd];
    }
    unsigned short* op = cat2 + pix * 512 + n * 20;
#pragma unroll
    for (int h4 = 0; h4 < 5; ++h4) {
        us4 h, lo;
#pragma unroll
        for (int e = 0; e < 4; ++e) {
            float v = acc[h4 * 4 + e];
            unsigned short hh = bf16rn(v);
            h[e] = hh;
            lo[e] = bf16rn(v - bf16tof(hh));
        }
        *(us4*)(op + h4 * 4) = h;
        *(us4*)(op + 256 + h4 * 4) = lo;
    }
    if (n == 0) {   // zero K-pad channels 240..255 (hi and lo)
        bfrag z = {0, 0, 0, 0, 0, 0, 0, 0};
        unsigned short* zp = cat2 + pix * 512;
        *(bfrag*)(zp + 240) = z;  *(bfrag*)(zp + 248) = z;
        *(bfrag*)(zp + 496) = z;  *(bfrag*)(zp + 504) = z;
    }
}

// FUSED channel correlation: phase 1 builds G[120][124] in LDS (corrc), phase 2
// consumes it for x_c (xc) for both mh halves.  G never touches HBM.
// Window mapping: w = (bid&7)*64 + (bid>>3)  (XCD affinity, as before).
__global__ __launch_bounds__(256) void corrxc_kernel(const float* __restrict__ qv,
                                                     unsigned short* __restrict__ cat2)
{
    __shared__ __align__(16) float G_s[120 * 124];   // 59,520 B
    __shared__ __align__(16) float vc_s[16 * 124];
    __shared__ __align__(16) float qc_s[16 * 124];
    __shared__ __align__(16) float a_s[8 * 132];
    int bid = blockIdx.x;                 // 512 = 8 * 64
    int w = (bid & 7) * 64 + (bid >> 3);
    int tid = threadIdx.x, ty = tid >> 4, tx = tid & 15;

    // ---------- phase 1: G = vc^T qc  (identical math to corrc_kernel) ----------
    float acc[8][8] = {};
    for (int l0 = 0; l0 < 256; l0 += 16) {
        for (int idx = tid; idx < 480; idx += 256) {
            int k = idx / 30, c4 = idx % 30;
            size_t pix = (size_t)pix_of(w, l0 + k);
            const float* qp = qv + pix * 240;
            *(float4*)&qc_s[k * 124 + c4 * 4] = *(const float4*)(qp + c4 * 4);
            *(float4*)&vc_s[k * 124 + c4 * 4] = *(const float4*)(qp + 120 + c4 * 4);
        }
        __syncthreads();
#pragma unroll
        for (int k = 0; k < 16; ++k) {
            float4 a0 = *(const float4*)&vc_s[k * 124 + ty * 8];
            float4 a1 = *(const float4*)&vc_s[k * 124 + ty * 8 + 4];
            float4 b0 = *(const float4*)&qc_s[k * 124 + tx * 8];
            float4 b1 = *(const float4*)&qc_s[k * 124 + tx * 8 + 4];
            float av[8] = {a0.x, a0.y, a0.z, a0.w, a1.x, a1.y, a1.z, a1.w};
            float bv[8] = {b0.x, b0.y, b0.z, b0.w, b1.x, b1.y, b1.z, b1.w};
#pragma unroll
            for (int i = 0; i < 8; ++i)
#pragma unroll
                for (int j = 0; j < 8; ++j) acc[i][j] += av[i] * bv[j];
        }
        __syncthreads();
    }
#pragma unroll
    for (int i = 0; i < 8; ++i) {
        int d = ty * 8 + i;
        if (d < 120) {
#pragma unroll
            for (int j4 = 0; j4 < 2; ++j4) {
                int c = tx * 8 + j4 * 4;
                if (c < 120) {
                    float4 o;
                    o.x = acc[i][j4 * 4 + 0]; o.y = acc[i][j4 * 4 + 1];
                    o.z = acc[i][j4 * 4 + 2]; o.w = acc[i][j4 * 4 + 3];
                    *(float4*)&G_s[d * 124 + c] = o;
                }
            }
        }
    }
    __syncthreads();   // G_s complete & visible

    // ---------- phase 2: x_c = vc G / 256  (identical math to xc_kernel) ----------
    for (int mh = 0; mh < 2; ++mh) {
#pragma unroll
        for (int i = 0; i < 8; ++i)
#pragma unroll
            for (int j2 = 0; j2 < 8; ++j2) acc[i][j2] = 0.f;
        for (int k0 = 0; k0 < 120; k0 += 8) {
            {
                int lloc = tid >> 1;
                int kk = (tid & 1) * 4;
                int l = mh * 128 + lloc;
                size_t pix = (size_t)pix_of(w, l);
                float4 v = *(const float4*)(qv + pix * 240 + 120 + k0 + kk);
                a_s[(kk + 0) * 132 + lloc] = v.x;
                a_s[(kk + 1) * 132 + lloc] = v.y;
                a_s[(kk + 2) * 132 + lloc] = v.z;
                a_s[(kk + 3) * 132 + lloc] = v.w;
            }
            __syncthreads();
#pragma unroll
            for (int k = 0; k < 8; ++k) {
                float4 a0 = *(const float4*)&a_s[k * 132 + ty * 8];
                float4 a1 = *(const float4*)&a_s[k * 132 + ty * 8 + 4];
                float4 b0 = *(const float4*)&G_s[(k0 + k) * 124 + tx * 8];
                float4 b1 = *(const float4*)&G_s[(k0 + k) * 124 + tx * 8 + 4];
                float av[8] = {a0.x, a0.y, a0.z, a0.w, a1.x, a1.y, a1.z, a1.w};
                float bv[8] = {b0.x, b0.y, b0.z, b0.w, b1.x, b1.y, b1.z, b1.w};
#pragma unroll
                for (int i = 0; i < 8; ++i)
#pragma unroll
                    for (int j2 = 0; j2 < 8; ++j2) acc[i][j2] += av[i] * bv[j2];
            }
            __syncthreads();
        }
#pragma unroll
        for (int i = 0; i < 8; ++i) {
            int l = mh * 128 + ty * 8 + i;
            size_t pix = (size_t)pix_of(w, l);
            unsigned short* op = cat2 + pix * 512;
#pragma unroll
            for (int j4 = 0; j4 < 2; ++j4) {
                int c = tx * 8 + j4 * 4;
                if (c < 120) {
                    us4 h, lo;
#pragma unroll
                    for (int e = 0; e < 4; ++e) {
                        float v = acc[i][j4 * 4 + e] * (1.f / 256.f);
                        unsigned short hh = bf16rn(v);
                        h[e] = hh;
                        lo[e] = bf16rn(v - bf16tof(hh));
                    }
                    *(us4*)(op + 120 + c) = h;
                    *(us4*)(op + 256 + 120 + c) = lo;
                }
            }
        }
    }
}

extern "C" void kernel_launch(void* const* d_in, const int* in_sizes, int n_in,
                              void* d_out, int out_size, void* d_ws, size_t ws_size,
                              hipStream_t stream)
{
    (void)in_sizes; (void)n_in; (void)out_size;
    const float* x     = (const float*)d_in[0];
    const float* c1_w  = (const float*)d_in[1];
    const float* c1_b  = (const float*)d_in[2];
    const float* c2_w  = (const float*)d_in[3];
    const float* c2_b  = (const float*)d_in[4];
    const float* c3_w  = (const float*)d_in[5];
    const float* c3_b  = (const float*)d_in[6];
    const float* lin_w = (const float*)d_in[7];
    const float* lin_b = (const float*)d_in[8];
    const float* sl_w  = (const float*)d_in[9];
    const float* sl_b  = (const float*)d_in[10];
    const float* pp_w  = (const float*)d_in[11];
    const float* pp_b  = (const float*)d_in[12];
    const float* ln1_g = (const float*)d_in[13];
    const float* ln1_b = (const float*)d_in[14];
    const float* p1_w  = (const float*)d_in[15];
    const float* p1_b  = (const float*)d_in[16];
    const float* ln2_g = (const float*)d_in[17];
    const float* ln2_b = (const float*)d_in[18];
    const float* p2_w  = (const float*)d_in[19];
    const float* p2_b  = (const float*)d_in[20];
    const float* ln3_g = (const float*)d_in[21];
    const float* ln3_b = (const float*)d_in[22];
    const float* p3_w  = (const float*)d_in[23];
    const float* p3_b  = (const float*)d_in[24];
    const float* proj_w = (const float*)d_in[25];
    const float* proj_b = (const float*)d_in[26];

    float* ws = (float*)d_ws;
    // ---------------- workspace layout (float units) ----------------
    // overlays (timeline-checked):
    //   t1s (8,388,608 fl) = head of qvb  [t1s dead after conv2; qvb written by qv]
    //   cat2 = xs2                         [xs2 dead after qv]
    //   (G eliminated: lives in LDS inside corrxc_kernel)
    float* pos3   = ws;                                           // -> 8192
    float* rpb_t  = ws + 8192;                                    // -> 106496
    unsigned short* lin_w2  = (unsigned short*)(ws + 106496);     // 256x512 sh -> 172032
    unsigned short* c3_w2   = (unsigned short*)(ws + 172032);     // 256x128 sh -> 188416
    unsigned short* proj_w2 = (unsigned short*)(ws + 188416);     // 256x512 sh -> 253952
    unsigned short* c1_w2   = (unsigned short*)(ws + 253952);     // 128x512 sh -> 286720
    unsigned short* c2w2    = (unsigned short*)(ws + 286720);     // 432x128 sh -> 314368
    unsigned short* t2s = (unsigned short*)(ws + 314368);         // 8388608 fl -> 8702976
    unsigned short* xs2 = (unsigned short*)(ws + 8702976);        // 33554432 fl -> 42257408
    unsigned short* cat2 = xs2;                                   // overlays xs2
    float* qvb    = ws + 42257408;                                // 31457280 fl -> 73714688
    unsigned short* t1s = (unsigned short*)qvb;                   // overlays qvb head
    const size_t required = (size_t)73714688 * 4;                 // 294.9 MB
    if (ws_size < required) return;

    pack_all_kernel<<<16499, 256, 0, stream>>>(lin_w, proj_w, c3_w, c1_w, c2_w, x,
                                               lin_w2, proj_w2, c3_w2, c1_w2, c2w2, xs2);
    prep_pos_kernel<<<4, 256, 0, stream>>>(pp_w, pp_b, ln1_g, ln1_b, p1_w, p1_b,
                                           ln2_g, ln2_b, p2_w, p2_b, ln3_g, ln3_b,
                                           p3_w, p3_b, pos3);
    rpb_kernel<<<384, 256, 0, stream>>>(pos3, rpb_t);
    conv1_mfma_kernel<<<1024, 256, 0, stream>>>(xs2, c1_w2, c1_b, t1s);
    conv2_mfma_kernel<<<1024, 256, 0, stream>>>(t1s, c2w2, c2_b, t2s);
    qv_mfma_kernel<<<dim3(2, 1024), 256, 0, stream>>>(xs2, lin_w2, lin_b, t2s, c3_w2, c3_b, qvb);
    xs_kernel<<<3072, 256, 0, stream>>>(qvb, rpb_t, sl_w, sl_b, cat2);
    corrxc_kernel<<<512, 256, 0, stream>>>(qvb, cat2);
    proj_mfma_kernel<<<dim3(2, 1024), 256, 0, stream>>>(cat2, proj_w2, proj_b, (float*)d_out);
}

// Round 17
// 509.892 us; speedup vs baseline: 1.1075x; 1.0629x over previous
//
#include <hip/hip_runtime.h>
#include <math.h>

#define NPIX 131072   // 2*256*256

typedef __attribute__((ext_vector_type(8))) short bfrag;
typedef __attribute__((ext_vector_type(4))) float facc;
typedef __attribute__((ext_vector_type(4))) unsigned short us4;

__device__ __forceinline__ float lrelu_f(float x) { return x >= 0.f ? x : 0.2f * x; }

// window w (0..511): b=w>>8, wi=(w>>4)&15, wj=w&15 ; l (0..255): i=l>>4, j=l&15
__device__ __forceinline__ int pix_of(int w, int l) {
    int b = w >> 8, wi = (w >> 4) & 15, wj = w & 15;
    return ((((b << 4) + wi) * 16 + (l >> 4)) << 8) + (wj << 4) + (l & 15);
}

// ---- bf16 split helpers (round-to-nearest-even) ----
__device__ __forceinline__ unsigned short bf16rn(float f) {
    unsigned u = __builtin_bit_cast(unsigned, f);
    u += 0x7FFFu + ((u >> 16) & 1u);
    return (unsigned short)(u >> 16);
}
__device__ __forceinline__ float bf16tof(unsigned short h) {
    unsigned u = ((unsigned)h) << 16;
    return __builtin_bit_cast(float, u);
}

// ---------------- split_x body: fp32 -> packed [hi|lo] bf16 ----------------
// xs2 row: shorts [0,256) = hi(k), [256,512) = lo(k); k>=240 zero.
__device__ __forceinline__ void split_x_body(const float* __restrict__ x,
                                             unsigned short* __restrict__ xs2, int idx)
{
    int row = idx >> 5;
    int k = (idx & 31) * 8;
    float v[8];
    if (k < 240) {
        float4 a = *(const float4*)(x + (size_t)row * 240 + k);
        float4 b = *(const float4*)(x + (size_t)row * 240 + k + 4);
        v[0] = a.x; v[1] = a.y; v[2] = a.z; v[3] = a.w;
        v[4] = b.x; v[5] = b.y; v[6] = b.z; v[7] = b.w;
    } else {
#pragma unroll
        for (int e = 0; e < 8; ++e) v[e] = 0.f;
    }
    bfrag hi, lo;
#pragma unroll
    for (int e = 0; e < 8; ++e) {
        unsigned short h = bf16rn(v[e]);
        hi[e] = (short)h;
        lo[e] = (short)bf16rn(v[e] - bf16tof(h));
    }
    unsigned short* dst = xs2 + (size_t)row * 512 + k;
    *(bfrag*)(dst) = hi;
    *(bfrag*)(dst + 256) = lo;
}

// generic weight pack body: src [rows][K] fp32 -> dst [rows_pad][2*KPAD] shorts (zero padded)
__device__ __forceinline__ void pack_w_body(const float* __restrict__ src,
                                            int rows, int K,
                                            unsigned short* __restrict__ dst,
                                            int total8, int KPAD, int idx)
{
    if (idx >= total8) return;
    int kper = KPAD >> 3;
    int row = idx / kper;
    int k = (idx - row * kper) * 8;
    float v[8];
#pragma unroll
    for (int e = 0; e < 8; ++e) {
        int kk = k + e;
        v[e] = (row < rows && kk < K) ? src[(size_t)row * K + kk] : 0.f;
    }
    bfrag hi, lo;
#pragma unroll
    for (int e = 0; e < 8; ++e) {
        unsigned short h = bf16rn(v[e]);
        hi[e] = (short)h;
        lo[e] = (short)bf16rn(v[e] - bf16tof(h));
    }
    unsigned short* d = dst + (size_t)row * 2 * KPAD + k;
    *(bfrag*)(d) = hi;
    *(bfrag*)(d + KPAD) = lo;
}

// c2 weights body -> c2w2[tap][n][ hi64 | lo64 ]  (tap = ky*3+kx; ci pad 48..63 = 0)
__device__ __forceinline__ void pack_c2w_body(const float* __restrict__ c2_w,
                                              unsigned short* __restrict__ c2w2, int idx)
{
    if (idx >= 6912) return;
    int rowid = idx >> 4;          // tap*48 + n
    int c = idx & 15;
    int tap = rowid / 48, n = rowid - tap * 48;
    int ty = tap / 3, tx = tap - ty * 3;
    int lohalf = c >> 3;
    int cbase = (c & 7) * 8;
    bfrag outv;
#pragma unroll
    for (int e = 0; e < 8; ++e) {
        int ci = cbase + e;
        float v = (ci < 48) ? c2_w[(((size_t)n * 48 + ci) * 3 + ty) * 3 + tx] : 0.f;
        unsigned short h = bf16rn(v);
        outv[e] = (short)(lohalf ? bf16rn(v - bf16tof(h)) : h);
    }
    *(bfrag*)(c2w2 + (size_t)rowid * 128 + c * 8) = outv;
}

// merged pre-pass kernel: weight packs (blocks 0..114) + split_x (blocks 115..16498)
__global__ __launch_bounds__(256) void pack_all_kernel(
    const float* __restrict__ lin_w, const float* __restrict__ proj_w,
    const float* __restrict__ c3_w, const float* __restrict__ c1_w,
    const float* __restrict__ c2_w, const float* __restrict__ x,
    unsigned short* __restrict__ lin_w2, unsigned short* __restrict__ proj_w2,
    unsigned short* __restrict__ c3_w2, unsigned short* __restrict__ c1_w2,
    unsigned short* __restrict__ c2w2, unsigned short* __restrict__ xs2)
{
    int blk = blockIdx.x, tid = threadIdx.x;
    if (blk < 32)       pack_w_body(lin_w, 240, 240, lin_w2, 8192, 256, blk * 256 + tid);
    else if (blk < 64)  pack_w_body(proj_w, 240, 240, proj_w2, 8192, 256, (blk - 32) * 256 + tid);
    else if (blk < 72)  pack_w_body(c3_w, 240, 48, c3_w2, 2048, 64, (blk - 64) * 256 + tid);
    else if (blk < 88)  pack_w_body(c1_w, 48, 240, c1_w2, 4096, 256, (blk - 72) * 256 + tid);
    else if (blk < 115) pack_c2w_body(c2_w, c2w2, (blk - 88) * 256 + tid);
    else                split_x_body(x, xs2, (blk - 115) * 256 + tid);
}

// ---------------- prep: DynamicPosBias MLP ----------------
__device__ __forceinline__ void ln_relu15(const float* h, float* r,
                                          const float* __restrict__ g,
                                          const float* __restrict__ b) {
    float m = 0.f;
#pragma unroll
    for (int f = 0; f < 15; ++f) m += h[f];
    m *= (1.f / 15.f);
    float v = 0.f;
#pragma unroll
    for (int f = 0; f < 15; ++f) { float d = h[f] - m; v += d * d; }
    float rs = rsqrtf(v * (1.f / 15.f) + 1e-5f);
#pragma unroll
    for (int f = 0; f < 15; ++f) {
        float xx = (h[f] - m) * rs * g[f] + b[f];
        r[f] = xx > 0.f ? xx : 0.f;
    }
}

__device__ __forceinline__ void lin15(const float* r, float* h,
                                      const float* __restrict__ w,
                                      const float* __restrict__ b) {
#pragma unroll
    for (int o = 0; o < 15; ++o) {
        float s = b[o];
#pragma unroll
        for (int g = 0; g < 15; ++g) s += r[g] * w[o * 15 + g];
        h[o] = s;
    }
}

__global__ __launch_bounds__(256) void prep_pos_kernel(
    const float* __restrict__ pp_w, const float* __restrict__ pp_b,
    const float* __restrict__ ln1_g, const float* __restrict__ ln1_b,
    const float* __restrict__ p1_w, const float* __restrict__ p1_b,
    const float* __restrict__ ln2_g, const float* __restrict__ ln2_b,
    const float* __restrict__ p2_w, const float* __restrict__ p2_b,
    const float* __restrict__ ln3_g, const float* __restrict__ ln3_b,
    const float* __restrict__ p3_w, const float* __restrict__ p3_b,
    float* __restrict__ pos3)
{
    int idx = blockIdx.x * 256 + threadIdx.x;
    if (idx >= 961) return;
    float h[15], r[15];
    float in0 = (float)(idx / 31) - 15.f;
    float in1 = (float)(idx % 31) - 15.f;
#pragma unroll
    for (int f = 0; f < 15; ++f) h[f] = in0 * pp_w[2 * f] + in1 * pp_w[2 * f + 1] + pp_b[f];
    ln_relu15(h, r, ln1_g, ln1_b);
    lin15(r, h, p1_w, p1_b);
    ln_relu15(h, r, ln2_g, ln2_b);
    lin15(r, h, p2_w, p2_b);
    ln_relu15(h, r, ln3_g, ln3_b);
#pragma unroll
    for (int o = 0; o < 6; ++o) {
        float s = p3_b[o];
#pragma unroll
        for (int g = 0; g < 15; ++g) s += r[g] * p3_w[o * 15 + g];
        pos3[idx * 6 + o] = s;
    }
}

// rpb_t[n][k][l]  (n<6, k<64 base-window key, l<256 query pos)
__global__ __launch_bounds__(256) void rpb_kernel(const float* __restrict__ pos3,
                                                  float* __restrict__ rpb_t)
{
    int out = blockIdx.x * 256 + threadIdx.x;   // < 98304
    int n = out >> 14;
    int k = (out >> 8) & 63;
    int l = out & 255;
    int a = k >> 3, c = k & 7;
    int i1 = l >> 4, j1 = l & 15;
    float s = 0.f;
#pragma unroll
    for (int bb = 0; bb < 2; ++bb)
#pragma unroll
        for (int d = 0; d < 2; ++d) {
            int i2 = a * 2 + bb, j2 = c * 2 + d;
            int rpi = (i1 - i2 + 15) * 31 + (j1 - j2 + 15);
            s += pos3[rpi * 6 + n];
        }
    rpb_t[out] = s * 0.25f;
}

// ---------------- MFMA split-bf16 NT GEMM core, BM=128 BN=128 (R11 known-good) ----------------
__device__ __forceinline__ void mfma_kpass3(const unsigned short* __restrict__ A2, int lda2,
                                            const unsigned short* __restrict__ W2, int ldw2,
                                            int ksteps, int mbase, int nbase,
                                            short* lds_a, short* lds_w,
                                            int tid, int wm, int wn,
                                            facc acc[4][4])
{
    int lane = tid & 63;
    int i = lane & 15, g = lane >> 4;
    int kpa = lda2 >> 1, kpw = ldw2 >> 1;
    for (int s = 0; s < ksteps; ++s) {
        int k0 = s * 32;
        {
            int r = tid >> 1, h16 = (tid & 1) * 16;
            const unsigned short* src = A2 + (size_t)(mbase + r) * lda2 + k0 + h16;
            bfrag h0 = *(const bfrag*)(src);
            bfrag h1 = *(const bfrag*)(src + 8);
            bfrag l0 = *(const bfrag*)(src + kpa);
            bfrag l1 = *(const bfrag*)(src + kpa + 8);
            short* dst = lds_a + r * 72 + h16;
            *(bfrag*)(dst)      = h0;  *(bfrag*)(dst + 8)  = h1;
            *(bfrag*)(dst + 32) = l0;  *(bfrag*)(dst + 40) = l1;
        }
        {
            int r = tid >> 1, half = tid & 1;
            const unsigned short* src = W2 + (size_t)(nbase + r) * ldw2 + half * kpw + k0;
            bfrag v0 = *(const bfrag*)(src);
            bfrag v1 = *(const bfrag*)(src + 8);
            bfrag v2 = *(const bfrag*)(src + 16);
            bfrag v3 = *(const bfrag*)(src + 24);
            short* dst = lds_w + r * 72 + half * 32;
            *(bfrag*)(dst)      = v0;  *(bfrag*)(dst + 8)  = v1;
            *(bfrag*)(dst + 16) = v2;  *(bfrag*)(dst + 24) = v3;
        }
        __syncthreads();
        bfrag ah[4], al[4], bh[4], bl[4];
#pragma unroll
        for (int mu = 0; mu < 4; ++mu) {
            const short* p = lds_a + (wm * 64 + mu * 16 + i) * 72 + g * 8;
            ah[mu] = *(const bfrag*)(p);
            al[mu] = *(const bfrag*)(p + 32);
        }
#pragma unroll
        for (int nu = 0; nu < 4; ++nu) {
            const short* p = lds_w + (wn * 64 + nu * 16 + i) * 72 + g * 8;
            bh[nu] = *(const bfrag*)(p);
            bl[nu] = *(const bfrag*)(p + 32);
        }
#pragma unroll
        for (int mu = 0; mu < 4; ++mu)
#pragma unroll
            for (int nu = 0; nu < 4; ++nu) {
                acc[mu][nu] = __builtin_amdgcn_mfma_f32_16x16x32_bf16(ah[mu], bh[nu], acc[mu][nu], 0, 0, 0);
                acc[mu][nu] = __builtin_amdgcn_mfma_f32_16x16x32_bf16(ah[mu], bl[nu], acc[mu][nu], 0, 0, 0);
                acc[mu][nu] = __builtin_amdgcn_mfma_f32_16x16x32_bf16(al[mu], bh[nu], acc[mu][nu], 0, 0, 0);
            }
        __syncthreads();
    }
}

// ---------------- BN=64 variant (conv1): simple 2-barrier loop, 4 waves = 2x2 ----------------
__device__ __forceinline__ void mfma_kpass_n64(const unsigned short* __restrict__ A2, int lda2,
                                               const unsigned short* __restrict__ W2, int ldw2,
                                               int ksteps, int mbase,
                                               short* lds_a, short* lds_w,
                                               int tid, int wm, int wn,
                                               facc acc[4][2])
{
    int lane = tid & 63;
    int i = lane & 15, g = lane >> 4;
    int kpa = lda2 >> 1, kpw = ldw2 >> 1;
    for (int s = 0; s < ksteps; ++s) {
        int k0 = s * 32;
        {
            int r = tid >> 1, h16 = (tid & 1) * 16;
            const unsigned short* src = A2 + (size_t)(mbase + r) * lda2 + k0 + h16;
            bfrag h0 = *(const bfrag*)(src);
            bfrag h1 = *(const bfrag*)(src + 8);
            bfrag l0 = *(const bfrag*)(src + kpa);
            bfrag l1 = *(const bfrag*)(src + kpa + 8);
            short* dst = lds_a + r * 72 + h16;
            *(bfrag*)(dst)      = h0;  *(bfrag*)(dst + 8)  = h1;
            *(bfrag*)(dst + 32) = l0;  *(bfrag*)(dst + 40) = l1;
        }
        if (tid < 128) {
            int r = tid >> 1, half = tid & 1;
            const unsigned short* src = W2 + (size_t)r * ldw2 + half * kpw + k0;
            bfrag v0 = *(const bfrag*)(src);
            bfrag v1 = *(const bfrag*)(src + 8);
            bfrag v2 = *(const bfrag*)(src + 16);
            bfrag v3 = *(const bfrag*)(src + 24);
            short* dst = lds_w + r * 72 + half * 32;
            *(bfrag*)(dst)      = v0;  *(bfrag*)(dst + 8)  = v1;
            *(bfrag*)(dst + 16) = v2;  *(bfrag*)(dst + 24) = v3;
        }
        __syncthreads();
        bfrag ah[4], al[4], bh[2], bl[2];
#pragma unroll
        for (int mu = 0; mu < 4; ++mu) {
            const short* p = lds_a + (wm * 64 + mu * 16 + i) * 72 + g * 8;
            ah[mu] = *(const bfrag*)(p);
            al[mu] = *(const bfrag*)(p + 32);
        }
#pragma unroll
        for (int nu = 0; nu < 2; ++nu) {
            const short* p = lds_w + (wn * 32 + nu * 16 + i) * 72 + g * 8;
            bh[nu] = *(const bfrag*)(p);
            bl[nu] = *(const bfrag*)(p + 32);
        }
#pragma unroll
        for (int mu = 0; mu < 4; ++mu)
#pragma unroll
            for (int nu = 0; nu < 2; ++nu) {
                acc[mu][nu] = __builtin_amdgcn_mfma_f32_16x16x32_bf16(ah[mu], bh[nu], acc[mu][nu], 0, 0, 0);
                acc[mu][nu] = __builtin_amdgcn_mfma_f32_16x16x32_bf16(ah[mu], bl[nu], acc[mu][nu], 0, 0, 0);
                acc[mu][nu] = __builtin_amdgcn_mfma_f32_16x16x32_bf16(al[mu], bh[nu], acc[mu][nu], 0, 0, 0);
            }
        __syncthreads();
    }
}

// conv1: t1s = split(lrelu(x @ c1_w^T + c1_b)) packed [hi64|lo64], N=48 (BN=64)
__global__ __launch_bounds__(256, 3) void conv1_mfma_kernel(const unsigned short* __restrict__ xs2,
    const unsigned short* __restrict__ c1_w2, const float* __restrict__ bias,
    unsigned short* __restrict__ t1s)
{
    __shared__ __align__(16) short lds_a[128 * 72];
    __shared__ __align__(16) short lds_w[64 * 72];
    int tid = threadIdx.x;
    int lane = tid & 63, wid = tid >> 6;
    int wm = wid >> 1, wn = wid & 1;
    int mbase = blockIdx.x * 128;
    facc zero = {0.f, 0.f, 0.f, 0.f};
    facc acc[4][2];
#pragma unroll
    for (int mu = 0; mu < 4; ++mu)
#pragma unroll
        for (int nu = 0; nu < 2; ++nu) acc[mu][nu] = zero;

    mfma_kpass_n64(xs2, 512, c1_w2, 512, 8, mbase, lds_a, lds_w, tid, wm, wn, acc);

    int i = lane & 15, g = lane >> 4;
#pragma unroll
    for (int nu = 0; nu < 2; ++nu) {
        int n = wn * 32 + nu * 16 + i;
        if (n < 48) {
            float bv = bias[n];
#pragma unroll
            for (int mu = 0; mu < 4; ++mu)
#pragma unroll
                for (int rr = 0; rr < 4; ++rr) {
                    size_t m = (size_t)mbase + wm * 64 + mu * 16 + g * 4 + rr;
                    float v = lrelu_f(acc[mu][nu][rr] + bv);
                    unsigned short h = bf16rn(v);
                    t1s[m * 128 + n] = h;
                    t1s[m * 128 + 64 + n] = bf16rn(v - bf16tof(h));
                }
        }
    }
    if (tid < 128) {
        size_t m = (size_t)mbase + tid;
        bfrag z = {0, 0, 0, 0, 0, 0, 0, 0};
        *(bfrag*)(t1s + m * 128 + 48)  = z;
        *(bfrag*)(t1s + m * 128 + 56)  = z;
        *(bfrag*)(t1s + m * 128 + 112) = z;
        *(bfrag*)(t1s + m * 128 + 120) = z;
    }
}

// conv2: 3x3 48->48 as MFMA shifted-GEMM.  block = 128 pixels (half image row).
__global__ __launch_bounds__(256) void conv2_mfma_kernel(const unsigned short* __restrict__ t1s,
    const unsigned short* __restrict__ c2w2, const float* __restrict__ bias,
    unsigned short* __restrict__ t2s)
{
    __shared__ __align__(16) short a_s[130 * 128];
    int bid = blockIdx.x;
    int xcd = bid & 7;
    int j = bid >> 3;
    int half = j & 1;
    int rl = (j >> 1) & 31;
    int b = j >> 6;
    int r = xcd * 32 + rl;
    int c0 = half * 128;
    int tid = threadIdx.x;
    int lane = tid & 63, wid = tid >> 6;
    int i = lane & 15, g = lane >> 4;
    facc zero = {0.f, 0.f, 0.f, 0.f};
    facc acc[2][3];
#pragma unroll
    for (int mu = 0; mu < 2; ++mu)
#pragma unroll
        for (int nu = 0; nu < 3; ++nu) acc[mu][nu] = zero;

    for (int dy = 0; dy < 3; ++dy) {
        int grow = r + dy - 1;
        bool rowok = (grow >= 0 && grow < 256);
        for (int idx = tid; idx < 130 * 16; idx += 256) {
            int j2 = idx >> 4, ch = idx & 15;
            int gc = c0 - 1 + j2;
            bfrag v = {0, 0, 0, 0, 0, 0, 0, 0};
            if (rowok && gc >= 0 && gc < 256) {
                size_t gpix = ((size_t)b * 256 + grow) * 256 + gc;
                v = *(const bfrag*)(t1s + gpix * 128 + ch * 8);
            }
            *(bfrag*)&a_s[j2 * 128 + ((ch ^ (j2 & 7)) * 8)] = v;
        }
        __syncthreads();
#pragma unroll
        for (int dx = 0; dx < 3; ++dx) {
            const unsigned short* wb = c2w2 + (size_t)(dy * 3 + dx) * 48 * 128;
#pragma unroll
            for (int h = 0; h < 2; ++h) {
                bfrag ah[2], al[2], bh[3], bl[3];
#pragma unroll
                for (int mu = 0; mu < 2; ++mu) {
                    int j2 = wid * 32 + mu * 16 + i + dx;
                    int chi = (h * 4 + g) ^ (j2 & 7);
                    int clo = (8 + h * 4 + g) ^ (j2 & 7);
                    ah[mu] = *(const bfrag*)&a_s[j2 * 128 + chi * 8];
                    al[mu] = *(const bfrag*)&a_s[j2 * 128 + clo * 8];
                }
#pragma unroll
                for (int nu = 0; nu < 3; ++nu) {
                    const unsigned short* wp = wb + (size_t)(nu * 16 + i) * 128 + h * 32 + g * 8;
                    bh[nu] = *(const bfrag*)(wp);
                    bl[nu] = *(const bfrag*)(wp + 64);
                }
#pragma unroll
                for (int mu = 0; mu < 2; ++mu)
#pragma unroll
                    for (int nu = 0; nu < 3; ++nu) {
                        acc[mu][nu] = __builtin_amdgcn_mfma_f32_16x16x32_bf16(ah[mu], bh[nu], acc[mu][nu], 0, 0, 0);
                        acc[mu][nu] = __builtin_amdgcn_mfma_f32_16x16x32_bf16(ah[mu], bl[nu], acc[mu][nu], 0, 0, 0);
                        acc[mu][nu] = __builtin_amdgcn_mfma_f32_16x16x32_bf16(al[mu], bh[nu], acc[mu][nu], 0, 0, 0);
                    }
            }
        }
        __syncthreads();
    }
#pragma unroll
    for (int nu = 0; nu < 3; ++nu) {
        int n = nu * 16 + i;
        float bv = bias[n];
#pragma unroll
        for (int mu = 0; mu < 2; ++mu)
#pragma unroll
            for (int rr = 0; rr < 4; ++rr) {
                int lp = wid * 32 + mu * 16 + g * 4 + rr;
                size_t gpix = ((size_t)b * 256 + r) * 256 + (c0 + lp);
                float v = lrelu_f(acc[mu][nu][rr] + bv);
                unsigned short h = bf16rn(v);
                t2s[gpix * 128 + n] = h;
                t2s[gpix * 128 + 64 + n] = bf16rn(v - bf16tof(h));
            }
    }
    if (tid < 128) {
        size_t gpix = ((size_t)b * 256 + r) * 256 + (c0 + tid);
        bfrag z = {0, 0, 0, 0, 0, 0, 0, 0};
        *(bfrag*)(t2s + gpix * 128 + 48)  = z;
        *(bfrag*)(t2s + gpix * 128 + 56)  = z;
        *(bfrag*)(t2s + gpix * 128 + 112) = z;
        *(bfrag*)(t2s + gpix * 128 + 120) = z;
    }
}

// qv = (t2 @ c3_w^T + c3_b) * (x @ lin_w^T + lin_b)   [MFMA, BN=128, XCD-swizzled]
__global__ __launch_bounds__(256) void qv_mfma_kernel(const unsigned short* __restrict__ xs2,
    const unsigned short* __restrict__ lin_w2, const float* __restrict__ lin_b,
    const unsigned short* __restrict__ t2s, const unsigned short* __restrict__ c3_w2,
    const float* __restrict__ c3_b, float* __restrict__ qv)
{
    __shared__ __align__(16) short lds_a[128 * 72];
    __shared__ __align__(16) short lds_w[128 * 72];
    int tid = threadIdx.x;
    int lane = tid & 63, wid = tid >> 6;
    int wm = wid >> 1, wn = wid & 1;
    int bid = blockIdx.y * 2 + blockIdx.x;
    int xcd = bid & 7, j = bid >> 3;
    int mbase = (xcd * 128 + (j >> 1)) * 128;
    int nbase = (j & 1) * 128;
    facc zero = {0.f, 0.f, 0.f, 0.f};
    facc acc1[4][4], acc2[4][4];
#pragma unroll
    for (int mu = 0; mu < 4; ++mu)
#pragma unroll
        for (int nu = 0; nu < 4; ++nu) { acc1[mu][nu] = zero; acc2[mu][nu] = zero; }

    mfma_kpass3(xs2, 512, lin_w2, 512, 8, mbase, nbase, lds_a, lds_w, tid, wm, wn, acc1);
    mfma_kpass3(t2s, 128, c3_w2, 128, 2, mbase, nbase, lds_a, lds_w, tid, wm, wn, acc2);

    int i = lane & 15, g = lane >> 4;
#pragma unroll
    for (int nu = 0; nu < 4; ++nu) {
        int n = nbase + wn * 64 + nu * 16 + i;
        if (n < 240) {
            float lb = lin_b[n], cb = c3_b[n];
#pragma unroll
            for (int mu = 0; mu < 4; ++mu)
#pragma unroll
                for (int rr = 0; rr < 4; ++rr) {
                    size_t m = (size_t)mbase + wm * 64 + mu * 16 + g * 4 + rr;
                    qv[m * 240 + n] = (acc2[mu][nu][rr] + cb) * (acc1[mu][nu][rr] + lb);
                }
        }
    }
}

// proj: out = cat2 @ proj_w^T + proj_b   [MFMA, BN=128, XCD-swizzled]
__global__ __launch_bounds__(256, 3) void proj_mfma_kernel(const unsigned short* __restrict__ cat2,
    const unsigned short* __restrict__ proj_w2, const float* __restrict__ bias,
    float* __restrict__ out)
{
    __shared__ __align__(16) short lds_a[128 * 72];
    __shared__ __align__(16) short lds_w[128 * 72];
    int tid = threadIdx.x;
    int lane = tid & 63, wid = tid >> 6;
    int wm = wid >> 1, wn = wid & 1;
    int bid = blockIdx.y * 2 + blockIdx.x;
    int xcd = bid & 7, j = bid >> 3;
    int mbase = (xcd * 128 + (j >> 1)) * 128;
    int nbase = (j & 1) * 128;
    facc zero = {0.f, 0.f, 0.f, 0.f};
    facc acc[4][4];
#pragma unroll
    for (int mu = 0; mu < 4; ++mu)
#pragma unroll
        for (int nu = 0; nu < 4; ++nu) acc[mu][nu] = zero;

    mfma_kpass3(cat2, 512, proj_w2, 512, 8, mbase, nbase, lds_a, lds_w, tid, wm, wn, acc);

    int i = lane & 15, g = lane >> 4;
#pragma unroll
    for (int nu = 0; nu < 4; ++nu) {
        int n = nbase + wn * 64 + nu * 16 + i;
        if (n < 240) {
            float bv = bias[n];
#pragma unroll
            for (int mu = 0; mu < 4; ++mu)
#pragma unroll
                for (int rr = 0; rr < 4; ++rr) {
                    size_t m = (size_t)mbase + wm * 64 + mu * 16 + g * 4 + rr;
                    out[m * 240 + n] = acc[mu][nu][rr] + bv;
                }
        }
    }
}

// spatial correlation: per (window, head) -> cat2 channels [n*20, n*20+20) split-bf16
__global__ __launch_bounds__(256) void xs_kernel(const float* __restrict__ qv,
    const float* __restrict__ rpb_t, const float* __restrict__ sl_w,
    const float* __restrict__ sl_b, unsigned short* __restrict__ cat2)
{
    __shared__ __align__(16) float v_s[256 * 20];
    __shared__ __align__(16) float vs_s[64 * 20];
    int bid = blockIdx.x;
    int xcd = bid & 7;
    int j = bid >> 3;
    int wl = j / 6;
    int n = j - wl * 6;
    int w = xcd * 64 + wl;
    int tid = threadIdx.x;
    int l = tid;
    size_t pix = (size_t)pix_of(w, l);
    const float* qp = qv + pix * 240 + n * 20;
    float qr[20];
#pragma unroll
    for (int h4 = 0; h4 < 5; ++h4) {
        *(float4*)&qr[h4 * 4] = *(const float4*)(qp + h4 * 4);
        *(float4*)&v_s[l * 20 + h4 * 4] = *(const float4*)(qp + 120 + h4 * 4);
    }
    __syncthreads();
    float slw0 = sl_w[0], slw1 = sl_w[1], slw2 = sl_w[2], slw3 = sl_w[3];
    float slb = sl_b[0];
    for (int idx = tid; idx < 1280; idx += 256) {
        int k = idx / 20, hd = idx % 20;
        int a = k >> 3, c = k & 7;
        int l00 = a * 32 + c * 2;
        float vsum = slb
                   + slw0 * v_s[(l00 + 0) * 20 + hd]
                   + slw1 * v_s[(l00 + 1) * 20 + hd]
                   + slw2 * v_s[(l00 + 16) * 20 + hd]
                   + slw3 * v_s[(l00 + 17) * 20 + hd];
        vs_s[idx] = vsum;
    }
    __syncthreads();
    const float* rp = rpb_t + (size_t)n * 16384 + l;
    float acc[20];
#pragma unroll
    for (int hd = 0; hd < 20; ++hd) acc[hd] = 0.f;
#pragma unroll
    for (int k = 0; k < 64; ++k) {
        float vr[20];
#pragma unroll
        for (int h4 = 0; h4 < 5; ++h4)
            *(float4*)&vr[h4 * 4] = *(const float4*)&vs_s[k * 20 + h4 * 4];
        float s0 = 0.f, s1 = 0.f, s2 = 0.f, s3 = 0.f;
#pragma unroll
        for (int hd = 0; hd < 20; hd += 4) {
            s0 += qr[hd + 0] * vr[hd + 0];
            s1 += qr[hd + 1] * vr[hd + 1];
            s2 += qr[hd + 2] * vr[hd + 2];
            s3 += qr[hd + 3] * vr[hd + 3];
        }
        float cc = (s0 + s1 + s2 + s3) * (1.f / 20.f) + rp[(size_t)k * 256];
#pragma unroll
        for (int hd = 0; hd < 20; ++hd) acc[hd] += cc * vr[hd];
    }
    unsigned short* op = cat2 + pix * 512 + n * 20;
#pragma unroll
    for (int h4 = 0; h4 < 5; ++h4) {
        us4 h, lo;
#pragma unroll
        for (int e = 0; e < 4; ++e) {
            float v = acc[h4 * 4 + e];
            unsigned short hh = bf16rn(v);
            h[e] = hh;
            lo[e] = bf16rn(v - bf16tof(hh));
        }
        *(us4*)(op + h4 * 4) = h;
        *(us4*)(op + 256 + h4 * 4) = lo;
    }
    if (n == 0) {
        bfrag z = {0, 0, 0, 0, 0, 0, 0, 0};
        unsigned short* zp = cat2 + pix * 512;
        *(bfrag*)(zp + 240) = z;  *(bfrag*)(zp + 248) = z;
        *(bfrag*)(zp + 496) = z;  *(bfrag*)(zp + 504) = z;
    }
}

// FUSED channel correlation, full MFMA split-bf16.
// Phase 1: G[d][c] = sum_l vc[l][d] qc[l][c]  (M=d,N=c,K=l=256) -> G^T split-bf16 in LDS.
// Phase 2: x_c[l][c] = (1/256) sum_d vc[l][d] G[d][c]  (M=l per mh-half, N=c, K=d=128).
// LDS (dynamic, 86,016 B): lds_g [128c x 264] (hi d[0,128), lo d[128,256), pad);
// phase1 a/w buffers alias lds_g (time-disjoint); phase2 A at +33792.
// d/c pads >=120 are zero in A-operands => garbage in pad regions is never observable.
__global__ __launch_bounds__(256) void corrxc_kernel(const float* __restrict__ qv,
                                                     unsigned short* __restrict__ cat2)
{
    extern __shared__ short smem[];
    short* lds_g = smem;             // [0, 33792)
    short* ph1_a = smem;             // [0, 9216)   phase1 only
    short* ph1_w = smem + 9216;      // [9216, 18432) phase1 only
    short* ph2_a = smem + 33792;     // [33792, 43008)

    int bid = blockIdx.x;            // 512 = 8 * 64
    int w = (bid & 7) * 64 + (bid >> 3);
    int tid = threadIdx.x;
    int lane = tid & 63, wid = tid >> 6;
    int wm = wid >> 1, wn = wid & 1;
    int i = lane & 15, g = lane >> 4;
    facc zero = {0.f, 0.f, 0.f, 0.f};
    facc acc[4][4];
#pragma unroll
    for (int mu = 0; mu < 4; ++mu)
#pragma unroll
        for (int nu = 0; nu < 4; ++nu) acc[mu][nu] = zero;

    // ---------------- phase 1 ----------------
    for (int l0 = 0; l0 < 256; l0 += 32) {
        int dl = tid & 31;
        int ch0 = (tid >> 5) * 16;
        const float* qp = qv + (size_t)pix_of(w, l0 + dl) * 240;
#pragma unroll
        for (int j4 = 0; j4 < 4; ++j4) {
            int c0 = ch0 + j4 * 4;
            float4 fa = make_float4(0.f, 0.f, 0.f, 0.f);
            float4 fb = make_float4(0.f, 0.f, 0.f, 0.f);
            if (c0 < 120) {                      // c0 multiple of 4; 120%4==0 => all-or-none
                fa = *(const float4*)(qp + 120 + c0);   // vc
                fb = *(const float4*)(qp + c0);         // qc
            }
            float ea[4] = {fa.x, fa.y, fa.z, fa.w};
            float eb[4] = {fb.x, fb.y, fb.z, fb.w};
#pragma unroll
            for (int e = 0; e < 4; ++e) {
                int ch = c0 + e;
                unsigned short h = bf16rn(ea[e]);
                ph1_a[ch * 72 + dl]      = (short)h;
                ph1_a[ch * 72 + 32 + dl] = (short)bf16rn(ea[e] - bf16tof(h));
                h = bf16rn(eb[e]);
                ph1_w[ch * 72 + dl]      = (short)h;
                ph1_w[ch * 72 + 32 + dl] = (short)bf16rn(eb[e] - bf16tof(h));
            }
        }
        __syncthreads();
        bfrag ah[4], al2[4], bh[4], bl2[4];
#pragma unroll
        for (int mu = 0; mu < 4; ++mu) {
            const short* p = ph1_a + (wm * 64 + mu * 16 + i) * 72 + g * 8;
            ah[mu] = *(const bfrag*)(p);
            al2[mu] = *(const bfrag*)(p + 32);
        }
#pragma unroll
        for (int nu = 0; nu < 4; ++nu) {
            const short* p = ph1_w + (wn * 64 + nu * 16 + i) * 72 + g * 8;
            bh[nu] = *(const bfrag*)(p);
            bl2[nu] = *(const bfrag*)(p + 32);
        }
#pragma unroll
        for (int mu = 0; mu < 4; ++mu)
#pragma unroll
            for (int nu = 0; nu < 4; ++nu) {
                acc[mu][nu] = __builtin_amdgcn_mfma_f32_16x16x32_bf16(ah[mu], bh[nu], acc[mu][nu], 0, 0, 0);
                acc[mu][nu] = __builtin_amdgcn_mfma_f32_16x16x32_bf16(ah[mu], bl2[nu], acc[mu][nu], 0, 0, 0);
                acc[mu][nu] = __builtin_amdgcn_mfma_f32_16x16x32_bf16(al2[mu], bh[nu], acc[mu][nu], 0, 0, 0);
            }
        __syncthreads();
    }
    // G^T split-bf16 -> lds_g  (phase1 a/w dead; all waves past last barrier)
#pragma unroll
    for (int mu = 0; mu < 4; ++mu)
#pragma unroll
        for (int nu = 0; nu < 4; ++nu)
#pragma unroll
            for (int rr = 0; rr < 4; ++rr) {
                int d = wm * 64 + mu * 16 + g * 4 + rr;
                int c = wn * 64 + nu * 16 + i;
                float v = acc[mu][nu][rr];
                unsigned short h = bf16rn(v);
                lds_g[c * 264 + d]       = (short)h;
                lds_g[c * 264 + 128 + d] = (short)bf16rn(v - bf16tof(h));
            }

    // ---------------- phase 2 ----------------
    for (int mh = 0; mh < 2; ++mh) {
#pragma unroll
        for (int mu = 0; mu < 4; ++mu)
#pragma unroll
            for (int nu = 0; nu < 4; ++nu) acc[mu][nu] = zero;
        for (int k0 = 0; k0 < 128; k0 += 32) {
            {   // stage A: rows l-local, [32 hi][32 lo] of d-chunk; d contiguous in qv
                int r = tid >> 1, h16 = (tid & 1) * 16;
                const float* qp = qv + (size_t)pix_of(w, mh * 128 + r) * 240 + 120;
                float v[16];
#pragma unroll
                for (int j4 = 0; j4 < 4; ++j4) {
                    int d0 = k0 + h16 + j4 * 4;
                    float4 f = make_float4(0.f, 0.f, 0.f, 0.f);
                    if (d0 < 120) f = *(const float4*)(qp + d0);
                    v[j4 * 4 + 0] = f.x; v[j4 * 4 + 1] = f.y;
                    v[j4 * 4 + 2] = f.z; v[j4 * 4 + 3] = f.w;
                }
                bfrag h0, h1, lo0, lo1;
#pragma unroll
                for (int e = 0; e < 8; ++e) {
                    unsigned short h = bf16rn(v[e]);
                    h0[e] = (short)h;
                    lo0[e] = (short)bf16rn(v[e] - bf16tof(h));
                    h = bf16rn(v[8 + e]);
                    h1[e] = (short)h;
                    lo1[e] = (short)bf16rn(v[8 + e] - bf16tof(h));
                }
                short* dst = ph2_a + r * 72 + h16;
                *(bfrag*)(dst)      = h0;  *(bfrag*)(dst + 8)  = h1;
                *(bfrag*)(dst + 32) = lo0; *(bfrag*)(dst + 40) = lo1;
            }
            __syncthreads();   // also orders lds_g writes before first reads
            bfrag ah[4], al2[4], bh[4], bl2[4];
#pragma unroll
            for (int mu = 0; mu < 4; ++mu) {
                const short* p = ph2_a + (wm * 64 + mu * 16 + i) * 72 + g * 8;
                ah[mu] = *(const bfrag*)(p);
                al2[mu] = *(const bfrag*)(p + 32);
            }
#pragma unroll
            for (int nu = 0; nu < 4; ++nu) {
                const short* p = lds_g + (wn * 64 + nu * 16 + i) * 264 + k0 + g * 8;
                bh[nu] = *(const bfrag*)(p);
                bl2[nu] = *(const bfrag*)(p + 128);
            }
#pragma unroll
            for (int mu = 0; mu < 4; ++mu)
#pragma unroll
                for (int nu = 0; nu < 4; ++nu) {
                    acc[mu][nu] = __builtin_amdgcn_mfma_f32_16x16x32_bf16(ah[mu], bh[nu], acc[mu][nu], 0, 0, 0);
                    acc[mu][nu] = __builtin_amdgcn_mfma_f32_16x16x32_bf16(ah[mu], bl2[nu], acc[mu][nu], 0, 0, 0);
                    acc[mu][nu] = __builtin_amdgcn_mfma_f32_16x16x32_bf16(al2[mu], bh[nu], acc[mu][nu], 0, 0, 0);
                }
            __syncthreads();
        }
        // epilogue: x_c -> cat2 channels 120..239 split-bf16
#pragma unroll
        for (int mu = 0; mu < 4; ++mu) {
#pragma unroll
            for (int rr = 0; rr < 4; ++rr) {
                int l = mh * 128 + wm * 64 + mu * 16 + g * 4 + rr;
                size_t pix = (size_t)pix_of(w, l);
                unsigned short* op = cat2 + pix * 512;
#pragma unroll
                for (int nu = 0; nu < 4; ++nu) {
                    int c = wn * 64 + nu * 16 + i;
                    if (c < 120) {
                        float v = acc[mu][nu][rr] * (1.f / 256.f);
                        unsigned short h = bf16rn(v);
                        op[120 + c] = h;
                        op[256 + 120 + c] = bf16rn(v - bf16tof(h));
                    }
                }
            }
        }
    }
}

extern "C" void kernel_launch(void* const* d_in, const int* in_sizes, int n_in,
                              void* d_out, int out_size, void* d_ws, size_t ws_size,
                              hipStream_t stream)
{
    (void)in_sizes; (void)n_in; (void)out_size;
    const float* x     = (const float*)d_in[0];
    const float* c1_w  = (const float*)d_in[1];
    const float* c1_b  = (const float*)d_in[2];
    const float* c2_w  = (const float*)d_in[3];
    const float* c2_b  = (const float*)d_in[4];
    const float* c3_w  = (const float*)d_in[5];
    const float* c3_b  = (const float*)d_in[6];
    const float* lin_w = (const float*)d_in[7];
    const float* lin_b = (const float*)d_in[8];
    const float* sl_w  = (const float*)d_in[9];
    const float* sl_b  = (const float*)d_in[10];
    const float* pp_w  = (const float*)d_in[11];
    const float* pp_b  = (const float*)d_in[12];
    const float* ln1_g = (const float*)d_in[13];
    const float* ln1_b = (const float*)d_in[14];
    const float* p1_w  = (const float*)d_in[15];
    const float* p1_b  = (const float*)d_in[16];
    const float* ln2_g = (const float*)d_in[17];
    const float* ln2_b = (const float*)d_in[18];
    const float* p2_w  = (const float*)d_in[19];
    const float* p2_b  = (const float*)d_in[20];
    const float* ln3_g = (const float*)d_in[21];
    const float* ln3_b = (const float*)d_in[22];
    const float* p3_w  = (const float*)d_in[23];
    const float* p3_b  = (const float*)d_in[24];
    const float* proj_w = (const float*)d_in[25];
    const float* proj_b = (const float*)d_in[26];

    float* ws = (float*)d_ws;
    float* pos3   = ws;                                           // -> 8192
    float* rpb_t  = ws + 8192;                                    // -> 106496
    unsigned short* lin_w2  = (unsigned short*)(ws + 106496);     // -> 172032
    unsigned short* c3_w2   = (unsigned short*)(ws + 172032);     // -> 188416
    unsigned short* proj_w2 = (unsigned short*)(ws + 188416);     // -> 253952
    unsigned short* c1_w2   = (unsigned short*)(ws + 253952);     // -> 286720
    unsigned short* c2w2    = (unsigned short*)(ws + 286720);     // -> 314368
    unsigned short* t2s = (unsigned short*)(ws + 314368);         // -> 8702976
    unsigned short* xs2 = (unsigned short*)(ws + 8702976);        // -> 42257408
    unsigned short* cat2 = xs2;                                   // overlays xs2
    float* qvb    = ws + 42257408;                                // -> 73714688
    unsigned short* t1s = (unsigned short*)qvb;                   // overlays qvb head
    const size_t required = (size_t)73714688 * 4;                 // 294.9 MB
    if (ws_size < required) return;

    pack_all_kernel<<<16499, 256, 0, stream>>>(lin_w, proj_w, c3_w, c1_w, c2_w, x,
                                               lin_w2, proj_w2, c3_w2, c1_w2, c2w2, xs2);
    prep_pos_kernel<<<4, 256, 0, stream>>>(pp_w, pp_b, ln1_g, ln1_b, p1_w, p1_b,
                                           ln2_g, ln2_b, p2_w, p2_b, ln3_g, ln3_b,
                                           p3_w, p3_b, pos3);
    rpb_kernel<<<384, 256, 0, stream>>>(pos3, rpb_t);
    conv1_mfma_kernel<<<1024, 256, 0, stream>>>(xs2, c1_w2, c1_b, t1s);
    conv2_mfma_kernel<<<1024, 256, 0, stream>>>(t1s, c2w2, c2_b, t2s);
    qv_mfma_kernel<<<dim3(2, 1024), 256, 0, stream>>>(xs2, lin_w2, lin_b, t2s, c3_w2, c3_b, qvb);
    xs_kernel<<<3072, 256, 0, stream>>>(qvb, rpb_t, sl_w, sl_b, cat2);
    corrxc_kernel<<<512, 256, 86016, stream>>>(qvb, cat2);
    proj_mfma_kernel<<<dim3(2, 1024), 256, 0, stream>>>(cat2, proj_w2, proj_b, (float*)d_out);
}

// Round 19
// 507.706 us; speedup vs baseline: 1.1122x; 1.0043x over previous
//
#include <hip/hip_runtime.h>
#include <math.h>

#define NPIX 131072   // 2*256*256

typedef __attribute__((ext_vector_type(8))) short bfrag;
typedef __attribute__((ext_vector_type(4))) float facc;
typedef __attribute__((ext_vector_type(4))) unsigned short us4;

__device__ __forceinline__ float lrelu_f(float x) { return x >= 0.f ? x : 0.2f * x; }

// window w (0..511): b=w>>8, wi=(w>>4)&15, wj=w&15 ; l (0..255): i=l>>4, j=l&15
__device__ __forceinline__ int pix_of(int w, int l) {
    int b = w >> 8, wi = (w >> 4) & 15, wj = w & 15;
    return ((((b << 4) + wi) * 16 + (l >> 4)) << 8) + (wj << 4) + (l & 15);
}

// ---- bf16 split helpers (round-to-nearest-even) ----
__device__ __forceinline__ unsigned short bf16rn(float f) {
    unsigned u = __builtin_bit_cast(unsigned, f);
    u += 0x7FFFu + ((u >> 16) & 1u);
    return (unsigned short)(u >> 16);
}
__device__ __forceinline__ float bf16tof(unsigned short h) {
    unsigned u = ((unsigned)h) << 16;
    return __builtin_bit_cast(float, u);
}

// ---------------- split_x body: fp32 -> packed [hi|lo] bf16 ----------------
__device__ __forceinline__ void split_x_body(const float* __restrict__ x,
                                             unsigned short* __restrict__ xs2, int idx)
{
    int row = idx >> 5;
    int k = (idx & 31) * 8;
    float v[8];
    if (k < 240) {
        float4 a = *(const float4*)(x + (size_t)row * 240 + k);
        float4 b = *(const float4*)(x + (size_t)row * 240 + k + 4);
        v[0] = a.x; v[1] = a.y; v[2] = a.z; v[3] = a.w;
        v[4] = b.x; v[5] = b.y; v[6] = b.z; v[7] = b.w;
    } else {
#pragma unroll
        for (int e = 0; e < 8; ++e) v[e] = 0.f;
    }
    bfrag hi, lo;
#pragma unroll
    for (int e = 0; e < 8; ++e) {
        unsigned short h = bf16rn(v[e]);
        hi[e] = (short)h;
        lo[e] = (short)bf16rn(v[e] - bf16tof(h));
    }
    unsigned short* dst = xs2 + (size_t)row * 512 + k;
    *(bfrag*)(dst) = hi;
    *(bfrag*)(dst + 256) = lo;
}

// generic weight pack body
__device__ __forceinline__ void pack_w_body(const float* __restrict__ src,
                                            int rows, int K,
                                            unsigned short* __restrict__ dst,
                                            int total8, int KPAD, int idx)
{
    if (idx >= total8) return;
    int kper = KPAD >> 3;
    int row = idx / kper;
    int k = (idx - row * kper) * 8;
    float v[8];
#pragma unroll
    for (int e = 0; e < 8; ++e) {
        int kk = k + e;
        v[e] = (row < rows && kk < K) ? src[(size_t)row * K + kk] : 0.f;
    }
    bfrag hi, lo;
#pragma unroll
    for (int e = 0; e < 8; ++e) {
        unsigned short h = bf16rn(v[e]);
        hi[e] = (short)h;
        lo[e] = (short)bf16rn(v[e] - bf16tof(h));
    }
    unsigned short* d = dst + (size_t)row * 2 * KPAD + k;
    *(bfrag*)(d) = hi;
    *(bfrag*)(d + KPAD) = lo;
}

// c2 weights body -> c2w2[tap][n][ hi64 | lo64 ]
__device__ __forceinline__ void pack_c2w_body(const float* __restrict__ c2_w,
                                              unsigned short* __restrict__ c2w2, int idx)
{
    if (idx >= 6912) return;
    int rowid = idx >> 4;
    int c = idx & 15;
    int tap = rowid / 48, n = rowid - tap * 48;
    int ty = tap / 3, tx = tap - ty * 3;
    int lohalf = c >> 3;
    int cbase = (c & 7) * 8;
    bfrag outv;
#pragma unroll
    for (int e = 0; e < 8; ++e) {
        int ci = cbase + e;
        float v = (ci < 48) ? c2_w[(((size_t)n * 48 + ci) * 3 + ty) * 3 + tx] : 0.f;
        unsigned short h = bf16rn(v);
        outv[e] = (short)(lohalf ? bf16rn(v - bf16tof(h)) : h);
    }
    *(bfrag*)(c2w2 + (size_t)rowid * 128 + c * 8) = outv;
}

// merged pre-pass kernel
__global__ __launch_bounds__(256) void pack_all_kernel(
    const float* __restrict__ lin_w, const float* __restrict__ proj_w,
    const float* __restrict__ c3_w, const float* __restrict__ c1_w,
    const float* __restrict__ c2_w, const float* __restrict__ x,
    unsigned short* __restrict__ lin_w2, unsigned short* __restrict__ proj_w2,
    unsigned short* __restrict__ c3_w2, unsigned short* __restrict__ c1_w2,
    unsigned short* __restrict__ c2w2, unsigned short* __restrict__ xs2)
{
    int blk = blockIdx.x, tid = threadIdx.x;
    if (blk < 32)       pack_w_body(lin_w, 240, 240, lin_w2, 8192, 256, blk * 256 + tid);
    else if (blk < 64)  pack_w_body(proj_w, 240, 240, proj_w2, 8192, 256, (blk - 32) * 256 + tid);
    else if (blk < 72)  pack_w_body(c3_w, 240, 48, c3_w2, 2048, 64, (blk - 64) * 256 + tid);
    else if (blk < 88)  pack_w_body(c1_w, 48, 240, c1_w2, 4096, 256, (blk - 72) * 256 + tid);
    else if (blk < 115) pack_c2w_body(c2_w, c2w2, (blk - 88) * 256 + tid);
    else                split_x_body(x, xs2, (blk - 115) * 256 + tid);
}

// ---------------- prep: DynamicPosBias MLP ----------------
__device__ __forceinline__ void ln_relu15(const float* h, float* r,
                                          const float* __restrict__ g,
                                          const float* __restrict__ b) {
    float m = 0.f;
#pragma unroll
    for (int f = 0; f < 15; ++f) m += h[f];
    m *= (1.f / 15.f);
    float v = 0.f;
#pragma unroll
    for (int f = 0; f < 15; ++f) { float d = h[f] - m; v += d * d; }
    float rs = rsqrtf(v * (1.f / 15.f) + 1e-5f);
#pragma unroll
    for (int f = 0; f < 15; ++f) {
        float xx = (h[f] - m) * rs * g[f] + b[f];
        r[f] = xx > 0.f ? xx : 0.f;
    }
}

__device__ __forceinline__ void lin15(const float* r, float* h,
                                      const float* __restrict__ w,
                                      const float* __restrict__ b) {
#pragma unroll
    for (int o = 0; o < 15; ++o) {
        float s = b[o];
#pragma unroll
        for (int g = 0; g < 15; ++g) s += r[g] * w[o * 15 + g];
        h[o] = s;
    }
}

__global__ __launch_bounds__(256) void prep_pos_kernel(
    const float* __restrict__ pp_w, const float* __restrict__ pp_b,
    const float* __restrict__ ln1_g, const float* __restrict__ ln1_b,
    const float* __restrict__ p1_w, const float* __restrict__ p1_b,
    const float* __restrict__ ln2_g, const float* __restrict__ ln2_b,
    const float* __restrict__ p2_w, const float* __restrict__ p2_b,
    const float* __restrict__ ln3_g, const float* __restrict__ ln3_b,
    const float* __restrict__ p3_w, const float* __restrict__ p3_b,
    float* __restrict__ pos3)
{
    int idx = blockIdx.x * 256 + threadIdx.x;
    if (idx >= 961) return;
    float h[15], r[15];
    float in0 = (float)(idx / 31) - 15.f;
    float in1 = (float)(idx % 31) - 15.f;
#pragma unroll
    for (int f = 0; f < 15; ++f) h[f] = in0 * pp_w[2 * f] + in1 * pp_w[2 * f + 1] + pp_b[f];
    ln_relu15(h, r, ln1_g, ln1_b);
    lin15(r, h, p1_w, p1_b);
    ln_relu15(h, r, ln2_g, ln2_b);
    lin15(r, h, p2_w, p2_b);
    ln_relu15(h, r, ln3_g, ln3_b);
#pragma unroll
    for (int o = 0; o < 6; ++o) {
        float s = p3_b[o];
#pragma unroll
        for (int g = 0; g < 15; ++g) s += r[g] * p3_w[o * 15 + g];
        pos3[idx * 6 + o] = s;
    }
}

// rpb_t[n][k][l]
__global__ __launch_bounds__(256) void rpb_kernel(const float* __restrict__ pos3,
                                                  float* __restrict__ rpb_t)
{
    int out = blockIdx.x * 256 + threadIdx.x;
    int n = out >> 14;
    int k = (out >> 8) & 63;
    int l = out & 255;
    int a = k >> 3, c = k & 7;
    int i1 = l >> 4, j1 = l & 15;
    float s = 0.f;
#pragma unroll
    for (int bb = 0; bb < 2; ++bb)
#pragma unroll
        for (int d = 0; d < 2; ++d) {
            int i2 = a * 2 + bb, j2 = c * 2 + d;
            int rpi = (i1 - i2 + 15) * 31 + (j1 - j2 + 15);
            s += pos3[rpi * 6 + n];
        }
    rpb_t[out] = s * 0.25f;
}

// ---------------- MFMA split-bf16 NT GEMM core, BM=128 BN=128 (R11 known-good) ----------------
__device__ __forceinline__ void mfma_kpass3(const unsigned short* __restrict__ A2, int lda2,
                                            const unsigned short* __restrict__ W2, int ldw2,
                                            int ksteps, int mbase, int nbase,
                                            short* lds_a, short* lds_w,
                                            int tid, int wm, int wn,
                                            facc acc[4][4])
{
    int lane = tid & 63;
    int i = lane & 15, g = lane >> 4;
    int kpa = lda2 >> 1, kpw = ldw2 >> 1;
    for (int s = 0; s < ksteps; ++s) {
        int k0 = s * 32;
        {
            int r = tid >> 1, h16 = (tid & 1) * 16;
            const unsigned short* src = A2 + (size_t)(mbase + r) * lda2 + k0 + h16;
            bfrag h0 = *(const bfrag*)(src);
            bfrag h1 = *(const bfrag*)(src + 8);
            bfrag l0 = *(const bfrag*)(src + kpa);
            bfrag l1 = *(const bfrag*)(src + kpa + 8);
            short* dst = lds_a + r * 72 + h16;
            *(bfrag*)(dst)      = h0;  *(bfrag*)(dst + 8)  = h1;
            *(bfrag*)(dst + 32) = l0;  *(bfrag*)(dst + 40) = l1;
        }
        {
            int r = tid >> 1, half = tid & 1;
            const unsigned short* src = W2 + (size_t)(nbase + r) * ldw2 + half * kpw + k0;
            bfrag v0 = *(const bfrag*)(src);
            bfrag v1 = *(const bfrag*)(src + 8);
            bfrag v2 = *(const bfrag*)(src + 16);
            bfrag v3 = *(const bfrag*)(src + 24);
            short* dst = lds_w + r * 72 + half * 32;
            *(bfrag*)(dst)      = v0;  *(bfrag*)(dst + 8)  = v1;
            *(bfrag*)(dst + 16) = v2;  *(bfrag*)(dst + 24) = v3;
        }
        __syncthreads();
        bfrag ah[4], al[4], bh[4], bl[4];
#pragma unroll
        for (int mu = 0; mu < 4; ++mu) {
            const short* p = lds_a + (wm * 64 + mu * 16 + i) * 72 + g * 8;
            ah[mu] = *(const bfrag*)(p);
            al[mu] = *(const bfrag*)(p + 32);
        }
#pragma unroll
        for (int nu = 0; nu < 4; ++nu) {
            const short* p = lds_w + (wn * 64 + nu * 16 + i) * 72 + g * 8;
            bh[nu] = *(const bfrag*)(p);
            bl[nu] = *(const bfrag*)(p + 32);
        }
#pragma unroll
        for (int mu = 0; mu < 4; ++mu)
#pragma unroll
            for (int nu = 0; nu < 4; ++nu) {
                acc[mu][nu] = __builtin_amdgcn_mfma_f32_16x16x32_bf16(ah[mu], bh[nu], acc[mu][nu], 0, 0, 0);
                acc[mu][nu] = __builtin_amdgcn_mfma_f32_16x16x32_bf16(ah[mu], bl[nu], acc[mu][nu], 0, 0, 0);
                acc[mu][nu] = __builtin_amdgcn_mfma_f32_16x16x32_bf16(al[mu], bh[nu], acc[mu][nu], 0, 0, 0);
            }
        __syncthreads();
    }
}

// ---------------- BN=64 variant (conv1): simple 2-barrier loop, 4 waves = 2x2 ----------------
__device__ __forceinline__ void mfma_kpass_n64(const unsigned short* __restrict__ A2, int lda2,
                                               const unsigned short* __restrict__ W2, int ldw2,
                                               int ksteps, int mbase,
                                               short* lds_a, short* lds_w,
                                               int tid, int wm, int wn,
                                               facc acc[4][2])
{
    int lane = tid & 63;
    int i = lane & 15, g = lane >> 4;
    int kpa = lda2 >> 1, kpw = ldw2 >> 1;
    for (int s = 0; s < ksteps; ++s) {
        int k0 = s * 32;
        {
            int r = tid >> 1, h16 = (tid & 1) * 16;
            const unsigned short* src = A2 + (size_t)(mbase + r) * lda2 + k0 + h16;
            bfrag h0 = *(const bfrag*)(src);
            bfrag h1 = *(const bfrag*)(src + 8);
            bfrag l0 = *(const bfrag*)(src + kpa);
            bfrag l1 = *(const bfrag*)(src + kpa + 8);
            short* dst = lds_a + r * 72 + h16;
            *(bfrag*)(dst)      = h0;  *(bfrag*)(dst + 8)  = h1;
            *(bfrag*)(dst + 32) = l0;  *(bfrag*)(dst + 40) = l1;
        }
        if (tid < 128) {
            int r = tid >> 1, half = tid & 1;
            const unsigned short* src = W2 + (size_t)r * ldw2 + half * kpw + k0;
            bfrag v0 = *(const bfrag*)(src);
            bfrag v1 = *(const bfrag*)(src + 8);
            bfrag v2 = *(const bfrag*)(src + 16);
            bfrag v3 = *(const bfrag*)(src + 24);
            short* dst = lds_w + r * 72 + half * 32;
            *(bfrag*)(dst)      = v0;  *(bfrag*)(dst + 8)  = v1;
            *(bfrag*)(dst + 16) = v2;  *(bfrag*)(dst + 24) = v3;
        }
        __syncthreads();
        bfrag ah[4], al[4], bh[2], bl[2];
#pragma unroll
        for (int mu = 0; mu < 4; ++mu) {
            const short* p = lds_a + (wm * 64 + mu * 16 + i) * 72 + g * 8;
            ah[mu] = *(const bfrag*)(p);
            al[mu] = *(const bfrag*)(p + 32);
        }
#pragma unroll
        for (int nu = 0; nu < 2; ++nu) {
            const short* p = lds_w + (wn * 32 + nu * 16 + i) * 72 + g * 8;
            bh[nu] = *(const bfrag*)(p);
            bl[nu] = *(const bfrag*)(p + 32);
        }
#pragma unroll
        for (int mu = 0; mu < 4; ++mu)
#pragma unroll
            for (int nu = 0; nu < 2; ++nu) {
                acc[mu][nu] = __builtin_amdgcn_mfma_f32_16x16x32_bf16(ah[mu], bh[nu], acc[mu][nu], 0, 0, 0);
                acc[mu][nu] = __builtin_amdgcn_mfma_f32_16x16x32_bf16(ah[mu], bl[nu], acc[mu][nu], 0, 0, 0);
                acc[mu][nu] = __builtin_amdgcn_mfma_f32_16x16x32_bf16(al[mu], bh[nu], acc[mu][nu], 0, 0, 0);
            }
        __syncthreads();
    }
}

// conv1: t1s = split(lrelu(x @ c1_w^T + c1_b)) packed [hi64|lo64], N=48 (BN=64)
__global__ __launch_bounds__(256, 3) void conv1_mfma_kernel(const unsigned short* __restrict__ xs2,
    const unsigned short* __restrict__ c1_w2, const float* __restrict__ bias,
    unsigned short* __restrict__ t1s)
{
    __shared__ __align__(16) short lds_a[128 * 72];
    __shared__ __align__(16) short lds_w[64 * 72];
    int tid = threadIdx.x;
    int lane = tid & 63, wid = tid >> 6;
    int wm = wid >> 1, wn = wid & 1;
    int mbase = blockIdx.x * 128;
    facc zero = {0.f, 0.f, 0.f, 0.f};
    facc acc[4][2];
#pragma unroll
    for (int mu = 0; mu < 4; ++mu)
#pragma unroll
        for (int nu = 0; nu < 2; ++nu) acc[mu][nu] = zero;

    mfma_kpass_n64(xs2, 512, c1_w2, 512, 8, mbase, lds_a, lds_w, tid, wm, wn, acc);

    int i = lane & 15, g = lane >> 4;
#pragma unroll
    for (int nu = 0; nu < 2; ++nu) {
        int n = wn * 32 + nu * 16 + i;
        if (n < 48) {
            float bv = bias[n];
#pragma unroll
            for (int mu = 0; mu < 4; ++mu)
#pragma unroll
                for (int rr = 0; rr < 4; ++rr) {
                    size_t m = (size_t)mbase + wm * 64 + mu * 16 + g * 4 + rr;
                    float v = lrelu_f(acc[mu][nu][rr] + bv);
                    unsigned short h = bf16rn(v);
                    t1s[m * 128 + n] = h;
                    t1s[m * 128 + 64 + n] = bf16rn(v - bf16tof(h));
                }
        }
    }
    if (tid < 128) {
        size_t m = (size_t)mbase + tid;
        bfrag z = {0, 0, 0, 0, 0, 0, 0, 0};
        *(bfrag*)(t1s + m * 128 + 48)  = z;
        *(bfrag*)(t1s + m * 128 + 56)  = z;
        *(bfrag*)(t1s + m * 128 + 112) = z;
        *(bfrag*)(t1s + m * 128 + 120) = z;
    }
}

// conv2: 3x3 48->48 as MFMA shifted-GEMM.
__global__ __launch_bounds__(256) void conv2_mfma_kernel(const unsigned short* __restrict__ t1s,
    const unsigned short* __restrict__ c2w2, const float* __restrict__ bias,
    unsigned short* __restrict__ t2s)
{
    __shared__ __align__(16) short a_s[130 * 128];
    int bid = blockIdx.x;
    int xcd = bid & 7;
    int j = bid >> 3;
    int half = j & 1;
    int rl = (j >> 1) & 31;
    int b = j >> 6;
    int r = xcd * 32 + rl;
    int c0 = half * 128;
    int tid = threadIdx.x;
    int lane = tid & 63, wid = tid >> 6;
    int i = lane & 15, g = lane >> 4;
    facc zero = {0.f, 0.f, 0.f, 0.f};
    facc acc[2][3];
#pragma unroll
    for (int mu = 0; mu < 2; ++mu)
#pragma unroll
        for (int nu = 0; nu < 3; ++nu) acc[mu][nu] = zero;

    for (int dy = 0; dy < 3; ++dy) {
        int grow = r + dy - 1;
        bool rowok = (grow >= 0 && grow < 256);
        for (int idx = tid; idx < 130 * 16; idx += 256) {
            int j2 = idx >> 4, ch = idx & 15;
            int gc = c0 - 1 + j2;
            bfrag v = {0, 0, 0, 0, 0, 0, 0, 0};
            if (rowok && gc >= 0 && gc < 256) {
                size_t gpix = ((size_t)b * 256 + grow) * 256 + gc;
                v = *(const bfrag*)(t1s + gpix * 128 + ch * 8);
            }
            *(bfrag*)&a_s[j2 * 128 + ((ch ^ (j2 & 7)) * 8)] = v;
        }
        __syncthreads();
#pragma unroll
        for (int dx = 0; dx < 3; ++dx) {
            const unsigned short* wb = c2w2 + (size_t)(dy * 3 + dx) * 48 * 128;
#pragma unroll
            for (int h = 0; h < 2; ++h) {
                bfrag ah[2], al[2], bh[3], bl[3];
#pragma unroll
                for (int mu = 0; mu < 2; ++mu) {
                    int j2 = wid * 32 + mu * 16 + i + dx;
                    int chi = (h * 4 + g) ^ (j2 & 7);
                    int clo = (8 + h * 4 + g) ^ (j2 & 7);
                    ah[mu] = *(const bfrag*)&a_s[j2 * 128 + chi * 8];
                    al[mu] = *(const bfrag*)&a_s[j2 * 128 + clo * 8];
                }
#pragma unroll
                for (int nu = 0; nu < 3; ++nu) {
                    const unsigned short* wp = wb + (size_t)(nu * 16 + i) * 128 + h * 32 + g * 8;
                    bh[nu] = *(const bfrag*)(wp);
                    bl[nu] = *(const bfrag*)(wp + 64);
                }
#pragma unroll
                for (int mu = 0; mu < 2; ++mu)
#pragma unroll
                    for (int nu = 0; nu < 3; ++nu) {
                        acc[mu][nu] = __builtin_amdgcn_mfma_f32_16x16x32_bf16(ah[mu], bh[nu], acc[mu][nu], 0, 0, 0);
                        acc[mu][nu] = __builtin_amdgcn_mfma_f32_16x16x32_bf16(ah[mu], bl[nu], acc[mu][nu], 0, 0, 0);
                        acc[mu][nu] = __builtin_amdgcn_mfma_f32_16x16x32_bf16(al[mu], bh[nu], acc[mu][nu], 0, 0, 0);
                    }
            }
        }
        __syncthreads();
    }
#pragma unroll
    for (int nu = 0; nu < 3; ++nu) {
        int n = nu * 16 + i;
        float bv = bias[n];
#pragma unroll
        for (int mu = 0; mu < 2; ++mu)
#pragma unroll
            for (int rr = 0; rr < 4; ++rr) {
                int lp = wid * 32 + mu * 16 + g * 4 + rr;
                size_t gpix = ((size_t)b * 256 + r) * 256 + (c0 + lp);
                float v = lrelu_f(acc[mu][nu][rr] + bv);
                unsigned short h = bf16rn(v);
                t2s[gpix * 128 + n] = h;
                t2s[gpix * 128 + 64 + n] = bf16rn(v - bf16tof(h));
            }
    }
    if (tid < 128) {
        size_t gpix = ((size_t)b * 256 + r) * 256 + (c0 + tid);
        bfrag z = {0, 0, 0, 0, 0, 0, 0, 0};
        *(bfrag*)(t2s + gpix * 128 + 48)  = z;
        *(bfrag*)(t2s + gpix * 128 + 56)  = z;
        *(bfrag*)(t2s + gpix * 128 + 112) = z;
        *(bfrag*)(t2s + gpix * 128 + 120) = z;
    }
}

// qv = (t2 @ c3_w^T + c3_b) * (x @ lin_w^T + lin_b)   [MFMA, BN=128, XCD-swizzled]
__global__ __launch_bounds__(256) void qv_mfma_kernel(const unsigned short* __restrict__ xs2,
    const unsigned short* __restrict__ lin_w2, const float* __restrict__ lin_b,
    const unsigned short* __restrict__ t2s, const unsigned short* __restrict__ c3_w2,
    const float* __restrict__ c3_b, float* __restrict__ qv)
{
    __shared__ __align__(16) short lds_a[128 * 72];
    __shared__ __align__(16) short lds_w[128 * 72];
    int tid = threadIdx.x;
    int lane = tid & 63, wid = tid >> 6;
    int wm = wid >> 1, wn = wid & 1;
    int bid = blockIdx.y * 2 + blockIdx.x;
    int xcd = bid & 7, j = bid >> 3;
    int mbase = (xcd * 128 + (j >> 1)) * 128;
    int nbase = (j & 1) * 128;
    facc zero = {0.f, 0.f, 0.f, 0.f};
    facc acc1[4][4], acc2[4][4];
#pragma unroll
    for (int mu = 0; mu < 4; ++mu)
#pragma unroll
        for (int nu = 0; nu < 4; ++nu) { acc1[mu][nu] = zero; acc2[mu][nu] = zero; }

    mfma_kpass3(xs2, 512, lin_w2, 512, 8, mbase, nbase, lds_a, lds_w, tid, wm, wn, acc1);
    mfma_kpass3(t2s, 128, c3_w2, 128, 2, mbase, nbase, lds_a, lds_w, tid, wm, wn, acc2);

    int i = lane & 15, g = lane >> 4;
#pragma unroll
    for (int nu = 0; nu < 4; ++nu) {
        int n = nbase + wn * 64 + nu * 16 + i;
        if (n < 240) {
            float lb = lin_b[n], cb = c3_b[n];
#pragma unroll
            for (int mu = 0; mu < 4; ++mu)
#pragma unroll
                for (int rr = 0; rr < 4; ++rr) {
                    size_t m = (size_t)mbase + wm * 64 + mu * 16 + g * 4 + rr;
                    qv[m * 240 + n] = (acc2[mu][nu][rr] + cb) * (acc1[mu][nu][rr] + lb);
                }
        }
    }
}

// proj: out = cat2 @ proj_w^T + proj_b   [MFMA, BN=128, XCD-swizzled]
__global__ __launch_bounds__(256, 3) void proj_mfma_kernel(const unsigned short* __restrict__ cat2,
    const unsigned short* __restrict__ proj_w2, const float* __restrict__ bias,
    float* __restrict__ out)
{
    __shared__ __align__(16) short lds_a[128 * 72];
    __shared__ __align__(16) short lds_w[128 * 72];
    int tid = threadIdx.x;
    int lane = tid & 63, wid = tid >> 6;
    int wm = wid >> 1, wn = wid & 1;
    int bid = blockIdx.y * 2 + blockIdx.x;
    int xcd = bid & 7, j = bid >> 3;
    int mbase = (xcd * 128 + (j >> 1)) * 128;
    int nbase = (j & 1) * 128;
    facc zero = {0.f, 0.f, 0.f, 0.f};
    facc acc[4][4];
#pragma unroll
    for (int mu = 0; mu < 4; ++mu)
#pragma unroll
        for (int nu = 0; nu < 4; ++nu) acc[mu][nu] = zero;

    mfma_kpass3(cat2, 512, proj_w2, 512, 8, mbase, nbase, lds_a, lds_w, tid, wm, wn, acc);

    int i = lane & 15, g = lane >> 4;
#pragma unroll
    for (int nu = 0; nu < 4; ++nu) {
        int n = nbase + wn * 64 + nu * 16 + i;
        if (n < 240) {
            float bv = bias[n];
#pragma unroll
            for (int mu = 0; mu < 4; ++mu)
#pragma unroll
                for (int rr = 0; rr < 4; ++rr) {
                    size_t m = (size_t)mbase + wm * 64 + mu * 16 + g * 4 + rr;
                    out[m * 240 + n] = acc[mu][nu][rr] + bv;
                }
        }
    }
}

// spatial correlation: per (window, head) -> cat2 channels [n*20, n*20+20) split-bf16
__global__ __launch_bounds__(256) void xs_kernel(const float* __restrict__ qv,
    const float* __restrict__ rpb_t, const float* __restrict__ sl_w,
    const float* __restrict__ sl_b, unsigned short* __restrict__ cat2)
{
    __shared__ __align__(16) float v_s[256 * 20];
    __shared__ __align__(16) float vs_s[64 * 20];
    int bid = blockIdx.x;
    int xcd = bid & 7;
    int j = bid >> 3;
    int wl = j / 6;
    int n = j - wl * 6;
    int w = xcd * 64 + wl;
    int tid = threadIdx.x;
    int l = tid;
    size_t pix = (size_t)pix_of(w, l);
    const float* qp = qv + pix * 240 + n * 20;
    float qr[20];
#pragma unroll
    for (int h4 = 0; h4 < 5; ++h4) {
        *(float4*)&qr[h4 * 4] = *(const float4*)(qp + h4 * 4);
        *(float4*)&v_s[l * 20 + h4 * 4] = *(const float4*)(qp + 120 + h4 * 4);
    }
    __syncthreads();
    float slw0 = sl_w[0], slw1 = sl_w[1], slw2 = sl_w[2], slw3 = sl_w[3];
    float slb = sl_b[0];
    for (int idx = tid; idx < 1280; idx += 256) {
        int k = idx / 20, hd = idx % 20;
        int a = k >> 3, c = k & 7;
        int l00 = a * 32 + c * 2;
        float vsum = slb
                   + slw0 * v_s[(l00 + 0) * 20 + hd]
                   + slw1 * v_s[(l00 + 1) * 20 + hd]
                   + slw2 * v_s[(l00 + 16) * 20 + hd]
                   + slw3 * v_s[(l00 + 17) * 20 + hd];
        vs_s[idx] = vsum;
    }
    __syncthreads();
    const float* rp = rpb_t + (size_t)n * 16384 + l;
    float acc[20];
#pragma unroll
    for (int hd = 0; hd < 20; ++hd) acc[hd] = 0.f;
#pragma unroll
    for (int k = 0; k < 64; ++k) {
        float vr[20];
#pragma unroll
        for (int h4 = 0; h4 < 5; ++h4)
            *(float4*)&vr[h4 * 4] = *(const float4*)&vs_s[k * 20 + h4 * 4];
        float s0 = 0.f, s1 = 0.f, s2 = 0.f, s3 = 0.f;
#pragma unroll
        for (int hd = 0; hd < 20; hd += 4) {
            s0 += qr[hd + 0] * vr[hd + 0];
            s1 += qr[hd + 1] * vr[hd + 1];
            s2 += qr[hd + 2] * vr[hd + 2];
            s3 += qr[hd + 3] * vr[hd + 3];
        }
        float cc = (s0 + s1 + s2 + s3) * (1.f / 20.f) + rp[(size_t)k * 256];
#pragma unroll
        for (int hd = 0; hd < 20; ++hd) acc[hd] += cc * vr[hd];
    }
    unsigned short* op = cat2 + pix * 512 + n * 20;
#pragma unroll
    for (int h4 = 0; h4 < 5; ++h4) {
        us4 h, lo;
#pragma unroll
        for (int e = 0; e < 4; ++e) {
            float v = acc[h4 * 4 + e];
            unsigned short hh = bf16rn(v);
            h[e] = hh;
            lo[e] = bf16rn(v - bf16tof(hh));
        }
        *(us4*)(op + h4 * 4) = h;
        *(us4*)(op + 256 + h4 * 4) = lo;
    }
    if (n == 0) {
        bfrag z = {0, 0, 0, 0, 0, 0, 0, 0};
        unsigned short* zp = cat2 + pix * 512;
        *(bfrag*)(zp + 240) = z;  *(bfrag*)(zp + 248) = z;
        *(bfrag*)(zp + 496) = z;  *(bfrag*)(zp + 504) = z;
    }
}

// FUSED channel correlation, full MFMA split-bf16 (R17 verified).
__global__ __launch_bounds__(256) void corrxc_kernel(const float* __restrict__ qv,
                                                     unsigned short* __restrict__ cat2)
{
    extern __shared__ short smem[];
    short* lds_g = smem;
    short* ph1_a = smem;
    short* ph1_w = smem + 9216;
    short* ph2_a = smem + 33792;

    int bid = blockIdx.x;
    int w = (bid & 7) * 64 + (bid >> 3);
    int tid = threadIdx.x;
    int lane = tid & 63, wid = tid >> 6;
    int wm = wid >> 1, wn = wid & 1;
    int i = lane & 15, g = lane >> 4;
    facc zero = {0.f, 0.f, 0.f, 0.f};
    facc acc[4][4];
#pragma unroll
    for (int mu = 0; mu < 4; ++mu)
#pragma unroll
        for (int nu = 0; nu < 4; ++nu) acc[mu][nu] = zero;

    // ---------------- phase 1 ----------------
    for (int l0 = 0; l0 < 256; l0 += 32) {
        int dl = tid & 31;
        int ch0 = (tid >> 5) * 16;
        const float* qp = qv + (size_t)pix_of(w, l0 + dl) * 240;
#pragma unroll
        for (int j4 = 0; j4 < 4; ++j4) {
            int c0 = ch0 + j4 * 4;
            float4 fa = make_float4(0.f, 0.f, 0.f, 0.f);
            float4 fb = make_float4(0.f, 0.f, 0.f, 0.f);
            if (c0 < 120) {
                fa = *(const float4*)(qp + 120 + c0);
                fb = *(const float4*)(qp + c0);
            }
            float ea[4] = {fa.x, fa.y, fa.z, fa.w};
            float eb[4] = {fb.x, fb.y, fb.z, fb.w};
#pragma unroll
            for (int e = 0; e < 4; ++e) {
                int ch = c0 + e;
                unsigned short h = bf16rn(ea[e]);
                ph1_a[ch * 72 + dl]      = (short)h;
                ph1_a[ch * 72 + 32 + dl] = (short)bf16rn(ea[e] - bf16tof(h));
                h = bf16rn(eb[e]);
                ph1_w[ch * 72 + dl]      = (short)h;
                ph1_w[ch * 72 + 32 + dl] = (short)bf16rn(eb[e] - bf16tof(h));
            }
        }
        __syncthreads();
        bfrag ah[4], al2[4], bh[4], bl2[4];
#pragma unroll
        for (int mu = 0; mu < 4; ++mu) {
            const short* p = ph1_a + (wm * 64 + mu * 16 + i) * 72 + g * 8;
            ah[mu] = *(const bfrag*)(p);
            al2[mu] = *(const bfrag*)(p + 32);
        }
#pragma unroll
        for (int nu = 0; nu < 4; ++nu) {
            const short* p = ph1_w + (wn * 64 + nu * 16 + i) * 72 + g * 8;
            bh[nu] = *(const bfrag*)(p);
            bl2[nu] = *(const bfrag*)(p + 32);
        }
#pragma unroll
        for (int mu = 0; mu < 4; ++mu)
#pragma unroll
            for (int nu = 0; nu < 4; ++nu) {
                acc[mu][nu] = __builtin_amdgcn_mfma_f32_16x16x32_bf16(ah[mu], bh[nu], acc[mu][nu], 0, 0, 0);
                acc[mu][nu] = __builtin_amdgcn_mfma_f32_16x16x32_bf16(ah[mu], bl2[nu], acc[mu][nu], 0, 0, 0);
                acc[mu][nu] = __builtin_amdgcn_mfma_f32_16x16x32_bf16(al2[mu], bh[nu], acc[mu][nu], 0, 0, 0);
            }
        __syncthreads();
    }
#pragma unroll
    for (int mu = 0; mu < 4; ++mu)
#pragma unroll
        for (int nu = 0; nu < 4; ++nu)
#pragma unroll
            for (int rr = 0; rr < 4; ++rr) {
                int d = wm * 64 + mu * 16 + g * 4 + rr;
                int c = wn * 64 + nu * 16 + i;
                float v = acc[mu][nu][rr];
                unsigned short h = bf16rn(v);
                lds_g[c * 264 + d]       = (short)h;
                lds_g[c * 264 + 128 + d] = (short)bf16rn(v - bf16tof(h));
            }

    // ---------------- phase 2 ----------------
    for (int mh = 0; mh < 2; ++mh) {
#pragma unroll
        for (int mu = 0; mu < 4; ++mu)
#pragma unroll
            for (int nu = 0; nu < 4; ++nu) acc[mu][nu] = zero;
        for (int k0 = 0; k0 < 128; k0 += 32) {
            {
                int r = tid >> 1, h16 = (tid & 1) * 16;
                const float* qp = qv + (size_t)pix_of(w, mh * 128 + r) * 240 + 120;
                float v[16];
#pragma unroll
                for (int j4 = 0; j4 < 4; ++j4) {
                    int d0 = k0 + h16 + j4 * 4;
                    float4 f = make_float4(0.f, 0.f, 0.f, 0.f);
                    if (d0 < 120) f = *(const float4*)(qp + d0);
                    v[j4 * 4 + 0] = f.x; v[j4 * 4 + 1] = f.y;
                    v[j4 * 4 + 2] = f.z; v[j4 * 4 + 3] = f.w;
                }
                bfrag h0, h1, lo0, lo1;
#pragma unroll
                for (int e = 0; e < 8; ++e) {
                    unsigned short h = bf16rn(v[e]);
                    h0[e] = (short)h;
                    lo0[e] = (short)bf16rn(v[e] - bf16tof(h));
                    h = bf16rn(v[8 + e]);
                    h1[e] = (short)h;
                    lo1[e] = (short)bf16rn(v[8 + e] - bf16tof(h));
                }
                short* dst = ph2_a + r * 72 + h16;
                *(bfrag*)(dst)      = h0;  *(bfrag*)(dst + 8)  = h1;
                *(bfrag*)(dst + 32) = lo0; *(bfrag*)(dst + 40) = lo1;
            }
            __syncthreads();
            bfrag ah[4], al2[4], bh[4], bl2[4];
#pragma unroll
            for (int mu = 0; mu < 4; ++mu) {
                const short* p = ph2_a + (wm * 64 + mu * 16 + i) * 72 + g * 8;
                ah[mu] = *(const bfrag*)(p);
                al2[mu] = *(const bfrag*)(p + 32);
            }
#pragma unroll
            for (int nu = 0; nu < 4; ++nu) {
                const short* p = lds_g + (wn * 64 + nu * 16 + i) * 264 + k0 + g * 8;
                bh[nu] = *(const bfrag*)(p);
                bl2[nu] = *(const bfrag*)(p + 128);
            }
#pragma unroll
            for (int mu = 0; mu < 4; ++mu)
#pragma unroll
                for (int nu = 0; nu < 4; ++nu) {
                    acc[mu][nu] = __builtin_amdgcn_mfma_f32_16x16x32_bf16(ah[mu], bh[nu], acc[mu][nu], 0, 0, 0);
                    acc[mu][nu] = __builtin_amdgcn_mfma_f32_16x16x32_bf16(ah[mu], bl2[nu], acc[mu][nu], 0, 0, 0);
                    acc[mu][nu] = __builtin_amdgcn_mfma_f32_16x16x32_bf16(al2[mu], bh[nu], acc[mu][nu], 0, 0, 0);
                }
            __syncthreads();
        }
#pragma unroll
        for (int mu = 0; mu < 4; ++mu) {
#pragma unroll
            for (int rr = 0; rr < 4; ++rr) {
                int l = mh * 128 + wm * 64 + mu * 16 + g * 4 + rr;
                size_t pix = (size_t)pix_of(w, l);
                unsigned short* op = cat2 + pix * 512;
#pragma unroll
                for (int nu = 0; nu < 4; ++nu) {
                    int c = wn * 64 + nu * 16 + i;
                    if (c < 120) {
                        float v = acc[mu][nu][rr] * (1.f / 256.f);
                        unsigned short h = bf16rn(v);
                        op[120 + c] = h;
                        op[256 + 120 + c] = bf16rn(v - bf16tof(h));
                    }
                }
            }
        }
    }
}

extern "C" void kernel_launch(void* const* d_in, const int* in_sizes, int n_in,
                              void* d_out, int out_size, void* d_ws, size_t ws_size,
                              hipStream_t stream)
{
    (void)in_sizes; (void)n_in; (void)out_size;
    const float* x     = (const float*)d_in[0];
    const float* c1_w  = (const float*)d_in[1];
    const float* c1_b  = (const float*)d_in[2];
    const float* c2_w  = (const float*)d_in[3];
    const float* c2_b  = (const float*)d_in[4];
    const float* c3_w  = (const float*)d_in[5];
    const float* c3_b  = (const float*)d_in[6];
    const float* lin_w = (const float*)d_in[7];
    const float* lin_b = (const float*)d_in[8];
    const float* sl_w  = (const float*)d_in[9];
    const float* sl_b  = (const float*)d_in[10];
    const float* pp_w  = (const float*)d_in[11];
    const float* pp_b  = (const float*)d_in[12];
    const float* ln1_g = (const float*)d_in[13];
    const float* ln1_b = (const float*)d_in[14];
    const float* p1_w  = (const float*)d_in[15];
    const float* p1_b  = (const float*)d_in[16];
    const float* ln2_g = (const float*)d_in[17];
    const float* ln2_b = (const float*)d_in[18];
    const float* p2_w  = (const float*)d_in[19];
    const float* p2_b  = (const float*)d_in[20];
    const float* ln3_g = (const float*)d_in[21];
    const float* ln3_b = (const float*)d_in[22];
    const float* p3_w  = (const float*)d_in[23];
    const float* p3_b  = (const float*)d_in[24];
    const float* proj_w = (const float*)d_in[25];
    const float* proj_b = (const float*)d_in[26];

    float* ws = (float*)d_ws;
    float* pos3   = ws;                                           // -> 8192
    float* rpb_t  = ws + 8192;                                    // -> 106496
    unsigned short* lin_w2  = (unsigned short*)(ws + 106496);     // -> 172032
    unsigned short* c3_w2   = (unsigned short*)(ws + 172032);     // -> 188416
    unsigned short* proj_w2 = (unsigned short*)(ws + 188416);     // -> 253952
    unsigned short* c1_w2   = (unsigned short*)(ws + 253952);     // -> 286720
    unsigned short* c2w2    = (unsigned short*)(ws + 286720);     // -> 314368
    unsigned short* t2s = (unsigned short*)(ws + 314368);         // -> 8702976
    unsigned short* xs2 = (unsigned short*)(ws + 8702976);        // -> 42257408
    unsigned short* cat2 = xs2;                                   // overlays xs2
    float* qvb    = ws + 42257408;                                // -> 73714688
    unsigned short* t1s = (unsigned short*)qvb;                   // overlays qvb head
    const size_t required = (size_t)73714688 * 4;                 // 294.9 MB
    if (ws_size < required) return;

    pack_all_kernel<<<16499, 256, 0, stream>>>(lin_w, proj_w, c3_w, c1_w, c2_w, x,
                                               lin_w2, proj_w2, c3_w2, c1_w2, c2w2, xs2);
    prep_pos_kernel<<<4, 256, 0, stream>>>(pp_w, pp_b, ln1_g, ln1_b, p1_w, p1_b,
                                           ln2_g, ln2_b, p2_w, p2_b, ln3_g, ln3_b,
                                           p3_w, p3_b, pos3);
    rpb_kernel<<<384, 256, 0, stream>>>(pos3, rpb_t);
    conv1_mfma_kernel<<<1024, 256, 0, stream>>>(xs2, c1_w2, c1_b, t1s);
    conv2_mfma_kernel<<<1024, 256, 0, stream>>>(t1s, c2w2, c2_b, t2s);
    qv_mfma_kernel<<<dim3(2, 1024), 256, 0, stream>>>(xs2, lin_w2, lin_b, t2s, c3_w2, c3_b, qvb);
    xs_kernel<<<3072, 256, 0, stream>>>(qvb, rpb_t, sl_w, sl_b, cat2);
    corrxc_kernel<<<512, 256, 86016, stream>>>(qvb, cat2);
    proj_mfma_kernel<<<dim3(2, 1024), 256, 0, stream>>>(cat2, proj_w2, proj_b, (float*)d_out);
}